// Round 1
// baseline (4556.934 us; speedup 1.0000x reference)
//
#include <hip/hip_runtime.h>
#include <math.h>

#define DIM    768
#define NTOK   2048
#define NSEQ   512
#define NBATCH 4
#define NHEADS 12
#define HD     64
#define QKVC   2304
#define MHEADS 8
#define MHD    96
#define NEXP   8
#define EDIM   3072

// ---------------- helpers ----------------
__device__ __forceinline__ float gelu_exact(float v){
    return 0.5f * v * (1.f + erff(v * 0.70710678118654752f));
}

// ---------------- generic GEMM core: C = act(scale * X@W^T + bias) [+ res] ----------------
// X: rows [rowBase,rowLim) x K, stride ldx.  W: cols via W[c*ldw+k] (wt=0) or W[k*ldw+c] (wt=1).
__device__ __forceinline__ void gemm_core(
    const float* __restrict__ X, int ldx, int rowBase, int rowLim,
    const float* __restrict__ W, int ldw, int wt, int colBase, int colLim,
    int K,
    const float* __restrict__ bias,
    const float* __restrict__ res, int ldres,
    float* __restrict__ C, int ldc, float scale, int act)
{
    __shared__ float Xs[16][65];
    __shared__ float Ws[16][65];
    int tid = threadIdx.x;
    int tx = tid & 15, ty = tid >> 4;
    float acc[4][4] = {};
    for (int k0 = 0; k0 < K; k0 += 16) {
        #pragma unroll
        for (int i = tid; i < 64*16; i += 256) {
            int r = i >> 4, kk = i & 15;
            int gr = rowBase + r;
            Xs[kk][r] = (gr < rowLim) ? X[(size_t)gr*ldx + k0 + kk] : 0.f;
        }
        if (!wt) {
            #pragma unroll
            for (int i = tid; i < 64*16; i += 256) {
                int c = i >> 4, kk = i & 15;
                int gc = colBase + c;
                Ws[kk][c] = (gc < colLim) ? W[(size_t)gc*ldw + k0 + kk] : 0.f;
            }
        } else {
            #pragma unroll
            for (int i = tid; i < 64*16; i += 256) {
                int kk = i >> 6, c = i & 63;
                int gc = colBase + c;
                Ws[kk][c] = (gc < colLim) ? W[(size_t)(k0+kk)*ldw + gc] : 0.f;
            }
        }
        __syncthreads();
        #pragma unroll
        for (int kk = 0; kk < 16; ++kk) {
            float av[4], bv[4];
            #pragma unroll
            for (int i=0;i<4;i++) av[i] = Xs[kk][ty + 16*i];
            #pragma unroll
            for (int j=0;j<4;j++) bv[j] = Ws[kk][tx + 16*j];
            #pragma unroll
            for (int i=0;i<4;i++)
                #pragma unroll
                for (int j=0;j<4;j++)
                    acc[i][j] = fmaf(av[i], bv[j], acc[i][j]);
        }
        __syncthreads();
    }
    #pragma unroll
    for (int i=0;i<4;i++){
        int r = rowBase + ty + 16*i;
        if (r >= rowLim) continue;
        #pragma unroll
        for (int j=0;j<4;j++){
            int c = colBase + tx + 16*j;
            if (c >= colLim) continue;
            float v = acc[i][j] * scale;
            if (bias) v += bias[c];
            if (act == 1) v = gelu_exact(v);
            if (res) v += res[(size_t)r*ldres + c];
            C[(size_t)r*ldc + c] = v;
        }
    }
}

__global__ __launch_bounds__(256) void k_gemm(
    const float* __restrict__ X, int ldx, int M,
    const float* __restrict__ W, int ldw, int N, int K,
    const float* __restrict__ bias, const float* __restrict__ res, int ldres,
    float* __restrict__ C, int ldc, float scale, int act)
{
    gemm_core(X, ldx, blockIdx.x*64, M, W, ldw, 0, blockIdx.y*64, N, K, bias, res, ldres, C, ldc, scale, act);
}

// attn[b,h,n,m] = 1/8 * q.k  (q,k inside packed qkv buffer, row stride QKVC)
__global__ __launch_bounds__(256) void k_gemm_qk(const float* __restrict__ qkv, float* __restrict__ attn)
{
    int z = blockIdx.z, b = z / NHEADS, h = z % NHEADS;
    const float* X = qkv + (size_t)b*NSEQ*QKVC + h*HD;          // q
    const float* W = qkv + (size_t)b*NSEQ*QKVC + DIM + h*HD;    // k
    float* C = attn + (size_t)z*NSEQ*NSEQ;
    gemm_core(X, QKVC, blockIdx.x*64, NSEQ, W, QKVC, 0, blockIdx.y*64, NSEQ, HD,
              nullptr, nullptr, 0, C, NSEQ, 0.125f, 0);
}

// o[b,n,h*64+d] = sum_m P[b,h,n,m] * v[b,m,h*64+d]   (B operand is K-major: wt=1)
__global__ __launch_bounds__(256) void k_gemm_av(const float* __restrict__ attn, const float* __restrict__ qkv, float* __restrict__ o)
{
    int z = blockIdx.z, b = z / NHEADS, h = z % NHEADS;
    const float* X = attn + (size_t)z*NSEQ*NSEQ;
    const float* W = qkv + (size_t)b*NSEQ*QKVC + 2*DIM + h*HD;  // v, accessed [m*QKVC + d]
    float* C = o + (size_t)b*NSEQ*DIM + h*HD;
    gemm_core(X, NSEQ, blockIdx.x*64, NSEQ, W, QKVC, 1, 0, HD, NSEQ,
              nullptr, nullptr, 0, C, DIM, 1.f, 0);
}

// per-expert GEMM on compact gathered rows [prefix[e], prefix[e]+cnt[e])
__global__ __launch_bounds__(256) void k_gemm_expert(
    const float* __restrict__ X, int ldx,
    const float* __restrict__ Wb, int ldw, long wStride,
    const float* __restrict__ biasB, int biasStride,
    const int* __restrict__ prefix, const int* __restrict__ cnt,
    float* __restrict__ C, int ldc, int N, int K, int act)
{
    int e = blockIdx.z;
    int n = cnt[e];
    if ((int)blockIdx.x * 64 >= n) return;
    int rowBase = prefix[e] + blockIdx.x*64;
    int rowLim  = prefix[e] + n;
    gemm_core(X, ldx, rowBase, rowLim, Wb + (size_t)e*wStride, ldw, 0, blockIdx.y*64, N, K,
              biasB + (size_t)e*biasStride, nullptr, 0, C, ldc, 1.f, act);
}

// ---------------- PHM weight materialization: W[a*So+c, b*Si+d] = sum_i A[i,a,b]*S[i,c,d] ----------------
__global__ __launch_bounds__(256) void k_phm(
    const float* __restrict__ A, const float* __restrict__ S, float* __restrict__ W,
    int So, int Si, int inF, long Astride, long Sstride, long Wstride)
{
    int e = blockIdx.y;
    const float* Ae = A + (size_t)e*Astride;
    const float* Se = S + (size_t)e*Sstride;
    float* We = W + (size_t)e*Wstride;
    size_t idx = (size_t)blockIdx.x*256 + threadIdx.x;
    size_t total = (size_t)(So*4) * inF;
    if (idx >= total) return;
    int in = (int)(idx % inF);
    int o  = (int)(idx / inF);
    int a = o / So, c = o % So, b = in / Si, d = in % Si;
    float w = 0.f;
    #pragma unroll
    for (int i=0;i<4;i++) w = fmaf(Ae[i*16 + a*4 + b], Se[((size_t)i*So + c)*Si + d], w);
    We[idx] = w;
}

// ---------------- LayerNorm (row=768), works in-place ----------------
__global__ __launch_bounds__(256) void k_ln(const float* __restrict__ x, const float* __restrict__ g,
                                            const float* __restrict__ b, float* __restrict__ y)
{
    int row = blockIdx.x, tid = threadIdx.x;
    const float* xr = x + (size_t)row * DIM;
    float v0 = xr[tid], v1 = xr[tid+256], v2 = xr[tid+512];
    float s = v0+v1+v2;
    float ss = v0*v0 + v1*v1 + v2*v2;
    for (int off=32; off; off>>=1){ s += __shfl_xor(s,off); ss += __shfl_xor(ss,off); }
    __shared__ float sa[4], sb[4];
    int wid = tid >> 6;
    if ((tid & 63) == 0){ sa[wid]=s; sb[wid]=ss; }
    __syncthreads();
    s  = sa[0]+sa[1]+sa[2]+sa[3];
    ss = sb[0]+sb[1]+sb[2]+sb[3];
    float mean = s * (1.f/DIM);
    float var  = ss * (1.f/DIM) - mean*mean;
    float rstd = rsqrtf(var + 1e-5f);
    float* yr = y + (size_t)row*DIM;
    yr[tid]     = (v0-mean)*rstd*g[tid]     + b[tid];
    yr[tid+256] = (v1-mean)*rstd*g[tid+256] + b[tid+256];
    yr[tid+512] = (v2-mean)*rstd*g[tid+512] + b[tid+512];
}

// ---------------- sup/ent head-mixing, in-place on attn scores ----------------
__global__ __launch_bounds__(256) void k_supent(float* __restrict__ attn,
                                                const float* __restrict__ wsup, const float* __restrict__ went)
{
    __shared__ float ws[144], we[144];
    int tid = threadIdx.x;
    if (tid < 144){ ws[tid] = wsup[tid]; we[tid] = went[tid]; }
    __syncthreads();
    size_t idx = (size_t)blockIdx.x*256 + tid;   // B*N*N total
    int m = idx & 511;
    int n = (int)((idx >> 9) & 511);
    int b = (int)(idx >> 18);
    size_t base = (((size_t)b*NHEADS)*NSEQ + n)*NSEQ + m;  // + j*NSEQ*NSEQ per head
    float av[12], sup[12];
    #pragma unroll
    for (int j=0;j<12;j++) av[j] = attn[base + (size_t)j*NSEQ*NSEQ];
    #pragma unroll
    for (int i=0;i<12;i++){
        float s = 0.f;
        #pragma unroll
        for (int j=0;j<12;j++) s = fmaf(ws[i*12+j], av[j], s);
        sup[i] = s;
    }
    #pragma unroll
    for (int i=0;i<12;i++){
        float s = sup[i];
        #pragma unroll
        for (int j=0;j<12;j++) s = fmaf(we[i*12+j], sup[j], s);
        attn[base + (size_t)i*NSEQ*NSEQ] = tanhf(s);
    }
}

// ---------------- softmax over last dim (512), one wave per row, in-place ----------------
__global__ __launch_bounds__(64) void k_softmax(float* __restrict__ buf)
{
    size_t base = (size_t)blockIdx.x * NSEQ;
    int lane = threadIdx.x;
    float v[8];
    float mx = -1e30f;
    #pragma unroll
    for (int i=0;i<8;i++){ v[i] = buf[base + i*64 + lane]; mx = fmaxf(mx, v[i]); }
    for (int off=32; off; off>>=1) mx = fmaxf(mx, __shfl_xor(mx, off));
    float sum = 0.f;
    #pragma unroll
    for (int i=0;i<8;i++){ v[i] = expf(v[i]-mx); sum += v[i]; }
    for (int off=32; off; off>>=1) sum += __shfl_xor(sum, off);
    float inv = 1.f/sum;
    #pragma unroll
    for (int i=0;i<8;i++) buf[base + i*64 + lane] = v[i]*inv;
}

// ---------------- MoE routing: logits, top-2, counts ----------------
__global__ __launch_bounds__(256) void k_route(
    const float* __restrict__ ln2, const float* __restrict__ Wr,
    const float* __restrict__ rb, const float* __restrict__ dr,
    const int* __restrict__ did, int* __restrict__ topi, float* __restrict__ topw, int* __restrict__ cnt)
{
    int t = blockIdx.x, tid = threadIdx.x;
    const float* xr = ln2 + (size_t)t*DIM;
    float a[8] = {};
    #pragma unroll
    for (int ii=0; ii<3; ii++){
        int i = tid + ii*256;
        float xv = xr[i];
        #pragma unroll
        for (int e=0;e<8;e++) a[e] = fmaf(xv, Wr[e*DIM + i], a[e]);
    }
    #pragma unroll
    for (int e=0;e<8;e++)
        for (int off=32; off; off>>=1) a[e] += __shfl_xor(a[e], off);
    __shared__ float sred[4][8];
    int wid = tid >> 6;
    if ((tid & 63) == 0){
        #pragma unroll
        for (int e=0;e<8;e++) sred[wid][e] = a[e];
    }
    __syncthreads();
    if (tid == 0){
        int d = did[0];
        float lg[8];
        #pragma unroll
        for (int e=0;e<8;e++) lg[e] = sred[0][e]+sred[1][e]+sred[2][e]+sred[3][e] + rb[e] + dr[d*8+e];
        int i1 = 0; float v1 = lg[0];
        #pragma unroll
        for (int e=1;e<8;e++) if (lg[e] > v1){ v1 = lg[e]; i1 = e; }
        int i2 = -1; float v2 = -1e30f;
        #pragma unroll
        for (int e=0;e<8;e++) if (e != i1 && lg[e] > v2){ v2 = lg[e]; i2 = e; }
        float e2 = expf(v2 - v1);
        float inv = 1.f / (1.f + e2);
        topi[2*t] = i1; topi[2*t+1] = i2;
        topw[2*t] = inv; topw[2*t+1] = e2 * inv;
        atomicAdd(&cnt[i1], 1); atomicAdd(&cnt[i2], 1);
    }
}

__global__ void k_zero(int* p, int n){ int i = threadIdx.x; if (i < n) p[i] = 0; }

__global__ void k_prefix(const int* __restrict__ cnt, int* __restrict__ prefix){
    if (threadIdx.x == 0){ int s=0; for (int e=0;e<8;e++){ prefix[e]=s; s+=cnt[e]; } }
}

__global__ __launch_bounds__(256) void k_assign(
    const int* __restrict__ topi, const int* __restrict__ prefix,
    int* __restrict__ cnt2, int* __restrict__ rowof, int* __restrict__ tokof)
{
    int t = blockIdx.x*256 + threadIdx.x;
    if (t >= NTOK) return;
    #pragma unroll
    for (int k=0;k<2;k++){
        int e = topi[2*t+k];
        int slot = atomicAdd(&cnt2[e], 1);
        int row = prefix[e] + slot;
        rowof[2*t+k] = row;
        tokof[row] = t;
    }
}

__global__ __launch_bounds__(256) void k_gather(const float* __restrict__ src, const int* __restrict__ tokof, float* __restrict__ dst)
{
    size_t i = (size_t)blockIdx.x*256 + threadIdx.x;
    int row = (int)(i / DIM), c = (int)(i % DIM);
    dst[i] = src[(size_t)tokof[row]*DIM + c];
}

__global__ __launch_bounds__(256) void k_combine(
    const float* __restrict__ att, const float* __restrict__ outg,
    const int* __restrict__ rowof, const float* __restrict__ topw, float* __restrict__ eo)
{
    size_t i = (size_t)blockIdx.x*256 + threadIdx.x;
    int t = (int)(i / DIM), c = (int)(i % DIM);
    int r0 = rowof[2*t], r1 = rowof[2*t+1];
    eo[i] = att[i] + topw[2*t]*outg[(size_t)r0*DIM+c] + topw[2*t+1]*outg[(size_t)r1*DIM+c];
}

// ---------------- memory-bank MHA: one block per (token, head) ----------------
__global__ __launch_bounds__(256) void k_memmha(
    const float* __restrict__ qb, const float* __restrict__ kb,
    const float* __restrict__ vb, float* __restrict__ ob, int M, float scale)
{
    int t = blockIdx.x, h = blockIdx.y, tid = threadIdx.x;
    __shared__ float q[MHD];
    __shared__ float p[256];
    __shared__ float red[256];
    if (tid < MHD) q[tid] = qb[(size_t)t*DIM + h*MHD + tid];
    __syncthreads();
    float s = -1e30f;
    if (tid < M){
        float acc = 0.f;
        const float* kr = kb + (size_t)tid*DIM + h*MHD;
        #pragma unroll 8
        for (int d=0; d<MHD; ++d) acc = fmaf(q[d], kr[d], acc);
        s = acc * scale;
    }
    red[tid] = s;
    __syncthreads();
    for (int off=128; off>0; off>>=1){ if (tid < off) red[tid] = fmaxf(red[tid], red[tid+off]); __syncthreads(); }
    float mx = red[0];
    __syncthreads();
    float e = (tid < M) ? expf(s - mx) : 0.f;
    p[tid] = e;
    red[tid] = e;
    __syncthreads();
    for (int off=128; off>0; off>>=1){ if (tid < off) red[tid] += red[tid+off]; __syncthreads(); }
    float inv = 1.f / red[0];
    __syncthreads();
    if (tid < MHD){
        float acc = 0.f;
        for (int m=0; m<M; ++m) acc = fmaf(p[m], vb[(size_t)m*DIM + h*MHD + tid], acc);
        ob[(size_t)t*DIM + h*MHD + tid] = acc * inv;
    }
}

__global__ __launch_bounds__(256) void k_add4(
    const float* __restrict__ a, const float* __restrict__ b,
    const float* __restrict__ c, const float* __restrict__ d, float* __restrict__ o)
{
    size_t i = (size_t)blockIdx.x*256 + threadIdx.x;
    o[i] = a[i] + b[i] + c[i] + d[i];
}

// ---------------- host ----------------
extern "C" void kernel_launch(void* const* d_in, const int* in_sizes, int n_in,
                              void* d_out, int out_size, void* d_ws, size_t ws_size,
                              hipStream_t stream)
{
    const float* x     = (const float*)d_in[0];
    const float* ln1g  = (const float*)d_in[1];
    const float* ln1b  = (const float*)d_in[2];
    const float* ln2g  = (const float*)d_in[3];
    const float* ln2b  = (const float*)d_in[4];
    const float* ln3g  = (const float*)d_in[5];
    const float* ln3b  = (const float*)d_in[6];
    const float* qkvA  = (const float*)d_in[7];
    const float* qkvS  = (const float*)d_in[8];
    const float* qkvb  = (const float*)d_in[9];
    const float* projA = (const float*)d_in[10];
    const float* projS = (const float*)d_in[11];
    const float* projb = (const float*)d_in[12];
    const float* wsup  = (const float*)d_in[13];
    const float* went  = (const float*)d_in[14];
    const float* rA    = (const float*)d_in[15];
    const float* rS    = (const float*)d_in[16];
    const float* rb    = (const float*)d_in[17];
    const float* dr    = (const float*)d_in[18];
    const float* eA    = (const float*)d_in[19];
    const float* eS    = (const float*)d_in[20];
    const float* eb    = (const float*)d_in[21];
    const float* ndw   = (const float*)d_in[22];
    const float* ndb   = (const float*)d_in[23];
    const float* mem0  = (const float*)d_in[24];
    const float* mem1  = (const float*)d_in[25];
    const float* mem2  = (const float*)d_in[26];
    const float* inw   = (const float*)d_in[27];
    const float* inb   = (const float*)d_in[28];
    const float* outw  = (const float*)d_in[29];
    const float* outb  = (const float*)d_in[30];
    const float* pw    = (const float*)d_in[31];
    const float* pb    = (const float*)d_in[32];
    const int*   did   = (const int*)d_in[33];

    float* f = (float*)d_ws;
    size_t off = 0;
    auto alloc = [&](size_t n){ float* p = f + off; off += n; return p; };
    float* Wqkv  = alloc((size_t)QKVC*DIM);
    float* Wproj = alloc((size_t)DIM*DIM);
    float* Wrout = alloc((size_t)NEXP*DIM);
    float* Wexp  = alloc((size_t)NEXP*EDIM*DIM);
    float* lnbuf = alloc((size_t)NTOK*DIM);               // ln1 out, later ln2 out
    float* qkvbuf= alloc((size_t)NTOK*QKVC);              // later gathered X (4096x768 fits)
    float* attnb = alloc((size_t)NBATCH*NHEADS*NSEQ*NSEQ);// later MoE hidden (4096x3072 == same size)
    float* obuf  = alloc((size_t)NTOK*DIM);               // later fractal mha out
    float* attnd = alloc((size_t)NTOK*DIM);
    float* outg  = alloc((size_t)2*NTOK*DIM);             // 4096x768
    float* eo    = alloc((size_t)NTOK*DIM);
    float* qbuf  = alloc((size_t)NTOK*DIM);
    float* kbuf  = alloc((size_t)256*DIM);
    float* vbuf  = alloc((size_t)256*DIM);
    float* a0    = alloc((size_t)NTOK*DIM);
    float* a1    = alloc((size_t)NTOK*DIM);
    float* a2    = alloc((size_t)NTOK*DIM);
    float* topw  = alloc((size_t)2*NTOK);
    int* ip = (int*)(f + off);
    int* topi   = ip; ip += 2*NTOK;
    int* rowof  = ip; ip += 2*NTOK;
    int* tokof  = ip; ip += 2*NTOK;
    int* cnt    = ip; ip += 8;     // cnt2 must follow cnt (zeroed together)
    int* cnt2   = ip; ip += 8;
    int* prefix = ip; ip += 8;
    float* Xg     = qkvbuf;
    float* hidden = attnb;
    float* mhao   = obuf;
    float* outf   = (float*)d_out;

    dim3 T(256);

    k_zero<<<1, 32, 0, stream>>>(cnt, 16);
    k_ln<<<NTOK, T, 0, stream>>>(x, ln1g, ln1b, lnbuf);
    // PHM weight builds
    k_phm<<<dim3((QKVC*DIM+255)/256,1), T, 0, stream>>>(qkvA, qkvS, Wqkv, 576, 192, DIM, 0,0,0);
    k_phm<<<dim3((DIM*DIM+255)/256,1),  T, 0, stream>>>(projA, projS, Wproj, 192, 192, DIM, 0,0,0);
    k_phm<<<dim3((NEXP*DIM+255)/256,1), T, 0, stream>>>(rA, rS, Wrout, 2, 192, DIM, 0,0,0);
    k_phm<<<dim3((EDIM*DIM+255)/256,NEXP), T, 0, stream>>>(eA, eS, Wexp, 768, 192, DIM,
                                                           64L, (long)4*768*192, (long)EDIM*DIM);
    // quantum attention
    k_gemm<<<dim3(32,36), T, 0, stream>>>(lnbuf, DIM, NTOK, Wqkv, DIM, QKVC, DIM, qkvb, nullptr, 0, qkvbuf, QKVC, 1.f, 0);
    k_gemm_qk<<<dim3(8,8,48), T, 0, stream>>>(qkvbuf, attnb);
    k_supent<<<dim3(4096), T, 0, stream>>>(attnb, wsup, went);
    k_softmax<<<dim3(48*NSEQ), dim3(64), 0, stream>>>(attnb);
    k_gemm_av<<<dim3(8,1,48), T, 0, stream>>>(attnb, qkvbuf, obuf);
    k_gemm<<<dim3(32,12), T, 0, stream>>>(obuf, DIM, NTOK, Wproj, DIM, DIM, DIM, projb, x, DIM, attnd, DIM, 1.f, 0);
    // MoE
    k_ln<<<NTOK, T, 0, stream>>>(attnd, ln2g, ln2b, lnbuf);
    k_route<<<NTOK, T, 0, stream>>>(lnbuf, Wrout, rb, dr, did, topi, topw, cnt);
    k_prefix<<<1, 1, 0, stream>>>(cnt, prefix);
    k_assign<<<8, T, 0, stream>>>(topi, prefix, cnt2, rowof, tokof);
    k_gather<<<dim3((4096*DIM)/256), T, 0, stream>>>(lnbuf, tokof, Xg);
    k_gemm_expert<<<dim3(32,48,8), T, 0, stream>>>(Xg, DIM, Wexp, DIM, (long)EDIM*DIM, eb, EDIM,
                                                   prefix, cnt, hidden, EDIM, EDIM, DIM, 1);
    k_gemm_expert<<<dim3(32,12,8), T, 0, stream>>>(hidden, EDIM, ndw, EDIM, (long)DIM*EDIM, ndb, DIM,
                                                   prefix, cnt, outg, DIM, DIM, EDIM, 0);
    k_combine<<<dim3(6144), T, 0, stream>>>(attnd, outg, rowof, topw, eo);
    // fractal memory (3 levels)
    const float* memsp[3] = {mem0, mem1, mem2};
    int Ms[3] = {64, 128, 256};
    float* als[3] = {a0, a1, a2};
    const float* inx = eo;
    for (int l=0; l<3; ++l){
        k_gemm<<<dim3(32,12), T, 0, stream>>>(inx, DIM, NTOK, inw + (size_t)l*QKVC*DIM, DIM, DIM, DIM,
                                              inb + (size_t)l*QKVC, nullptr, 0, qbuf, DIM, 1.f, 0);
        int mt = (Ms[l]+63)/64;
        k_gemm<<<dim3(mt,12), T, 0, stream>>>(memsp[l], DIM, Ms[l], inw + (size_t)l*QKVC*DIM + (size_t)DIM*DIM, DIM, DIM, DIM,
                                              inb + (size_t)l*QKVC + DIM, nullptr, 0, kbuf, DIM, 1.f, 0);
        k_gemm<<<dim3(mt,12), T, 0, stream>>>(memsp[l], DIM, Ms[l], inw + (size_t)l*QKVC*DIM + (size_t)2*DIM*DIM, DIM, DIM, DIM,
                                              inb + (size_t)l*QKVC + 2*DIM, nullptr, 0, vbuf, DIM, 1.f, 0);
        k_memmha<<<dim3(NTOK, MHEADS), T, 0, stream>>>(qbuf, kbuf, vbuf, mhao, Ms[l], 0.10206207261596577f);
        k_gemm<<<dim3(32,12), T, 0, stream>>>(mhao, DIM, NTOK, outw + (size_t)l*DIM*DIM, DIM, DIM, DIM,
                                              outb + (size_t)l*DIM, nullptr, 0, qbuf, DIM, 1.f, 0);
        k_gemm<<<dim3(32,12), T, 0, stream>>>(qbuf, DIM, NTOK, pw + (size_t)l*DIM*DIM, DIM, DIM, DIM,
                                              pb + (size_t)l*DIM, nullptr, 0, als[l], DIM, 1.f, 0);
        inx = als[l];
    }
    k_add4<<<dim3(6144), T, 0, stream>>>(eo, a0, a1, a2, outf);
    k_ln<<<NTOK, T, 0, stream>>>(outf, ln3g, ln3b, outf);
}

// Round 2
// 1989.390 us; speedup vs baseline: 2.2906x; 2.2906x over previous
//
#include <hip/hip_runtime.h>
#include <math.h>

#define DIM    768
#define NTOK   2048
#define NSEQ   512
#define NBATCH 4
#define NHEADS 12
#define HD     64
#define QKVC   2304
#define MHEADS 8
#define MHD    96
#define NEXP   8
#define EDIM   3072

typedef unsigned short u16;
typedef __attribute__((ext_vector_type(8))) short short8;
typedef __attribute__((ext_vector_type(4))) float f32x4;

__device__ __forceinline__ float gelu_exact(float v){
    return 0.5f * v * (1.f + erff(v * 0.70710678118654752f));
}
__device__ __forceinline__ u16 f2bf(float f){
    unsigned int u = __builtin_bit_cast(unsigned int, f);
    unsigned int r = (u + 0x7FFFu + ((u >> 16) & 1u)) >> 16;
    return (u16)r;
}
__device__ __forceinline__ float bf2f(u16 b){
    unsigned int u = ((unsigned int)b) << 16;
    return __builtin_bit_cast(float, u);
}

// ================= MFMA bf16 GEMM core =================
// C[row,col] = act(scale * X@W^T + bias) ; optional fp32 out (+res) and bf16 out (no res).
// X: bf16 [rows x K] stride ldx. W: bf16 [cols x K] stride ldw (i.e. (N,K) row-major).
// Tile 128x128, BK=64, 256 threads = 4 waves (2x2 of 64x64).
__device__ __forceinline__ void mgemm_core(
    const u16* __restrict__ Xb, int ldx, int rowBase, int rowLim,
    const u16* __restrict__ Wb, int ldw, int colBase, int colLim, int K,
    const float* __restrict__ bias,
    const float* __restrict__ res, int ldres,
    float* __restrict__ Cf, u16* __restrict__ Cb, int ldc,
    float scale, int act)
{
    __shared__ u16 As[128*64];
    __shared__ u16 Bs[128*64];
    int tid = threadIdx.x;
    int lane = tid & 63, w = tid >> 6;
    int wm = (w >> 1) * 64, wn = (w & 1) * 64;
    const f32x4 zf = {0.f, 0.f, 0.f, 0.f};
    f32x4 acc[4][4];
    #pragma unroll
    for (int i=0;i<4;i++)
        #pragma unroll
        for (int j=0;j<4;j++) acc[i][j] = zf;

    for (int k0 = 0; k0 < K; k0 += 64) {
        // stage A: 128 rows x 64 k (16KB) = 1024 x 16B chunks, 4 iters
        #pragma unroll
        for (int it = 0; it < 4; ++it) {
            int idx = it*256 + tid;
            int r = idx >> 3, c = idx & 7;
            int gr = rowBase + r;
            uint4 v = {0u,0u,0u,0u};
            if (gr < rowLim) v = *(const uint4*)&Xb[(size_t)gr*ldx + k0 + c*8];
            *(uint4*)&As[r*64 + ((c ^ (r & 7)) * 8)] = v;
        }
        // stage B
        #pragma unroll
        for (int it = 0; it < 4; ++it) {
            int idx = it*256 + tid;
            int r = idx >> 3, c = idx & 7;
            int gc = colBase + r;
            uint4 v = {0u,0u,0u,0u};
            if (gc < colLim) v = *(const uint4*)&Wb[(size_t)gc*ldw + k0 + c*8];
            *(uint4*)&Bs[r*64 + ((c ^ (r & 7)) * 8)] = v;
        }
        __syncthreads();
        int lr = lane & 15, lk = lane >> 4;
        #pragma unroll
        for (int ks = 0; ks < 2; ++ks) {
            short8 af[4], bfr[4];
            #pragma unroll
            for (int mi=0; mi<4; mi++){
                int row = wm + mi*16 + lr;
                int cidx = (ks*4 + lk) ^ (row & 7);
                af[mi] = *(const short8*)&As[row*64 + cidx*8];
            }
            #pragma unroll
            for (int ni=0; ni<4; ni++){
                int col = wn + ni*16 + lr;
                int cidx = (ks*4 + lk) ^ (col & 7);
                bfr[ni] = *(const short8*)&Bs[col*64 + cidx*8];
            }
            #pragma unroll
            for (int mi=0; mi<4; mi++)
                #pragma unroll
                for (int ni=0; ni<4; ni++)
                    acc[mi][ni] = __builtin_amdgcn_mfma_f32_16x16x32_bf16(af[mi], bfr[ni], acc[mi][ni], 0, 0, 0);
        }
        __syncthreads();
    }
    // epilogue: D row = (lane>>4)*4 + reg, col = lane&15  [m89-verified]
    int lr = lane & 15, lg = lane >> 4;
    #pragma unroll
    for (int mi=0; mi<4; mi++){
        #pragma unroll
        for (int r=0; r<4; r++){
            int row = rowBase + wm + mi*16 + lg*4 + r;
            if (row >= rowLim) continue;
            #pragma unroll
            for (int ni=0; ni<4; ni++){
                int col = colBase + wn + ni*16 + lr;
                if (col >= colLim) continue;
                float v = acc[mi][ni][r] * scale;
                if (bias) v += bias[col];
                if (act == 1) v = gelu_exact(v);
                if (Cb) Cb[(size_t)row*ldc + col] = f2bf(v);
                if (res) v += res[(size_t)row*ldres + col];
                if (Cf) Cf[(size_t)row*ldc + col] = v;
            }
        }
    }
}

__global__ __launch_bounds__(256) void k_mgemm(
    const u16* __restrict__ X, int ldx, int M,
    const u16* __restrict__ W, int ldw, int N, int K,
    const float* __restrict__ bias, const float* __restrict__ res, int ldres,
    float* __restrict__ Cf, u16* __restrict__ Cb, int ldc, float scale, int act)
{
    mgemm_core(X, ldx, blockIdx.x*128, M, W, ldw, blockIdx.y*128, N, K,
               bias, res, ldres, Cf, Cb, ldc, scale, act);
}

__global__ __launch_bounds__(256) void k_mgemm_expert(
    const u16* __restrict__ X, int ldx,
    const u16* __restrict__ Wb, int ldw, long wStride,
    const float* __restrict__ biasB, int biasStride,
    const int* __restrict__ prefix, const int* __restrict__ cnt,
    float* __restrict__ Cf, u16* __restrict__ Cb, int ldc, int N, int K, int act)
{
    int e = blockIdx.z;
    int n = cnt[e];
    if ((int)blockIdx.x * 128 >= n) return;
    mgemm_core(X, ldx, prefix[e] + blockIdx.x*128, prefix[e] + n,
               Wb + (size_t)e*wStride, ldw, blockIdx.y*128, N, K,
               biasB + (size_t)e*biasStride, nullptr, 0, Cf, Cb, ldc, 1.f, act);
}

// scores[b,h,n,m] = 0.125 * q_n . k_m
__global__ __launch_bounds__(256) void k_mgemm_qk(const u16* __restrict__ qkv, float* __restrict__ attn)
{
    int z = blockIdx.z, b = z / NHEADS, h = z % NHEADS;
    const u16* X = qkv + (size_t)b*NSEQ*QKVC + h*HD;          // q
    const u16* W = qkv + (size_t)b*NSEQ*QKVC + DIM + h*HD;    // k
    float* C = attn + (size_t)z*NSEQ*NSEQ;
    mgemm_core(X, QKVC, blockIdx.x*128, NSEQ, W, QKVC, blockIdx.y*128, NSEQ, HD,
               nullptr, nullptr, 0, C, nullptr, NSEQ, 0.125f, 0);
}

// o[b,n,h*64+d] = sum_m P[b,h,n,m] * V[b,m,h*64+d]; Vt[b][d][m] supplies W (cols=d, K=m)
__global__ __launch_bounds__(256) void k_mgemm_pv(const u16* __restrict__ P, const u16* __restrict__ Vt, u16* __restrict__ o)
{
    int z = blockIdx.z, b = z / NHEADS, h = z % NHEADS;
    const u16* X = P + (size_t)z*NSEQ*NSEQ;
    const u16* W = Vt + ((size_t)b*DIM + h*HD)*NSEQ;
    u16* C = o + (size_t)b*NSEQ*DIM + h*HD;
    mgemm_core(X, NSEQ, blockIdx.x*128, NSEQ, W, NSEQ, 0, HD, NSEQ,
               nullptr, nullptr, 0, nullptr, C, DIM, 1.f, 0);
}

// ================= PHM weight materialization =================
// W[a*So+c, b*Si+d] = sum_i A[i,a,b]*S[i,c,d]; obf=1 -> bf16 out
__global__ __launch_bounds__(256) void k_phm(
    const float* __restrict__ A, const float* __restrict__ S, void* __restrict__ W,
    int So, int Si, int inF, long Astride, long Sstride, long Wstride, int obf)
{
    int e = blockIdx.y;
    const float* Ae = A + (size_t)e*Astride;
    const float* Se = S + (size_t)e*Sstride;
    size_t idx = (size_t)blockIdx.x*256 + threadIdx.x;
    size_t total = (size_t)(So*4) * inF;
    if (idx >= total) return;
    int in = (int)(idx % inF);
    int o  = (int)(idx / inF);
    int a = o / So, c = o % So, b = in / Si, d = in % Si;
    float w = 0.f;
    #pragma unroll
    for (int i=0;i<4;i++) w = fmaf(Ae[i*16 + a*4 + b], Se[((size_t)i*So + c)*Si + d], w);
    if (obf) ((u16*)W)[(size_t)e*Wstride + idx] = f2bf(w);
    else     ((float*)W)[(size_t)e*Wstride + idx] = w;
}

// ================= fp32 -> bf16 convert =================
__global__ __launch_bounds__(256) void k_cvt(const float* __restrict__ s, u16* __restrict__ d, int n)
{
    for (int i = blockIdx.x*256 + threadIdx.x; i < n; i += gridDim.x*256)
        d[i] = f2bf(s[i]);
}

// ================= LayerNorm (row=768), dual output =================
__global__ __launch_bounds__(256) void k_ln(const float* __restrict__ x, const float* __restrict__ g,
                                            const float* __restrict__ b,
                                            float* __restrict__ yf, u16* __restrict__ yb)
{
    int row = blockIdx.x, tid = threadIdx.x;
    const float* xr = x + (size_t)row * DIM;
    float v0 = xr[tid], v1 = xr[tid+256], v2 = xr[tid+512];
    float s = v0+v1+v2;
    float ss = v0*v0 + v1*v1 + v2*v2;
    for (int off=32; off; off>>=1){ s += __shfl_xor(s,off); ss += __shfl_xor(ss,off); }
    __shared__ float sa[4], sb[4];
    int wid = tid >> 6;
    if ((tid & 63) == 0){ sa[wid]=s; sb[wid]=ss; }
    __syncthreads();
    s  = sa[0]+sa[1]+sa[2]+sa[3];
    ss = sb[0]+sb[1]+sb[2]+sb[3];
    float mean = s * (1.f/DIM);
    float var  = ss * (1.f/DIM) - mean*mean;
    float rstd = rsqrtf(var + 1e-5f);
    float o0 = (v0-mean)*rstd*g[tid]     + b[tid];
    float o1 = (v1-mean)*rstd*g[tid+256] + b[tid+256];
    float o2 = (v2-mean)*rstd*g[tid+512] + b[tid+512];
    if (yf){ float* yr = yf + (size_t)row*DIM; yr[tid]=o0; yr[tid+256]=o1; yr[tid+512]=o2; }
    if (yb){ u16* yr = yb + (size_t)row*DIM; yr[tid]=f2bf(o0); yr[tid+256]=f2bf(o1); yr[tid+512]=f2bf(o2); }
}

// ================= sup/ent head-mixing, in-place fp32 =================
__global__ __launch_bounds__(256) void k_supent(float* __restrict__ attn,
                                                const float* __restrict__ wsup, const float* __restrict__ went)
{
    __shared__ float ws[144], we[144];
    int tid = threadIdx.x;
    if (tid < 144){ ws[tid] = wsup[tid]; we[tid] = went[tid]; }
    __syncthreads();
    size_t idx = (size_t)blockIdx.x*256 + tid;
    int m = idx & 511;
    int n = (int)((idx >> 9) & 511);
    int b = (int)(idx >> 18);
    size_t base = (((size_t)b*NHEADS)*NSEQ + n)*NSEQ + m;
    float av[12], sup[12];
    #pragma unroll
    for (int j=0;j<12;j++) av[j] = attn[base + (size_t)j*NSEQ*NSEQ];
    #pragma unroll
    for (int i=0;i<12;i++){
        float s = 0.f;
        #pragma unroll
        for (int j=0;j<12;j++) s = fmaf(ws[i*12+j], av[j], s);
        sup[i] = s;
    }
    #pragma unroll
    for (int i=0;i<12;i++){
        float s = sup[i];
        #pragma unroll
        for (int j=0;j<12;j++) s = fmaf(we[i*12+j], sup[j], s);
        attn[base + (size_t)i*NSEQ*NSEQ] = tanhf(s);
    }
}

// ================= softmax (row 512) fp32 in -> bf16 out =================
__global__ __launch_bounds__(64) void k_softmax(const float* __restrict__ buf, u16* __restrict__ P)
{
    size_t base = (size_t)blockIdx.x * NSEQ;
    int lane = threadIdx.x;
    float v[8];
    float mx = -1e30f;
    #pragma unroll
    for (int i=0;i<8;i++){ v[i] = buf[base + i*64 + lane]; mx = fmaxf(mx, v[i]); }
    for (int off=32; off; off>>=1) mx = fmaxf(mx, __shfl_xor(mx, off));
    float sum = 0.f;
    #pragma unroll
    for (int i=0;i<8;i++){ v[i] = expf(v[i]-mx); sum += v[i]; }
    for (int off=32; off; off>>=1) sum += __shfl_xor(sum, off);
    float inv = 1.f/sum;
    #pragma unroll
    for (int i=0;i<8;i++) P[base + i*64 + lane] = f2bf(v[i]*inv);
}

// ================= V transpose: Vt[b][d][m] = qkv_bf[b][m][1536+d] =================
__global__ __launch_bounds__(256) void k_transv(const u16* __restrict__ qkv, u16* __restrict__ Vt)
{
    __shared__ u16 L[64][65];
    int mt = blockIdx.x*64, dt = blockIdx.y*64, b = blockIdx.z;
    int tid = threadIdx.x;
    #pragma unroll
    for (int it=0; it<16; ++it){
        int idx = it*256 + tid;
        int mm = idx >> 6, dd = idx & 63;
        L[mm][dd] = qkv[((size_t)b*NSEQ + mt + mm)*QKVC + 3*DIM/3*2 + dt + dd]; // 1536 + ...
    }
    __syncthreads();
    #pragma unroll
    for (int it=0; it<16; ++it){
        int idx = it*256 + tid;
        int dd = idx >> 6, mm = idx & 63;
        Vt[((size_t)b*DIM + dt + dd)*NSEQ + mt + mm] = L[mm][dd];
    }
}

// ================= MoE routing =================
__global__ __launch_bounds__(256) void k_route(
    const float* __restrict__ ln2, const float* __restrict__ Wr,
    const float* __restrict__ rb, const float* __restrict__ dr,
    const int* __restrict__ did, int* __restrict__ topi, float* __restrict__ topw, int* __restrict__ cnt)
{
    int t = blockIdx.x, tid = threadIdx.x;
    const float* xr = ln2 + (size_t)t*DIM;
    float a[8] = {};
    #pragma unroll
    for (int ii=0; ii<3; ii++){
        int i = tid + ii*256;
        float xv = xr[i];
        #pragma unroll
        for (int e=0;e<8;e++) a[e] = fmaf(xv, Wr[e*DIM + i], a[e]);
    }
    #pragma unroll
    for (int e=0;e<8;e++)
        for (int off=32; off; off>>=1) a[e] += __shfl_xor(a[e], off);
    __shared__ float sred[4][8];
    int wid = tid >> 6;
    if ((tid & 63) == 0){
        #pragma unroll
        for (int e=0;e<8;e++) sred[wid][e] = a[e];
    }
    __syncthreads();
    if (tid == 0){
        int d = did[0];
        float lg[8];
        #pragma unroll
        for (int e=0;e<8;e++) lg[e] = sred[0][e]+sred[1][e]+sred[2][e]+sred[3][e] + rb[e] + dr[d*8+e];
        int i1 = 0; float v1 = lg[0];
        #pragma unroll
        for (int e=1;e<8;e++) if (lg[e] > v1){ v1 = lg[e]; i1 = e; }
        int i2 = -1; float v2 = -1e30f;
        #pragma unroll
        for (int e=0;e<8;e++) if (e != i1 && lg[e] > v2){ v2 = lg[e]; i2 = e; }
        float e2 = expf(v2 - v1);
        float inv = 1.f / (1.f + e2);
        topi[2*t] = i1; topi[2*t+1] = i2;
        topw[2*t] = inv; topw[2*t+1] = e2 * inv;
        atomicAdd(&cnt[i1], 1); atomicAdd(&cnt[i2], 1);
    }
}

__global__ void k_zero(int* p, int n){ int i = threadIdx.x; if (i < n) p[i] = 0; }

__global__ void k_prefix(const int* __restrict__ cnt, int* __restrict__ prefix){
    if (threadIdx.x == 0){ int s=0; for (int e=0;e<8;e++){ prefix[e]=s; s+=cnt[e]; } }
}

__global__ __launch_bounds__(256) void k_assign(
    const int* __restrict__ topi, const int* __restrict__ prefix,
    int* __restrict__ cnt2, int* __restrict__ rowof, int* __restrict__ tokof)
{
    int t = blockIdx.x*256 + threadIdx.x;
    if (t >= NTOK) return;
    #pragma unroll
    for (int k=0;k<2;k++){
        int e = topi[2*t+k];
        int slot = atomicAdd(&cnt2[e], 1);
        int row = prefix[e] + slot;
        rowof[2*t+k] = row;
        tokof[row] = t;
    }
}

__global__ __launch_bounds__(256) void k_gather(const u16* __restrict__ src, const int* __restrict__ tokof, u16* __restrict__ dst)
{
    size_t i = (size_t)blockIdx.x*256 + threadIdx.x;
    int row = (int)(i / DIM), c = (int)(i % DIM);
    dst[i] = src[(size_t)tokof[row]*DIM + c];
}

__global__ __launch_bounds__(256) void k_combine(
    const float* __restrict__ att, const float* __restrict__ outg,
    const int* __restrict__ rowof, const float* __restrict__ topw,
    float* __restrict__ eo, u16* __restrict__ eob)
{
    size_t i = (size_t)blockIdx.x*256 + threadIdx.x;
    int t = (int)(i / DIM), c = (int)(i % DIM);
    int r0 = rowof[2*t], r1 = rowof[2*t+1];
    float v = att[i] + topw[2*t]*outg[(size_t)r0*DIM+c] + topw[2*t+1]*outg[(size_t)r1*DIM+c];
    eo[i] = v;
    eob[i] = f2bf(v);
}

// ================= memory-bank MHA (fp32) =================
__global__ __launch_bounds__(256) void k_memmha(
    const float* __restrict__ qb, const float* __restrict__ kb,
    const float* __restrict__ vb, float* __restrict__ ob, int M, float scale)
{
    int t = blockIdx.x, h = blockIdx.y, tid = threadIdx.x;
    __shared__ float q[MHD];
    __shared__ float p[256];
    __shared__ float red[256];
    if (tid < MHD) q[tid] = qb[(size_t)t*DIM + h*MHD + tid];
    __syncthreads();
    float s = -1e30f;
    if (tid < M){
        float acc = 0.f;
        const float* kr = kb + (size_t)tid*DIM + h*MHD;
        #pragma unroll 8
        for (int d=0; d<MHD; ++d) acc = fmaf(q[d], kr[d], acc);
        s = acc * scale;
    }
    red[tid] = s;
    __syncthreads();
    for (int off=128; off>0; off>>=1){ if (tid < off) red[tid] = fmaxf(red[tid], red[tid+off]); __syncthreads(); }
    float mx = red[0];
    __syncthreads();
    float e = (tid < M) ? expf(s - mx) : 0.f;
    p[tid] = e;
    red[tid] = e;
    __syncthreads();
    for (int off=128; off>0; off>>=1){ if (tid < off) red[tid] += red[tid+off]; __syncthreads(); }
    float inv = 1.f / red[0];
    __syncthreads();
    if (tid < MHD){
        float acc = 0.f;
        for (int m=0; m<M; ++m) acc = fmaf(p[m], vb[(size_t)m*DIM + h*MHD + tid], acc);
        ob[(size_t)t*DIM + h*MHD + tid] = acc * inv;
    }
}

// ================= host =================
extern "C" void kernel_launch(void* const* d_in, const int* in_sizes, int n_in,
                              void* d_out, int out_size, void* d_ws, size_t ws_size,
                              hipStream_t stream)
{
    const float* x     = (const float*)d_in[0];
    const float* ln1g  = (const float*)d_in[1];
    const float* ln1b  = (const float*)d_in[2];
    const float* ln2g  = (const float*)d_in[3];
    const float* ln2b  = (const float*)d_in[4];
    const float* ln3g  = (const float*)d_in[5];
    const float* ln3b  = (const float*)d_in[6];
    const float* qkvA  = (const float*)d_in[7];
    const float* qkvS  = (const float*)d_in[8];
    const float* qkvb  = (const float*)d_in[9];
    const float* projA = (const float*)d_in[10];
    const float* projS = (const float*)d_in[11];
    const float* projb = (const float*)d_in[12];
    const float* wsup  = (const float*)d_in[13];
    const float* went  = (const float*)d_in[14];
    const float* rA    = (const float*)d_in[15];
    const float* rS    = (const float*)d_in[16];
    const float* rb    = (const float*)d_in[17];
    const float* dr    = (const float*)d_in[18];
    const float* eA    = (const float*)d_in[19];
    const float* eS    = (const float*)d_in[20];
    const float* eb    = (const float*)d_in[21];
    const float* ndw   = (const float*)d_in[22];
    const float* ndb   = (const float*)d_in[23];
    const float* mem0  = (const float*)d_in[24];
    const float* mem1  = (const float*)d_in[25];
    const float* mem2  = (const float*)d_in[26];
    const float* inw   = (const float*)d_in[27];
    const float* inb   = (const float*)d_in[28];
    const float* outw  = (const float*)d_in[29];
    const float* outb  = (const float*)d_in[30];
    const float* pw    = (const float*)d_in[31];
    const float* pb    = (const float*)d_in[32];
    const int*   did   = (const int*)d_in[33];

    float* f = (float*)d_ws;
    size_t off = 0;
    auto alloc = [&](size_t n){ float* p = f + off; off += (n + 3) & ~(size_t)3; return p; };
    auto allocb = [&](size_t n){ return (u16*)alloc((n + 1) / 2); };

    // fp32 buffers
    float* lnbuf  = alloc((size_t)NTOK*DIM);       // ln2 fp32 (router)
    float* attnd  = alloc((size_t)NTOK*DIM);
    float* eo     = alloc((size_t)NTOK*DIM);
    float* accum  = alloc((size_t)NTOK*DIM);
    float* qbuf_f = alloc((size_t)NTOK*DIM);
    float* kbuf   = alloc((size_t)256*DIM);
    float* vbuf   = alloc((size_t)256*DIM);
    float* mhao   = alloc((size_t)NTOK*DIM);
    float* attnb  = alloc((size_t)48*NSEQ*NSEQ);   // 12.58M floats; hosts outg + ndw_bf later
    float* Wrout  = alloc((size_t)NEXP*DIM);
    float* topw   = alloc((size_t)2*NTOK);
    int* ip = (int*)alloc((size_t)6*NTOK + 64);
    int* topi   = ip;            ip += 2*NTOK;
    int* rowof  = ip;            ip += 2*NTOK;
    int* tokof  = ip;            ip += 2*NTOK;
    int* cnt    = ip;            ip += 8;
    int* cnt2   = ip;            ip += 8;
    int* prefix = ip;            ip += 8;

    // aliases inside attnb (dead after softmax)
    float* outg   = attnb;                               // 4096x768 fp32 = 3.146M floats
    u16*   ndw_bf = (u16*)(attnb + (size_t)3146240);     // 18.87M u16 = 9.44M floats; fits

    // bf16 buffers
    u16* Wqkv_bf  = allocb((size_t)QKVC*DIM);
    u16* Wproj_bf = allocb((size_t)DIM*DIM);
    u16* Wexp_bf  = allocb((size_t)NEXP*EDIM*DIM);
    u16* inw_bf   = allocb((size_t)3*QKVC*DIM);
    u16* outw_bf  = allocb((size_t)3*DIM*DIM);
    u16* pw_bf    = allocb((size_t)3*DIM*DIM);
    u16* mem_bf   = allocb((size_t)448*DIM);
    u16* qkv_bf   = allocb((size_t)NTOK*QKVC);     // hosts Xg_bf later (3.146M <= 4.72M)
    u16* Vt_bf    = allocb((size_t)NBATCH*DIM*NSEQ);
    u16* P_bf     = allocb((size_t)48*NSEQ*NSEQ);  // == hidden_bf (4096x3072) alias, exact size
    u16* lnx_bf   = allocb((size_t)NTOK*DIM);
    u16* o_bf     = allocb((size_t)NTOK*DIM);
    u16* inx_bf   = allocb((size_t)NTOK*DIM);
    u16* mhao_bf  = allocb((size_t)NTOK*DIM);
    u16* qbuf_bf  = allocb((size_t)NTOK*DIM);
    u16* Xg_bf    = qkv_bf;
    u16* hidden_bf= P_bf;

    float* outf = (float*)d_out;
    dim3 T(256);

    k_zero<<<1, 32, 0, stream>>>(cnt, 16);
    k_ln<<<NTOK, T, 0, stream>>>(x, ln1g, ln1b, nullptr, lnx_bf);
    // PHM weight builds (bf16 except router)
    k_phm<<<dim3((QKVC*DIM+255)/256,1), T, 0, stream>>>(qkvA, qkvS, Wqkv_bf, 576, 192, DIM, 0,0,0, 1);
    k_phm<<<dim3((DIM*DIM+255)/256,1),  T, 0, stream>>>(projA, projS, Wproj_bf, 192, 192, DIM, 0,0,0, 1);
    k_phm<<<dim3((NEXP*DIM+255)/256,1), T, 0, stream>>>(rA, rS, Wrout, 2, 192, DIM, 0,0,0, 0);
    k_phm<<<dim3((EDIM*DIM+255)/256,NEXP), T, 0, stream>>>(eA, eS, Wexp_bf, 768, 192, DIM,
                                                           64L, (long)4*768*192, (long)EDIM*DIM, 1);
    // weight converts (fp32 -> bf16), already (N,K) layout
    k_cvt<<<4096, T, 0, stream>>>(inw,  inw_bf,  3*QKVC*DIM);
    k_cvt<<<2048, T, 0, stream>>>(outw, outw_bf, 3*DIM*DIM);
    k_cvt<<<2048, T, 0, stream>>>(pw,   pw_bf,   3*DIM*DIM);
    k_cvt<<<256,  T, 0, stream>>>(mem0, mem_bf,              64*DIM);
    k_cvt<<<256,  T, 0, stream>>>(mem1, mem_bf + 64*DIM,    128*DIM);
    k_cvt<<<512,  T, 0, stream>>>(mem2, mem_bf + 192*DIM,   256*DIM);

    // ---- quantum attention ----
    k_mgemm<<<dim3(16,18), T, 0, stream>>>(lnx_bf, DIM, NTOK, Wqkv_bf, DIM, QKVC, DIM,
                                           qkvb, nullptr, 0, nullptr, qkv_bf, QKVC, 1.f, 0);
    k_transv<<<dim3(8,12,NBATCH), T, 0, stream>>>(qkv_bf, Vt_bf);
    k_mgemm_qk<<<dim3(4,4,48), T, 0, stream>>>(qkv_bf, attnb);
    k_supent<<<dim3(4096), T, 0, stream>>>(attnb, wsup, went);
    k_softmax<<<dim3(48*NSEQ), dim3(64), 0, stream>>>(attnb, P_bf);
    k_cvt<<<4096, T, 0, stream>>>(ndw, ndw_bf, NEXP*DIM*EDIM);   // after softmax: attnb region reusable
    k_mgemm_pv<<<dim3(4,1,48), T, 0, stream>>>(P_bf, Vt_bf, o_bf);
    k_mgemm<<<dim3(16,6), T, 0, stream>>>(o_bf, DIM, NTOK, Wproj_bf, DIM, DIM, DIM,
                                          projb, x, DIM, attnd, nullptr, DIM, 1.f, 0);
    // ---- MoE ----
    k_ln<<<NTOK, T, 0, stream>>>(attnd, ln2g, ln2b, lnbuf, lnx_bf);
    k_route<<<NTOK, T, 0, stream>>>(lnbuf, Wrout, rb, dr, did, topi, topw, cnt);
    k_prefix<<<1, 1, 0, stream>>>(cnt, prefix);
    k_assign<<<8, T, 0, stream>>>(topi, prefix, cnt2, rowof, tokof);
    k_gather<<<dim3((4096*DIM)/256), T, 0, stream>>>(lnx_bf, tokof, Xg_bf);
    k_mgemm_expert<<<dim3(16,24,NEXP), T, 0, stream>>>(Xg_bf, DIM, Wexp_bf, DIM, (long)EDIM*DIM,
                                                       eb, EDIM, prefix, cnt,
                                                       nullptr, hidden_bf, EDIM, EDIM, DIM, 1);
    k_mgemm_expert<<<dim3(16,6,NEXP), T, 0, stream>>>(hidden_bf, EDIM, ndw_bf, EDIM, (long)DIM*EDIM,
                                                      ndb, DIM, prefix, cnt,
                                                      outg, nullptr, DIM, DIM, EDIM, 0);
    k_combine<<<dim3(6144), T, 0, stream>>>(attnd, outg, rowof, topw, eo, inx_bf);
    // ---- fractal memory (3 levels) ----
    int Ms[3] = {64, 128, 256};
    long moff[3] = {0, 64L*DIM, 192L*DIM};
    for (int l=0; l<3; ++l){
        const u16* iwl = inw_bf + (size_t)l*QKVC*DIM;
        k_mgemm<<<dim3(16,6), T, 0, stream>>>(inx_bf, DIM, NTOK, iwl, DIM, DIM, DIM,
                                              inb + (size_t)l*QKVC, nullptr, 0, qbuf_f, nullptr, DIM, 1.f, 0);
        int mt = (Ms[l]+127)/128;
        k_mgemm<<<dim3(mt,6), T, 0, stream>>>(mem_bf + moff[l], DIM, Ms[l], iwl + (size_t)DIM*DIM, DIM, DIM, DIM,
                                              inb + (size_t)l*QKVC + DIM, nullptr, 0, kbuf, nullptr, DIM, 1.f, 0);
        k_mgemm<<<dim3(mt,6), T, 0, stream>>>(mem_bf + moff[l], DIM, Ms[l], iwl + (size_t)2*DIM*DIM, DIM, DIM, DIM,
                                              inb + (size_t)l*QKVC + 2*DIM, nullptr, 0, vbuf, nullptr, DIM, 1.f, 0);
        k_memmha<<<dim3(NTOK, MHEADS), T, 0, stream>>>(qbuf_f, kbuf, vbuf, mhao, Ms[l], 0.10206207261596577f);
        k_cvt<<<2048, T, 0, stream>>>(mhao, mhao_bf, NTOK*DIM);
        k_mgemm<<<dim3(16,6), T, 0, stream>>>(mhao_bf, DIM, NTOK, outw_bf + (size_t)l*DIM*DIM, DIM, DIM, DIM,
                                              outb + (size_t)l*DIM, nullptr, 0, nullptr, qbuf_bf, DIM, 1.f, 0);
        k_mgemm<<<dim3(16,6), T, 0, stream>>>(qbuf_bf, DIM, NTOK, pw_bf + (size_t)l*DIM*DIM, DIM, DIM, DIM,
                                              pb + (size_t)l*DIM, (l==0 ? eo : accum), DIM,
                                              accum, inx_bf, DIM, 1.f, 0);
    }
    k_ln<<<NTOK, T, 0, stream>>>(accum, ln3g, ln3b, outf, nullptr);
}

// Round 3
// 1600.774 us; speedup vs baseline: 2.8467x; 1.2428x over previous
//
#include <hip/hip_runtime.h>
#include <math.h>

#define DIM    768
#define NTOK   2048
#define NSEQ   512
#define NBATCH 4
#define NHEADS 12
#define HD     64
#define QKVC   2304
#define MHEADS 8
#define MHD    96
#define NEXP   8
#define EDIM   3072

typedef unsigned short u16;
typedef __attribute__((ext_vector_type(8))) short short8;
typedef __attribute__((ext_vector_type(4))) float f32x4;

__device__ __forceinline__ float gelu_exact(float v){
    return 0.5f * v * (1.f + erff(v * 0.70710678118654752f));
}
__device__ __forceinline__ u16 f2bf(float f){
    unsigned int u = __builtin_bit_cast(unsigned int, f);
    unsigned int r = (u + 0x7FFFu + ((u >> 16) & 1u)) >> 16;
    return (u16)r;
}

// ================= MFMA bf16 GEMM core =================
// C[row,col] = act(scale * X@W^T + bias) ; optional fp32 out (+res) and bf16 out.
// X: bf16 [rows x K] stride ldx. W: bf16 [cols x K] stride ldw ((N,K) row-major).
// Tile 128x128, BK=64, 256 threads = 4 waves (2x2 of 64x64). K must be mult of 8.
__device__ __forceinline__ void mgemm_core(
    const u16* __restrict__ Xb, int ldx, int rowBase, int rowLim,
    const u16* __restrict__ Wb, int ldw, int colBase, int colLim, int K,
    const float* __restrict__ bias,
    const float* __restrict__ res, int ldres,
    float* __restrict__ Cf, u16* __restrict__ Cb, int ldc,
    float scale, int act)
{
    __shared__ u16 As[128*64];
    __shared__ u16 Bs[128*64];
    int tid = threadIdx.x;
    int lane = tid & 63, w = tid >> 6;
    int wm = (w >> 1) * 64, wn = (w & 1) * 64;
    const f32x4 zf = {0.f, 0.f, 0.f, 0.f};
    f32x4 acc[4][4];
    #pragma unroll
    for (int i=0;i<4;i++)
        #pragma unroll
        for (int j=0;j<4;j++) acc[i][j] = zf;

    for (int k0 = 0; k0 < K; k0 += 64) {
        // stage A: 128 rows x 64 k (16KB); K-tail chunks zero-padded
        #pragma unroll
        for (int it = 0; it < 4; ++it) {
            int idx = it*256 + tid;
            int r = idx >> 3, c = idx & 7;
            int gr = rowBase + r;
            uint4 v = {0u,0u,0u,0u};
            if (gr < rowLim && (k0 + c*8) < K) v = *(const uint4*)&Xb[(size_t)gr*ldx + k0 + c*8];
            *(uint4*)&As[r*64 + ((c ^ (r & 7)) * 8)] = v;
        }
        // stage B
        #pragma unroll
        for (int it = 0; it < 4; ++it) {
            int idx = it*256 + tid;
            int r = idx >> 3, c = idx & 7;
            int gc = colBase + r;
            uint4 v = {0u,0u,0u,0u};
            if (gc < colLim && (k0 + c*8) < K) v = *(const uint4*)&Wb[(size_t)gc*ldw + k0 + c*8];
            *(uint4*)&Bs[r*64 + ((c ^ (r & 7)) * 8)] = v;
        }
        __syncthreads();
        int lr = lane & 15, lk = lane >> 4;
        #pragma unroll
        for (int ks = 0; ks < 2; ++ks) {
            short8 af[4], bfr[4];
            #pragma unroll
            for (int mi=0; mi<4; mi++){
                int row = wm + mi*16 + lr;
                int cidx = (ks*4 + lk) ^ (row & 7);
                af[mi] = *(const short8*)&As[row*64 + cidx*8];
            }
            #pragma unroll
            for (int ni=0; ni<4; ni++){
                int col = wn + ni*16 + lr;
                int cidx = (ks*4 + lk) ^ (col & 7);
                bfr[ni] = *(const short8*)&Bs[col*64 + cidx*8];
            }
            #pragma unroll
            for (int mi=0; mi<4; mi++)
                #pragma unroll
                for (int ni=0; ni<4; ni++)
                    acc[mi][ni] = __builtin_amdgcn_mfma_f32_16x16x32_bf16(af[mi], bfr[ni], acc[mi][ni], 0, 0, 0);
        }
        __syncthreads();
    }
    // epilogue: D row = (lane>>4)*4 + reg, col = lane&15  [m89-verified]
    int lr = lane & 15, lg = lane >> 4;
    #pragma unroll
    for (int mi=0; mi<4; mi++){
        #pragma unroll
        for (int r=0; r<4; r++){
            int row = rowBase + wm + mi*16 + lg*4 + r;
            if (row >= rowLim) continue;
            #pragma unroll
            for (int ni=0; ni<4; ni++){
                int col = colBase + wn + ni*16 + lr;
                if (col >= colLim) continue;
                float v = acc[mi][ni][r] * scale;
                if (bias) v += bias[col];
                if (act == 1) v = gelu_exact(v);
                if (Cb) Cb[(size_t)row*ldc + col] = f2bf(v);
                if (res) v += res[(size_t)row*ldres + col];
                if (Cf) Cf[(size_t)row*ldc + col] = v;
            }
        }
    }
}

__global__ __launch_bounds__(256) void k_mgemm(
    const u16* __restrict__ X, int ldx, int M,
    const u16* __restrict__ W, int ldw, int N, int K,
    const float* __restrict__ bias, const float* __restrict__ res, int ldres,
    float* __restrict__ Cf, u16* __restrict__ Cb, int ldc, float scale, int act)
{
    mgemm_core(X, ldx, blockIdx.x*128, M, W, ldw, blockIdx.y*128, N, K,
               bias, res, ldres, Cf, Cb, ldc, scale, act);
}

__global__ __launch_bounds__(256) void k_mgemm_expert(
    const u16* __restrict__ X, int ldx,
    const u16* __restrict__ Wb, int ldw, long wStride,
    const float* __restrict__ biasB, int biasStride,
    const int* __restrict__ prefix, const int* __restrict__ cnt,
    float* __restrict__ Cf, u16* __restrict__ Cb, int ldc, int N, int K, int act)
{
    int e = blockIdx.z;
    int n = cnt[e];
    if ((int)blockIdx.x * 128 >= n) return;
    mgemm_core(X, ldx, prefix[e] + blockIdx.x*128, prefix[e] + n,
               Wb + (size_t)e*wStride, ldw, blockIdx.y*128, N, K,
               biasB + (size_t)e*biasStride, nullptr, 0, Cf, Cb, ldc, 1.f, act);
}

// scores[b,h,n,m] = 0.125 * q_n . k_m
__global__ __launch_bounds__(256) void k_mgemm_qk(const u16* __restrict__ qkv, float* __restrict__ attn)
{
    int z = blockIdx.z, b = z / NHEADS, h = z % NHEADS;
    const u16* X = qkv + (size_t)b*NSEQ*QKVC + h*HD;          // q
    const u16* W = qkv + (size_t)b*NSEQ*QKVC + DIM + h*HD;    // k
    float* C = attn + (size_t)z*NSEQ*NSEQ;
    mgemm_core(X, QKVC, blockIdx.x*128, NSEQ, W, QKVC, blockIdx.y*128, NSEQ, HD,
               nullptr, nullptr, 0, C, nullptr, NSEQ, 0.125f, 0);
}

// o[b,n,h*64+d] = sum_m P[b,h,n,m] * V[b,m,h*64+d]; Vt[b][d][m] supplies W
__global__ __launch_bounds__(256) void k_mgemm_pv(const u16* __restrict__ P, const u16* __restrict__ Vt, u16* __restrict__ o)
{
    int z = blockIdx.z, b = z / NHEADS, h = z % NHEADS;
    const u16* X = P + (size_t)z*NSEQ*NSEQ;
    const u16* W = Vt + ((size_t)b*DIM + h*HD)*NSEQ;
    u16* C = o + (size_t)b*NSEQ*DIM + h*HD;
    mgemm_core(X, NSEQ, blockIdx.x*128, NSEQ, W, NSEQ, 0, HD, NSEQ,
               nullptr, nullptr, 0, nullptr, C, DIM, 1.f, 0);
}

// mem-MHA scores: S[h][n][m] = scale * q[n, h*96:..] . k[m, h*96:..]   (K=96)
__global__ __launch_bounds__(256) void k_mgemm_memqk(const u16* __restrict__ q, const u16* __restrict__ k,
                                                     float* __restrict__ S, int M, float scale)
{
    int h = blockIdx.z;
    mgemm_core(q + h*MHD, DIM, blockIdx.x*128, NTOK, k + h*MHD, DIM, blockIdx.y*128, M, MHD,
               nullptr, nullptr, 0, S + (size_t)h*NTOK*M, nullptr, M, scale, 0);
}

// mem-MHA PV: O[n, h*96+d] = sum_m P[h][n][m] * Vt[h*96+d][m]
__global__ __launch_bounds__(256) void k_mgemm_mempv(const u16* __restrict__ P, const u16* __restrict__ Vt,
                                                     u16* __restrict__ O, int M)
{
    int h = blockIdx.z;
    mgemm_core(P + (size_t)h*NTOK*M, M, blockIdx.x*128, NTOK, Vt + (size_t)h*MHD*M, M, 0, MHD, M,
               nullptr, nullptr, 0, nullptr, O + h*MHD, DIM, 1.f, 0);
}

// Vt[d][m] = v[m][d]  (d covers all heads: 768)
__global__ __launch_bounds__(256) void k_transvm(const u16* __restrict__ v, u16* __restrict__ Vt, int M)
{
    int idx = blockIdx.x*256 + threadIdx.x;
    if (idx >= DIM*M) return;
    int m = idx / DIM, d = idx % DIM;
    Vt[(size_t)d*M + m] = v[(size_t)m*DIM + d];
}

// softmax over row of length M (<=256), fp32 in -> bf16 out
__global__ __launch_bounds__(64) void k_softmax_mem(const float* __restrict__ S, u16* __restrict__ P, int M)
{
    size_t base = (size_t)blockIdx.x * M;
    int lane = threadIdx.x;
    float mx = -1e30f;
    for (int i = lane; i < M; i += 64) mx = fmaxf(mx, S[base+i]);
    for (int off=32; off; off>>=1) mx = fmaxf(mx, __shfl_xor(mx, off));
    float sum = 0.f;
    for (int i = lane; i < M; i += 64) sum += expf(S[base+i]-mx);
    for (int off=32; off; off>>=1) sum += __shfl_xor(sum, off);
    float inv = 1.f/sum;
    for (int i = lane; i < M; i += 64) P[base+i] = f2bf(expf(S[base+i]-mx)*inv);
}

// ================= PHM weight materialization =================
__global__ __launch_bounds__(256) void k_phm(
    const float* __restrict__ A, const float* __restrict__ S, void* __restrict__ W,
    int So, int Si, int inF, long Astride, long Sstride, long Wstride, int obf)
{
    int e = blockIdx.y;
    const float* Ae = A + (size_t)e*Astride;
    const float* Se = S + (size_t)e*Sstride;
    size_t idx = (size_t)blockIdx.x*256 + threadIdx.x;
    size_t total = (size_t)(So*4) * inF;
    if (idx >= total) return;
    int in = (int)(idx % inF);
    int o  = (int)(idx / inF);
    int a = o / So, c = o % So, b = in / Si, d = in % Si;
    float w = 0.f;
    #pragma unroll
    for (int i=0;i<4;i++) w = fmaf(Ae[i*16 + a*4 + b], Se[((size_t)i*So + c)*Si + d], w);
    if (obf) ((u16*)W)[(size_t)e*Wstride + idx] = f2bf(w);
    else     ((float*)W)[(size_t)e*Wstride + idx] = w;
}

// ================= fp32 -> bf16 convert =================
__global__ __launch_bounds__(256) void k_cvt(const float* __restrict__ s, u16* __restrict__ d, int n)
{
    for (int i = blockIdx.x*256 + threadIdx.x; i < n; i += gridDim.x*256)
        d[i] = f2bf(s[i]);
}

// ================= LayerNorm (row=768), dual output =================
__global__ __launch_bounds__(256) void k_ln(const float* __restrict__ x, const float* __restrict__ g,
                                            const float* __restrict__ b,
                                            float* __restrict__ yf, u16* __restrict__ yb)
{
    int row = blockIdx.x, tid = threadIdx.x;
    const float* xr = x + (size_t)row * DIM;
    float v0 = xr[tid], v1 = xr[tid+256], v2 = xr[tid+512];
    float s = v0+v1+v2;
    float ss = v0*v0 + v1*v1 + v2*v2;
    for (int off=32; off; off>>=1){ s += __shfl_xor(s,off); ss += __shfl_xor(ss,off); }
    __shared__ float sa[4], sb[4];
    int wid = tid >> 6;
    if ((tid & 63) == 0){ sa[wid]=s; sb[wid]=ss; }
    __syncthreads();
    s  = sa[0]+sa[1]+sa[2]+sa[3];
    ss = sb[0]+sb[1]+sb[2]+sb[3];
    float mean = s * (1.f/DIM);
    float var  = ss * (1.f/DIM) - mean*mean;
    float rstd = rsqrtf(var + 1e-5f);
    float o0 = (v0-mean)*rstd*g[tid]     + b[tid];
    float o1 = (v1-mean)*rstd*g[tid+256] + b[tid+256];
    float o2 = (v2-mean)*rstd*g[tid+512] + b[tid+512];
    if (yf){ float* yr = yf + (size_t)row*DIM; yr[tid]=o0; yr[tid+256]=o1; yr[tid+512]=o2; }
    if (yb){ u16* yr = yb + (size_t)row*DIM; yr[tid]=f2bf(o0); yr[tid+256]=f2bf(o1); yr[tid+512]=f2bf(o2); }
}

// ================= sup/ent head-mixing, in-place fp32 =================
__global__ __launch_bounds__(256) void k_supent(float* __restrict__ attn,
                                                const float* __restrict__ wsup, const float* __restrict__ went)
{
    __shared__ float ws[144], we[144];
    int tid = threadIdx.x;
    if (tid < 144){ ws[tid] = wsup[tid]; we[tid] = went[tid]; }
    __syncthreads();
    size_t idx = (size_t)blockIdx.x*256 + tid;
    int m = idx & 511;
    int n = (int)((idx >> 9) & 511);
    int b = (int)(idx >> 18);
    size_t base = (((size_t)b*NHEADS)*NSEQ + n)*NSEQ + m;
    float av[12], sup[12];
    #pragma unroll
    for (int j=0;j<12;j++) av[j] = attn[base + (size_t)j*NSEQ*NSEQ];
    #pragma unroll
    for (int i=0;i<12;i++){
        float s = 0.f;
        #pragma unroll
        for (int j=0;j<12;j++) s = fmaf(ws[i*12+j], av[j], s);
        sup[i] = s;
    }
    #pragma unroll
    for (int i=0;i<12;i++){
        float s = sup[i];
        #pragma unroll
        for (int j=0;j<12;j++) s = fmaf(we[i*12+j], sup[j], s);
        attn[base + (size_t)i*NSEQ*NSEQ] = tanhf(s);
    }
}

// ================= softmax (row 512) fp32 in -> bf16 out =================
__global__ __launch_bounds__(64) void k_softmax(const float* __restrict__ buf, u16* __restrict__ P)
{
    size_t base = (size_t)blockIdx.x * NSEQ;
    int lane = threadIdx.x;
    float v[8];
    float mx = -1e30f;
    #pragma unroll
    for (int i=0;i<8;i++){ v[i] = buf[base + i*64 + lane]; mx = fmaxf(mx, v[i]); }
    for (int off=32; off; off>>=1) mx = fmaxf(mx, __shfl_xor(mx, off));
    float sum = 0.f;
    #pragma unroll
    for (int i=0;i<8;i++){ v[i] = expf(v[i]-mx); sum += v[i]; }
    for (int off=32; off; off>>=1) sum += __shfl_xor(sum, off);
    float inv = 1.f/sum;
    #pragma unroll
    for (int i=0;i<8;i++) P[base + i*64 + lane] = f2bf(v[i]*inv);
}

// ================= V transpose (main attn): Vt[b][d][m] = qkv_bf[b][m][1536+d] =================
__global__ __launch_bounds__(256) void k_transv(const u16* __restrict__ qkv, u16* __restrict__ Vt)
{
    __shared__ u16 L[64][65];
    int mt = blockIdx.x*64, dt = blockIdx.y*64, b = blockIdx.z;
    int tid = threadIdx.x;
    #pragma unroll
    for (int it=0; it<16; ++it){
        int idx = it*256 + tid;
        int mm = idx >> 6, dd = idx & 63;
        L[mm][dd] = qkv[((size_t)b*NSEQ + mt + mm)*QKVC + 1536 + dt + dd];
    }
    __syncthreads();
    #pragma unroll
    for (int it=0; it<16; ++it){
        int idx = it*256 + tid;
        int dd = idx >> 6, mm = idx & 63;
        Vt[((size_t)b*DIM + dt + dd)*NSEQ + mt + mm] = L[mm][dd];
    }
}

// ================= MoE routing =================
__global__ __launch_bounds__(256) void k_route(
    const float* __restrict__ ln2, const float* __restrict__ Wr,
    const float* __restrict__ rb, const float* __restrict__ dr,
    const int* __restrict__ did, int* __restrict__ topi, float* __restrict__ topw, int* __restrict__ cnt)
{
    int t = blockIdx.x, tid = threadIdx.x;
    const float* xr = ln2 + (size_t)t*DIM;
    float a[8] = {};
    #pragma unroll
    for (int ii=0; ii<3; ii++){
        int i = tid + ii*256;
        float xv = xr[i];
        #pragma unroll
        for (int e=0;e<8;e++) a[e] = fmaf(xv, Wr[e*DIM + i], a[e]);
    }
    #pragma unroll
    for (int e=0;e<8;e++)
        for (int off=32; off; off>>=1) a[e] += __shfl_xor(a[e], off);
    __shared__ float sred[4][8];
    int wid = tid >> 6;
    if ((tid & 63) == 0){
        #pragma unroll
        for (int e=0;e<8;e++) sred[wid][e] = a[e];
    }
    __syncthreads();
    if (tid == 0){
        int d = did[0];
        float lg[8];
        #pragma unroll
        for (int e=0;e<8;e++) lg[e] = sred[0][e]+sred[1][e]+sred[2][e]+sred[3][e] + rb[e] + dr[d*8+e];
        int i1 = 0; float v1 = lg[0];
        #pragma unroll
        for (int e=1;e<8;e++) if (lg[e] > v1){ v1 = lg[e]; i1 = e; }
        int i2 = -1; float v2 = -1e30f;
        #pragma unroll
        for (int e=0;e<8;e++) if (e != i1 && lg[e] > v2){ v2 = lg[e]; i2 = e; }
        float e2 = expf(v2 - v1);
        float inv = 1.f / (1.f + e2);
        topi[2*t] = i1; topi[2*t+1] = i2;
        topw[2*t] = inv; topw[2*t+1] = e2 * inv;
        atomicAdd(&cnt[i1], 1); atomicAdd(&cnt[i2], 1);
    }
}

__global__ void k_zero(int* p, int n){ int i = threadIdx.x; if (i < n) p[i] = 0; }

__global__ void k_prefix(const int* __restrict__ cnt, int* __restrict__ prefix){
    if (threadIdx.x == 0){ int s=0; for (int e=0;e<8;e++){ prefix[e]=s; s+=cnt[e]; } }
}

__global__ __launch_bounds__(256) void k_assign(
    const int* __restrict__ topi, const int* __restrict__ prefix,
    int* __restrict__ cnt2, int* __restrict__ rowof, int* __restrict__ tokof)
{
    int t = blockIdx.x*256 + threadIdx.x;
    if (t >= NTOK) return;
    #pragma unroll
    for (int k=0;k<2;k++){
        int e = topi[2*t+k];
        int slot = atomicAdd(&cnt2[e], 1);
        int row = prefix[e] + slot;
        rowof[2*t+k] = row;
        tokof[row] = t;
    }
}

__global__ __launch_bounds__(256) void k_gather(const u16* __restrict__ src, const int* __restrict__ tokof, u16* __restrict__ dst)
{
    size_t i = (size_t)blockIdx.x*256 + threadIdx.x;
    int row = (int)(i / DIM), c = (int)(i % DIM);
    dst[i] = src[(size_t)tokof[row]*DIM + c];
}

__global__ __launch_bounds__(256) void k_combine(
    const float* __restrict__ att, const float* __restrict__ outg,
    const int* __restrict__ rowof, const float* __restrict__ topw,
    float* __restrict__ eo, u16* __restrict__ eob)
{
    size_t i = (size_t)blockIdx.x*256 + threadIdx.x;
    int t = (int)(i / DIM), c = (int)(i % DIM);
    int r0 = rowof[2*t], r1 = rowof[2*t+1];
    float v = att[i] + topw[2*t]*outg[(size_t)r0*DIM+c] + topw[2*t+1]*outg[(size_t)r1*DIM+c];
    eo[i] = v;
    eob[i] = f2bf(v);
}

// ================= host =================
extern "C" void kernel_launch(void* const* d_in, const int* in_sizes, int n_in,
                              void* d_out, int out_size, void* d_ws, size_t ws_size,
                              hipStream_t stream)
{
    const float* x     = (const float*)d_in[0];
    const float* ln1g  = (const float*)d_in[1];
    const float* ln1b  = (const float*)d_in[2];
    const float* ln2g  = (const float*)d_in[3];
    const float* ln2b  = (const float*)d_in[4];
    const float* ln3g  = (const float*)d_in[5];
    const float* ln3b  = (const float*)d_in[6];
    const float* qkvA  = (const float*)d_in[7];
    const float* qkvS  = (const float*)d_in[8];
    const float* qkvb  = (const float*)d_in[9];
    const float* projA = (const float*)d_in[10];
    const float* projS = (const float*)d_in[11];
    const float* projb = (const float*)d_in[12];
    const float* wsup  = (const float*)d_in[13];
    const float* went  = (const float*)d_in[14];
    const float* rA    = (const float*)d_in[15];
    const float* rS    = (const float*)d_in[16];
    const float* rb    = (const float*)d_in[17];
    const float* dr    = (const float*)d_in[18];
    const float* eA    = (const float*)d_in[19];
    const float* eS    = (const float*)d_in[20];
    const float* eb    = (const float*)d_in[21];
    const float* ndw   = (const float*)d_in[22];
    const float* ndb   = (const float*)d_in[23];
    const float* mem0  = (const float*)d_in[24];
    const float* mem1  = (const float*)d_in[25];
    const float* mem2  = (const float*)d_in[26];
    const float* inw   = (const float*)d_in[27];
    const float* inb   = (const float*)d_in[28];
    const float* outw  = (const float*)d_in[29];
    const float* outb  = (const float*)d_in[30];
    const float* pw    = (const float*)d_in[31];
    const float* pb    = (const float*)d_in[32];
    const int*   did   = (const int*)d_in[33];

    float* f = (float*)d_ws;
    size_t off = 0;
    auto alloc = [&](size_t n){ float* p = f + off; off += (n + 3) & ~(size_t)3; return p; };
    auto allocb = [&](size_t n){ return (u16*)alloc((n + 1) / 2); };

    // fp32 buffers
    float* lnbuf  = alloc((size_t)NTOK*DIM);       // ln2 fp32 (router)
    float* attnd  = alloc((size_t)NTOK*DIM);
    float* eo     = alloc((size_t)NTOK*DIM);
    float* accum  = alloc((size_t)NTOK*DIM);
    float* attnb  = alloc((size_t)48*NSEQ*NSEQ);   // scores; hosts outg + ndw_bf; later Smem
    float* Wrout  = alloc((size_t)NEXP*DIM);
    float* topw   = alloc((size_t)2*NTOK);
    int* ip = (int*)alloc((size_t)6*NTOK + 64);
    int* topi   = ip;            ip += 2*NTOK;
    int* rowof  = ip;            ip += 2*NTOK;
    int* tokof  = ip;            ip += 2*NTOK;
    int* cnt    = ip;            ip += 8;
    int* cnt2   = ip;            ip += 8;
    int* prefix = ip;            ip += 8;

    // aliases inside attnb
    float* outg   = attnb;                               // 4096x768 fp32
    u16*   ndw_bf = (u16*)(attnb + (size_t)3146240);     // 18.87M u16
    float* Smem   = attnb;                               // fractal-phase scores (<=4.2M floats)

    // bf16 buffers
    u16* Wqkv_bf  = allocb((size_t)QKVC*DIM);
    u16* Wproj_bf = allocb((size_t)DIM*DIM);
    u16* Wexp_bf  = allocb((size_t)NEXP*EDIM*DIM);
    u16* inw_bf   = allocb((size_t)3*QKVC*DIM);
    u16* outw_bf  = allocb((size_t)3*DIM*DIM);
    u16* pw_bf    = allocb((size_t)3*DIM*DIM);
    u16* mem_bf   = allocb((size_t)448*DIM);
    u16* qkv_bf   = allocb((size_t)NTOK*QKVC);     // hosts Xg_bf later
    u16* Vt_bf    = allocb((size_t)NBATCH*DIM*NSEQ);
    u16* P_bf     = allocb((size_t)48*NSEQ*NSEQ);  // also hidden_bf, later Pm_bf
    u16* lnx_bf   = allocb((size_t)NTOK*DIM);
    u16* o_bf     = allocb((size_t)NTOK*DIM);      // attn out; later qm_bf
    u16* inx_bf   = allocb((size_t)NTOK*DIM);
    u16* mhao_bf  = allocb((size_t)NTOK*DIM);
    u16* qbuf_bf  = allocb((size_t)NTOK*DIM);
    u16* km_bf    = allocb((size_t)256*DIM);
    u16* vm_bf    = allocb((size_t)256*DIM);
    u16* Vtm_bf   = allocb((size_t)MHEADS*MHD*256);
    u16* Xg_bf    = qkv_bf;
    u16* hidden_bf= P_bf;
    u16* Pm_bf    = P_bf;
    u16* qm_bf    = o_bf;

    float* outf = (float*)d_out;
    dim3 T(256);

    k_zero<<<1, 32, 0, stream>>>(cnt, 16);
    k_ln<<<NTOK, T, 0, stream>>>(x, ln1g, ln1b, nullptr, lnx_bf);
    // PHM weight builds (bf16 except router)
    k_phm<<<dim3((QKVC*DIM+255)/256,1), T, 0, stream>>>(qkvA, qkvS, Wqkv_bf, 576, 192, DIM, 0,0,0, 1);
    k_phm<<<dim3((DIM*DIM+255)/256,1),  T, 0, stream>>>(projA, projS, Wproj_bf, 192, 192, DIM, 0,0,0, 1);
    k_phm<<<dim3((NEXP*DIM+255)/256,1), T, 0, stream>>>(rA, rS, Wrout, 2, 192, DIM, 0,0,0, 0);
    k_phm<<<dim3((EDIM*DIM+255)/256,NEXP), T, 0, stream>>>(eA, eS, Wexp_bf, 768, 192, DIM,
                                                           64L, (long)4*768*192, (long)EDIM*DIM, 1);
    // weight converts (fp32 -> bf16), already (N,K) layout
    k_cvt<<<4096, T, 0, stream>>>(inw,  inw_bf,  3*QKVC*DIM);
    k_cvt<<<2048, T, 0, stream>>>(outw, outw_bf, 3*DIM*DIM);
    k_cvt<<<2048, T, 0, stream>>>(pw,   pw_bf,   3*DIM*DIM);
    k_cvt<<<256,  T, 0, stream>>>(mem0, mem_bf,              64*DIM);
    k_cvt<<<256,  T, 0, stream>>>(mem1, mem_bf + 64*DIM,    128*DIM);
    k_cvt<<<512,  T, 0, stream>>>(mem2, mem_bf + 192*DIM,   256*DIM);

    // ---- quantum attention ----
    k_mgemm<<<dim3(16,18), T, 0, stream>>>(lnx_bf, DIM, NTOK, Wqkv_bf, DIM, QKVC, DIM,
                                           qkvb, nullptr, 0, nullptr, qkv_bf, QKVC, 1.f, 0);
    k_transv<<<dim3(8,12,NBATCH), T, 0, stream>>>(qkv_bf, Vt_bf);
    k_mgemm_qk<<<dim3(4,4,48), T, 0, stream>>>(qkv_bf, attnb);
    k_supent<<<dim3(4096), T, 0, stream>>>(attnb, wsup, went);
    k_softmax<<<dim3(48*NSEQ), dim3(64), 0, stream>>>(attnb, P_bf);
    k_cvt<<<4096, T, 0, stream>>>(ndw, ndw_bf, NEXP*DIM*EDIM);   // attnb tail reusable now
    k_mgemm_pv<<<dim3(4,1,48), T, 0, stream>>>(P_bf, Vt_bf, o_bf);
    k_mgemm<<<dim3(16,6), T, 0, stream>>>(o_bf, DIM, NTOK, Wproj_bf, DIM, DIM, DIM,
                                          projb, x, DIM, attnd, nullptr, DIM, 1.f, 0);
    // ---- MoE ----
    k_ln<<<NTOK, T, 0, stream>>>(attnd, ln2g, ln2b, lnbuf, lnx_bf);
    k_route<<<NTOK, T, 0, stream>>>(lnbuf, Wrout, rb, dr, did, topi, topw, cnt);
    k_prefix<<<1, 1, 0, stream>>>(cnt, prefix);
    k_assign<<<8, T, 0, stream>>>(topi, prefix, cnt2, rowof, tokof);
    k_gather<<<dim3((4096*DIM)/256), T, 0, stream>>>(lnx_bf, tokof, Xg_bf);
    k_mgemm_expert<<<dim3(16,24,NEXP), T, 0, stream>>>(Xg_bf, DIM, Wexp_bf, DIM, (long)EDIM*DIM,
                                                       eb, EDIM, prefix, cnt,
                                                       nullptr, hidden_bf, EDIM, EDIM, DIM, 1);
    k_mgemm_expert<<<dim3(16,6,NEXP), T, 0, stream>>>(hidden_bf, EDIM, ndw_bf, EDIM, (long)DIM*EDIM,
                                                      ndb, DIM, prefix, cnt,
                                                      outg, nullptr, DIM, DIM, EDIM, 0);
    k_combine<<<dim3(6144), T, 0, stream>>>(attnd, outg, rowof, topw, eo, inx_bf);
    // ---- fractal memory (3 levels, MFMA mem-MHA) ----
    int Ms[3] = {64, 128, 256};
    long moff[3] = {0, 64L*DIM, 192L*DIM};
    for (int l=0; l<3; ++l){
        const u16* iwl = inw_bf + (size_t)l*QKVC*DIM;
        int M = Ms[l];
        int mt = (M+127)/128;
        k_mgemm<<<dim3(16,6), T, 0, stream>>>(inx_bf, DIM, NTOK, iwl, DIM, DIM, DIM,
                                              inb + (size_t)l*QKVC, nullptr, 0, nullptr, qm_bf, DIM, 1.f, 0);
        k_mgemm<<<dim3(mt,6), T, 0, stream>>>(mem_bf + moff[l], DIM, M, iwl + (size_t)DIM*DIM, DIM, DIM, DIM,
                                              inb + (size_t)l*QKVC + DIM, nullptr, 0, nullptr, km_bf, DIM, 1.f, 0);
        k_mgemm<<<dim3(mt,6), T, 0, stream>>>(mem_bf + moff[l], DIM, M, iwl + (size_t)2*DIM*DIM, DIM, DIM, DIM,
                                              inb + (size_t)l*QKVC + 2*DIM, nullptr, 0, nullptr, vm_bf, DIM, 1.f, 0);
        k_mgemm_memqk<<<dim3(16, mt, MHEADS), T, 0, stream>>>(qm_bf, km_bf, Smem, M, 0.10206207261596577f);
        k_softmax_mem<<<dim3(MHEADS*NTOK), dim3(64), 0, stream>>>(Smem, Pm_bf, M);
        k_transvm<<<dim3((DIM*M+255)/256), T, 0, stream>>>(vm_bf, Vtm_bf, M);
        k_mgemm_mempv<<<dim3(16,1,MHEADS), T, 0, stream>>>(Pm_bf, Vtm_bf, mhao_bf, M);
        k_mgemm<<<dim3(16,6), T, 0, stream>>>(mhao_bf, DIM, NTOK, outw_bf + (size_t)l*DIM*DIM, DIM, DIM, DIM,
                                              outb + (size_t)l*DIM, nullptr, 0, nullptr, qbuf_bf, DIM, 1.f, 0);
        k_mgemm<<<dim3(16,6), T, 0, stream>>>(qbuf_bf, DIM, NTOK, pw_bf + (size_t)l*DIM*DIM, DIM, DIM, DIM,
                                              pb + (size_t)l*DIM, (l==0 ? eo : accum), DIM,
                                              accum, inx_bf, DIM, 1.f, 0);
    }
    k_ln<<<NTOK, T, 0, stream>>>(accum, ln3g, ln3b, outf, nullptr);
}

// Round 4
// 1001.841 us; speedup vs baseline: 4.5486x; 1.5978x over previous
//
#include <hip/hip_runtime.h>
#include <math.h>

#define DIM    768
#define NTOK   2048
#define NSEQ   512
#define NBATCH 4
#define NHEADS 12
#define HD     64
#define QKVC   2304
#define MHEADS 8
#define MHD    96
#define NEXP   8
#define EDIM   3072

typedef unsigned short u16;
typedef __attribute__((ext_vector_type(8))) short short8;
typedef __attribute__((ext_vector_type(4))) float f32x4;

__device__ __forceinline__ float gelu_exact(float v){
    return 0.5f * v * (1.f + erff(v * 0.70710678118654752f));
}
__device__ __forceinline__ u16 f2bf(float f){
    unsigned int u = __builtin_bit_cast(unsigned int, f);
    unsigned int r = (u + 0x7FFFu + ((u >> 16) & 1u)) >> 16;
    return (u16)r;
}
// async global->LDS, 16B per lane; LDS dest linear (wave-uniform base + lane*16)
__device__ __forceinline__ void gll16(const u16* g, u16* l){
    __builtin_amdgcn_global_load_lds((const __attribute__((address_space(1))) void*)g,
                                     (__attribute__((address_space(3))) void*)l, 16, 0, 0);
}

// ================= MFMA bf16 GEMM core, wave-layout templated =================
// Tile (WM*64) x (WN*64), BK=64, WM*WN waves. XOR-swizzled LDS (T2-style):
// content LDS[r*64 + c*8] = G[row, (c^(r&7))*8] — fast path achieves this with
// linear-dest global_load_lds + pre-swizzled per-lane SOURCE (involution, m201 rule).
template<int WM,int WN>
__device__ __forceinline__ void mgemm_core(
    const u16* __restrict__ Xb, int ldx, int rowBase, int rowLim,
    const u16* __restrict__ Wb, int ldw, int colBase, int colLim, int K,
    const float* __restrict__ bias,
    const float* __restrict__ res, int ldres,
    float* __restrict__ Cf, u16* __restrict__ Cb, int ldc,
    float scale, int act)
{
    constexpr int RM = WM*64, RN = WN*64, NT = WM*WN*64;
    constexpr int IA = 8/WN, IB = 8/WM;
    __shared__ u16 As[RM*64];
    __shared__ u16 Bs[RN*64];
    int tid = threadIdx.x;
    int lane = tid & 63, w = tid >> 6;
    int wm = (w / WN) * 64, wn = (w % WN) * 64;
    const f32x4 zf = {0.f, 0.f, 0.f, 0.f};
    f32x4 acc[4][4];
    #pragma unroll
    for (int i=0;i<4;i++)
        #pragma unroll
        for (int j=0;j<4;j++) acc[i][j] = zf;

    const bool fullA = (rowBase + RM <= rowLim);
    const bool fullB = (colBase + RN <= colLim);

    for (int k0 = 0; k0 < K; k0 += 64) {
        const bool kfull = (k0 + 64 <= K);
        if (fullA && kfull) {
            #pragma unroll
            for (int it = 0; it < IA; ++it) {
                int idx = it*NT + tid;
                int r = idx >> 3, c = idx & 7;
                gll16(&Xb[(size_t)(rowBase + r)*ldx + k0 + ((c ^ (r & 7)) << 3)], &As[(size_t)idx*8]);
            }
        } else {
            #pragma unroll
            for (int it = 0; it < IA; ++it) {
                int idx = it*NT + tid;
                int r = idx >> 3, c = idx & 7;
                int gr = rowBase + r;
                uint4 v = {0u,0u,0u,0u};
                if (gr < rowLim && (k0 + c*8) < K) v = *(const uint4*)&Xb[(size_t)gr*ldx + k0 + c*8];
                *(uint4*)&As[r*64 + ((c ^ (r & 7)) * 8)] = v;
            }
        }
        if (fullB && kfull) {
            #pragma unroll
            for (int it = 0; it < IB; ++it) {
                int idx = it*NT + tid;
                int r = idx >> 3, c = idx & 7;
                gll16(&Wb[(size_t)(colBase + r)*ldw + k0 + ((c ^ (r & 7)) << 3)], &Bs[(size_t)idx*8]);
            }
        } else {
            #pragma unroll
            for (int it = 0; it < IB; ++it) {
                int idx = it*NT + tid;
                int r = idx >> 3, c = idx & 7;
                int gc = colBase + r;
                uint4 v = {0u,0u,0u,0u};
                if (gc < colLim && (k0 + c*8) < K) v = *(const uint4*)&Wb[(size_t)gc*ldw + k0 + c*8];
                *(uint4*)&Bs[r*64 + ((c ^ (r & 7)) * 8)] = v;
            }
        }
        __syncthreads();
        int lr = lane & 15, lk = lane >> 4;
        #pragma unroll
        for (int ks = 0; ks < 2; ++ks) {
            short8 af[4], bfr[4];
            #pragma unroll
            for (int mi=0; mi<4; mi++){
                int row = wm + mi*16 + lr;
                int cidx = (ks*4 + lk) ^ (row & 7);
                af[mi] = *(const short8*)&As[row*64 + cidx*8];
            }
            #pragma unroll
            for (int ni=0; ni<4; ni++){
                int col = wn + ni*16 + lr;
                int cidx = (ks*4 + lk) ^ (col & 7);
                bfr[ni] = *(const short8*)&Bs[col*64 + cidx*8];
            }
            #pragma unroll
            for (int mi=0; mi<4; mi++)
                #pragma unroll
                for (int ni=0; ni<4; ni++)
                    acc[mi][ni] = __builtin_amdgcn_mfma_f32_16x16x32_bf16(af[mi], bfr[ni], acc[mi][ni], 0, 0, 0);
        }
        __syncthreads();
    }
    // epilogue: D row = (lane>>4)*4 + reg, col = lane&15  [m89-verified]
    int lr = lane & 15, lg = lane >> 4;
    #pragma unroll
    for (int mi=0; mi<4; mi++){
        #pragma unroll
        for (int r=0; r<4; r++){
            int row = rowBase + wm + mi*16 + lg*4 + r;
            if (row >= rowLim) continue;
            #pragma unroll
            for (int ni=0; ni<4; ni++){
                int col = colBase + wn + ni*16 + lr;
                if (col >= colLim) continue;
                float v = acc[mi][ni][r] * scale;
                if (bias) v += bias[col];
                if (act == 1) v = gelu_exact(v);
                if (Cb) Cb[(size_t)row*ldc + col] = f2bf(v);
                if (res) v += res[(size_t)row*ldres + col];
                if (Cf) Cf[(size_t)row*ldc + col] = v;
            }
        }
    }
}

template<int WM,int WN>
__global__ __launch_bounds__(WM*WN*64) void k_mgemm(
    const u16* __restrict__ X, int ldx, int M,
    const u16* __restrict__ W, int ldw, int N, int K,
    const float* __restrict__ bias, const float* __restrict__ res, int ldres,
    float* __restrict__ Cf, u16* __restrict__ Cb, int ldc, float scale, int act)
{
    mgemm_core<WM,WN>(X, ldx, blockIdx.x*(WM*64), M, W, ldw, blockIdx.y*(WN*64), N, K,
                      bias, res, ldres, Cf, Cb, ldc, scale, act);
}

template<int WM,int WN>
__global__ __launch_bounds__(WM*WN*64) void k_mgemm_expert(
    const u16* __restrict__ X, int ldx,
    const u16* __restrict__ Wb, int ldw, long wStride,
    const float* __restrict__ biasB, int biasStride,
    const int* __restrict__ prefix, const int* __restrict__ cnt,
    float* __restrict__ Cf, u16* __restrict__ Cb, int ldc, int N, int K, int act)
{
    int e = blockIdx.z;
    int n = cnt[e];
    if ((int)blockIdx.x * (WM*64) >= n) return;
    mgemm_core<WM,WN>(X, ldx, prefix[e] + blockIdx.x*(WM*64), prefix[e] + n,
                      Wb + (size_t)e*wStride, ldw, blockIdx.y*(WN*64), N, K,
                      biasB + (size_t)e*biasStride, nullptr, 0, Cf, Cb, ldc, 1.f, act);
}

// scores[b,h,n,m] = 0.125 * q_n . k_m
template<int WM,int WN>
__global__ __launch_bounds__(WM*WN*64) void k_mgemm_qk(const u16* __restrict__ qkv, float* __restrict__ attn)
{
    int z = blockIdx.z, b = z / NHEADS, h = z % NHEADS;
    const u16* X = qkv + (size_t)b*NSEQ*QKVC + h*HD;          // q
    const u16* W = qkv + (size_t)b*NSEQ*QKVC + DIM + h*HD;    // k
    float* C = attn + (size_t)z*NSEQ*NSEQ;
    mgemm_core<WM,WN>(X, QKVC, blockIdx.x*(WM*64), NSEQ, W, QKVC, blockIdx.y*(WN*64), NSEQ, HD,
                      nullptr, nullptr, 0, C, nullptr, NSEQ, 0.125f, 0);
}

// o[b,n,h*64+d] = sum_m P[b,h,n,m] * V[b,m,h*64+d]; Vt[b][d][m] supplies W
template<int WM,int WN>
__global__ __launch_bounds__(WM*WN*64) void k_mgemm_pv(const u16* __restrict__ P, const u16* __restrict__ Vt, u16* __restrict__ o)
{
    int z = blockIdx.z, b = z / NHEADS, h = z % NHEADS;
    const u16* X = P + (size_t)z*NSEQ*NSEQ;
    const u16* W = Vt + ((size_t)b*DIM + h*HD)*NSEQ;
    u16* C = o + (size_t)b*NSEQ*DIM + h*HD;
    mgemm_core<WM,WN>(X, NSEQ, blockIdx.x*(WM*64), NSEQ, W, NSEQ, blockIdx.y*(WN*64), HD, NSEQ,
                      nullptr, nullptr, 0, nullptr, C, DIM, 1.f, 0);
}

// mem-MHA scores: S[h][n][m] = scale * q[n, h*96:..] . k[m, h*96:..]   (K=96)
template<int WM,int WN>
__global__ __launch_bounds__(WM*WN*64) void k_mgemm_memqk(const u16* __restrict__ q, const u16* __restrict__ k, int ldk,
                                                          float* __restrict__ S, int M, float scale)
{
    int h = blockIdx.z;
    mgemm_core<WM,WN>(q + h*MHD, DIM, blockIdx.x*(WM*64), NTOK, k + h*MHD, ldk, blockIdx.y*(WN*64), M, MHD,
                      nullptr, nullptr, 0, S + (size_t)h*NTOK*M, nullptr, M, scale, 0);
}

// mem-MHA PV: O[n, h*96+d] = sum_m P[h][n][m] * Vt[h*96+d][m]
template<int WM,int WN>
__global__ __launch_bounds__(WM*WN*64) void k_mgemm_mempv(const u16* __restrict__ P, const u16* __restrict__ Vt,
                                                          u16* __restrict__ O, int M)
{
    int h = blockIdx.z;
    mgemm_core<WM,WN>(P + (size_t)h*NTOK*M, M, blockIdx.x*(WM*64), NTOK, Vt + (size_t)h*MHD*M, M,
                      blockIdx.y*(WN*64), MHD, M,
                      nullptr, nullptr, 0, nullptr, O + h*MHD, DIM, 1.f, 0);
}

// Vt[d][m] = v[m*ldv + d]
__global__ __launch_bounds__(256) void k_transvm(const u16* __restrict__ v, int ldv, u16* __restrict__ Vt, int M)
{
    int idx = blockIdx.x*256 + threadIdx.x;
    if (idx >= DIM*M) return;
    int m = idx / DIM, d = idx % DIM;
    Vt[(size_t)d*M + m] = v[(size_t)m*ldv + d];
}

// softmax over row of length M (<=256), fp32 in -> bf16 out
__global__ __launch_bounds__(64) void k_softmax_mem(const float* __restrict__ S, u16* __restrict__ P, int M)
{
    size_t base = (size_t)blockIdx.x * M;
    int lane = threadIdx.x;
    float mx = -1e30f;
    for (int i = lane; i < M; i += 64) mx = fmaxf(mx, S[base+i]);
    for (int off=32; off; off>>=1) mx = fmaxf(mx, __shfl_xor(mx, off));
    float sum = 0.f;
    for (int i = lane; i < M; i += 64) sum += expf(S[base+i]-mx);
    for (int off=32; off; off>>=1) sum += __shfl_xor(sum, off);
    float inv = 1.f/sum;
    for (int i = lane; i < M; i += 64) P[base+i] = f2bf(expf(S[base+i]-mx)*inv);
}

// ================= PHM weight materialization =================
__global__ __launch_bounds__(256) void k_phm(
    const float* __restrict__ A, const float* __restrict__ S, void* __restrict__ W,
    int So, int Si, int inF, long Astride, long Sstride, long Wstride, int obf)
{
    int e = blockIdx.y;
    const float* Ae = A + (size_t)e*Astride;
    const float* Se = S + (size_t)e*Sstride;
    size_t idx = (size_t)blockIdx.x*256 + threadIdx.x;
    size_t total = (size_t)(So*4) * inF;
    if (idx >= total) return;
    int in = (int)(idx % inF);
    int o  = (int)(idx / inF);
    int a = o / So, c = o % So, b = in / Si, d = in % Si;
    float w = 0.f;
    #pragma unroll
    for (int i=0;i<4;i++) w = fmaf(Ae[i*16 + a*4 + b], Se[((size_t)i*So + c)*Si + d], w);
    if (obf) ((u16*)W)[(size_t)e*Wstride + idx] = f2bf(w);
    else     ((float*)W)[(size_t)e*Wstride + idx] = w;
}

// ================= fp32 -> bf16 convert =================
__global__ __launch_bounds__(256) void k_cvt(const float* __restrict__ s, u16* __restrict__ d, int n)
{
    for (int i = blockIdx.x*256 + threadIdx.x; i < n; i += gridDim.x*256)
        d[i] = f2bf(s[i]);
}

// ================= LayerNorm (row=768), dual output =================
__global__ __launch_bounds__(256) void k_ln(const float* __restrict__ x, const float* __restrict__ g,
                                            const float* __restrict__ b,
                                            float* __restrict__ yf, u16* __restrict__ yb)
{
    int row = blockIdx.x, tid = threadIdx.x;
    const float* xr = x + (size_t)row * DIM;
    float v0 = xr[tid], v1 = xr[tid+256], v2 = xr[tid+512];
    float s = v0+v1+v2;
    float ss = v0*v0 + v1*v1 + v2*v2;
    for (int off=32; off; off>>=1){ s += __shfl_xor(s,off); ss += __shfl_xor(ss,off); }
    __shared__ float sa[4], sb[4];
    int wid = tid >> 6;
    if ((tid & 63) == 0){ sa[wid]=s; sb[wid]=ss; }
    __syncthreads();
    s  = sa[0]+sa[1]+sa[2]+sa[3];
    ss = sb[0]+sb[1]+sb[2]+sb[3];
    float mean = s * (1.f/DIM);
    float var  = ss * (1.f/DIM) - mean*mean;
    float rstd = rsqrtf(var + 1e-5f);
    float o0 = (v0-mean)*rstd*g[tid]     + b[tid];
    float o1 = (v1-mean)*rstd*g[tid+256] + b[tid+256];
    float o2 = (v2-mean)*rstd*g[tid+512] + b[tid+512];
    if (yf){ float* yr = yf + (size_t)row*DIM; yr[tid]=o0; yr[tid+256]=o1; yr[tid+512]=o2; }
    if (yb){ u16* yr = yb + (size_t)row*DIM; yr[tid]=f2bf(o0); yr[tid+256]=f2bf(o1); yr[tid+512]=f2bf(o2); }
}

// ================= fused sup/ent mix + tanh + softmax: block per (b,n) =================
__global__ __launch_bounds__(256) void k_supsoft(
    const float* __restrict__ attn, u16* __restrict__ P,
    const float* __restrict__ wsup, const float* __restrict__ went)
{
    __shared__ float S[NHEADS][NSEQ];
    __shared__ float ws[144], we[144];
    int bn = blockIdx.x;
    int b = bn >> 9, n = bn & 511;
    int tid = threadIdx.x;
    if (tid < 144){ ws[tid] = wsup[tid]; we[tid] = went[tid]; }
    size_t base = ((size_t)b*NHEADS*NSEQ + n)*NSEQ;   // attn[b,0,n,0]; head stride NSEQ*NSEQ
    #pragma unroll
    for (int it=0; it<24; ++it){
        int idx = it*256 + tid;
        int j = idx >> 9, m = idx & 511;
        S[j][m] = attn[base + (size_t)j*NSEQ*NSEQ + m];
    }
    __syncthreads();
    #pragma unroll
    for (int half=0; half<2; ++half){
        int m = tid + half*256;
        float av[12], sup[12];
        #pragma unroll
        for (int j=0;j<12;j++) av[j] = S[j][m];
        #pragma unroll
        for (int i=0;i<12;i++){
            float s = 0.f;
            #pragma unroll
            for (int j=0;j<12;j++) s = fmaf(ws[i*12+j], av[j], s);
            sup[i] = s;
        }
        #pragma unroll
        for (int i=0;i<12;i++){
            float s = sup[i];
            #pragma unroll
            for (int j=0;j<12;j++) s = fmaf(we[i*12+j], sup[j], s);
            av[i] = tanhf(s);
        }
        #pragma unroll
        for (int i=0;i<12;i++) S[i][m] = av[i];
    }
    __syncthreads();
    // softmax: wave wv handles heads 3*wv .. 3*wv+2, fully wave-local
    int lane = tid & 63, wv = tid >> 6;
    #pragma unroll
    for (int jj=0; jj<3; ++jj){
        int j = wv*3 + jj;
        float v[8], mx = -1e30f;
        #pragma unroll
        for (int k=0;k<8;k++){ v[k] = S[j][lane + 64*k]; mx = fmaxf(mx, v[k]); }
        for (int off=32; off; off>>=1) mx = fmaxf(mx, __shfl_xor(mx, off));
        float sum = 0.f;
        #pragma unroll
        for (int k=0;k<8;k++){ v[k] = expf(v[k]-mx); sum += v[k]; }
        for (int off=32; off; off>>=1) sum += __shfl_xor(sum, off);
        float inv = 1.f/sum;
        #pragma unroll
        for (int k=0;k<8;k++) P[base + (size_t)j*NSEQ*NSEQ + lane + 64*k] = f2bf(v[k]*inv);
    }
}

// ================= V transpose (main attn): Vt[b][d][m] = qkv_bf[b][m][1536+d] =================
__global__ __launch_bounds__(256) void k_transv(const u16* __restrict__ qkv, u16* __restrict__ Vt)
{
    __shared__ u16 L[64][65];
    int mt = blockIdx.x*64, dt = blockIdx.y*64, b = blockIdx.z;
    int tid = threadIdx.x;
    #pragma unroll
    for (int it=0; it<16; ++it){
        int idx = it*256 + tid;
        int mm = idx >> 6, dd = idx & 63;
        L[mm][dd] = qkv[((size_t)b*NSEQ + mt + mm)*QKVC + 1536 + dt + dd];
    }
    __syncthreads();
    #pragma unroll
    for (int it=0; it<16; ++it){
        int idx = it*256 + tid;
        int dd = idx >> 6, mm = idx & 63;
        Vt[((size_t)b*DIM + dt + dd)*NSEQ + mt + mm] = L[mm][dd];
    }
}

// ================= MoE routing =================
__global__ __launch_bounds__(256) void k_route(
    const float* __restrict__ ln2, const float* __restrict__ Wr,
    const float* __restrict__ rb, const float* __restrict__ dr,
    const int* __restrict__ did, int* __restrict__ topi, float* __restrict__ topw, int* __restrict__ cnt)
{
    int t = blockIdx.x, tid = threadIdx.x;
    const float* xr = ln2 + (size_t)t*DIM;
    float a[8] = {};
    #pragma unroll
    for (int ii=0; ii<3; ii++){
        int i = tid + ii*256;
        float xv = xr[i];
        #pragma unroll
        for (int e=0;e<8;e++) a[e] = fmaf(xv, Wr[e*DIM + i], a[e]);
    }
    #pragma unroll
    for (int e=0;e<8;e++)
        for (int off=32; off; off>>=1) a[e] += __shfl_xor(a[e], off);
    __shared__ float sred[4][8];
    int wid = tid >> 6;
    if ((tid & 63) == 0){
        #pragma unroll
        for (int e=0;e<8;e++) sred[wid][e] = a[e];
    }
    __syncthreads();
    if (tid == 0){
        int d = did[0];
        float lg[8];
        #pragma unroll
        for (int e=0;e<8;e++) lg[e] = sred[0][e]+sred[1][e]+sred[2][e]+sred[3][e] + rb[e] + dr[d*8+e];
        int i1 = 0; float v1 = lg[0];
        #pragma unroll
        for (int e=1;e<8;e++) if (lg[e] > v1){ v1 = lg[e]; i1 = e; }
        int i2 = -1; float v2 = -1e30f;
        #pragma unroll
        for (int e=0;e<8;e++) if (e != i1 && lg[e] > v2){ v2 = lg[e]; i2 = e; }
        float e2 = expf(v2 - v1);
        float inv = 1.f / (1.f + e2);
        topi[2*t] = i1; topi[2*t+1] = i2;
        topw[2*t] = inv; topw[2*t+1] = e2 * inv;
        atomicAdd(&cnt[i1], 1); atomicAdd(&cnt[i2], 1);
    }
}

__global__ void k_zero(int* p, int n){ int i = threadIdx.x; if (i < n) p[i] = 0; }

__global__ void k_prefix(const int* __restrict__ cnt, int* __restrict__ prefix){
    if (threadIdx.x == 0){ int s=0; for (int e=0;e<8;e++){ prefix[e]=s; s+=cnt[e]; } }
}

__global__ __launch_bounds__(256) void k_assign(
    const int* __restrict__ topi, const int* __restrict__ prefix,
    int* __restrict__ cnt2, int* __restrict__ rowof, int* __restrict__ tokof)
{
    int t = blockIdx.x*256 + threadIdx.x;
    if (t >= NTOK) return;
    #pragma unroll
    for (int k=0;k<2;k++){
        int e = topi[2*t+k];
        int slot = atomicAdd(&cnt2[e], 1);
        int row = prefix[e] + slot;
        rowof[2*t+k] = row;
        tokof[row] = t;
    }
}

__global__ __launch_bounds__(256) void k_gather(const u16* __restrict__ src, const int* __restrict__ tokof, u16* __restrict__ dst)
{
    size_t i = (size_t)blockIdx.x*256 + threadIdx.x;
    int row = (int)(i / DIM), c = (int)(i % DIM);
    dst[i] = src[(size_t)tokof[row]*DIM + c];
}

__global__ __launch_bounds__(256) void k_combine(
    const float* __restrict__ att, const float* __restrict__ outg,
    const int* __restrict__ rowof, const float* __restrict__ topw,
    float* __restrict__ eo, u16* __restrict__ eob)
{
    size_t i = (size_t)blockIdx.x*256 + threadIdx.x;
    int t = (int)(i / DIM), c = (int)(i % DIM);
    int r0 = rowof[2*t], r1 = rowof[2*t+1];
    float v = att[i] + topw[2*t]*outg[(size_t)r0*DIM+c] + topw[2*t+1]*outg[(size_t)r1*DIM+c];
    eo[i] = v;
    eob[i] = f2bf(v);
}

// ================= host =================
extern "C" void kernel_launch(void* const* d_in, const int* in_sizes, int n_in,
                              void* d_out, int out_size, void* d_ws, size_t ws_size,
                              hipStream_t stream)
{
    const float* x     = (const float*)d_in[0];
    const float* ln1g  = (const float*)d_in[1];
    const float* ln1b  = (const float*)d_in[2];
    const float* ln2g  = (const float*)d_in[3];
    const float* ln2b  = (const float*)d_in[4];
    const float* ln3g  = (const float*)d_in[5];
    const float* ln3b  = (const float*)d_in[6];
    const float* qkvA  = (const float*)d_in[7];
    const float* qkvS  = (const float*)d_in[8];
    const float* qkvb  = (const float*)d_in[9];
    const float* projA = (const float*)d_in[10];
    const float* projS = (const float*)d_in[11];
    const float* projb = (const float*)d_in[12];
    const float* wsup  = (const float*)d_in[13];
    const float* went  = (const float*)d_in[14];
    const float* rA    = (const float*)d_in[15];
    const float* rS    = (const float*)d_in[16];
    const float* rb    = (const float*)d_in[17];
    const float* dr    = (const float*)d_in[18];
    const float* eA    = (const float*)d_in[19];
    const float* eS    = (const float*)d_in[20];
    const float* eb    = (const float*)d_in[21];
    const float* ndw   = (const float*)d_in[22];
    const float* ndb   = (const float*)d_in[23];
    const float* mem0  = (const float*)d_in[24];
    const float* mem1  = (const float*)d_in[25];
    const float* mem2  = (const float*)d_in[26];
    const float* inw   = (const float*)d_in[27];
    const float* inb   = (const float*)d_in[28];
    const float* outw  = (const float*)d_in[29];
    const float* outb  = (const float*)d_in[30];
    const float* pw    = (const float*)d_in[31];
    const float* pb    = (const float*)d_in[32];
    const int*   did   = (const int*)d_in[33];

    float* f = (float*)d_ws;
    size_t off = 0;
    auto alloc = [&](size_t n){ float* p = f + off; off += (n + 3) & ~(size_t)3; return p; };
    auto allocb = [&](size_t n){ return (u16*)alloc((n + 1) / 2); };

    // fp32 buffers
    float* lnbuf  = alloc((size_t)NTOK*DIM);
    float* attnd  = alloc((size_t)NTOK*DIM);
    float* eo     = alloc((size_t)NTOK*DIM);
    float* accum  = alloc((size_t)NTOK*DIM);
    float* attnb  = alloc((size_t)48*NSEQ*NSEQ);   // scores; hosts outg + ndw_bf; later Smem
    float* Wrout  = alloc((size_t)NEXP*DIM);
    float* topw   = alloc((size_t)2*NTOK);
    int* ip = (int*)alloc((size_t)6*NTOK + 64);
    int* topi   = ip;            ip += 2*NTOK;
    int* rowof  = ip;            ip += 2*NTOK;
    int* tokof  = ip;            ip += 2*NTOK;
    int* cnt    = ip;            ip += 8;
    int* cnt2   = ip;            ip += 8;
    int* prefix = ip;            ip += 8;

    // aliases inside attnb
    float* outg   = attnb;                               // 4096x768 fp32
    u16*   ndw_bf = (u16*)(attnb + (size_t)3146240);     // 18.87M u16
    float* Smem   = attnb;                               // fractal-phase scores (<=4.2M floats)

    // bf16 buffers
    u16* Wqkv_bf  = allocb((size_t)QKVC*DIM);
    u16* Wproj_bf = allocb((size_t)DIM*DIM);
    u16* Wexp_bf  = allocb((size_t)NEXP*EDIM*DIM);
    u16* inw_bf   = allocb((size_t)3*QKVC*DIM);
    u16* outw_bf  = allocb((size_t)3*DIM*DIM);
    u16* pw_bf    = allocb((size_t)3*DIM*DIM);
    u16* mem_bf   = allocb((size_t)448*DIM);
    u16* qkv_bf   = allocb((size_t)NTOK*QKVC);     // hosts Xg_bf later
    u16* Vt_bf    = allocb((size_t)NBATCH*DIM*NSEQ);
    u16* P_bf     = allocb((size_t)48*NSEQ*NSEQ);  // also hidden_bf, later Pm_bf
    u16* lnx_bf   = allocb((size_t)NTOK*DIM);
    u16* o_bf     = allocb((size_t)NTOK*DIM);      // attn out; later qm_bf
    u16* inx_bf   = allocb((size_t)NTOK*DIM);
    u16* mhao_bf  = allocb((size_t)NTOK*DIM);
    u16* qbuf_bf  = allocb((size_t)NTOK*DIM);
    u16* kv_bf    = allocb((size_t)256*2*DIM);     // [M][1536] fused K|V
    u16* Vtm_bf   = allocb((size_t)MHEADS*MHD*256);
    u16* Xg_bf    = qkv_bf;
    u16* hidden_bf= P_bf;
    u16* Pm_bf    = P_bf;
    u16* qm_bf    = o_bf;

    float* outf = (float*)d_out;
    dim3 T256(256), T128(128), T64(64);

    k_zero<<<1, 32, 0, stream>>>(cnt, 16);
    k_ln<<<NTOK, T256, 0, stream>>>(x, ln1g, ln1b, nullptr, lnx_bf);
    // PHM weight builds (bf16 except router)
    k_phm<<<dim3((QKVC*DIM+255)/256,1), T256, 0, stream>>>(qkvA, qkvS, Wqkv_bf, 576, 192, DIM, 0,0,0, 1);
    k_phm<<<dim3((DIM*DIM+255)/256,1),  T256, 0, stream>>>(projA, projS, Wproj_bf, 192, 192, DIM, 0,0,0, 1);
    k_phm<<<dim3((NEXP*DIM+255)/256,1), T256, 0, stream>>>(rA, rS, Wrout, 2, 192, DIM, 0,0,0, 0);
    k_phm<<<dim3((EDIM*DIM+255)/256,NEXP), T256, 0, stream>>>(eA, eS, Wexp_bf, 768, 192, DIM,
                                                              64L, (long)4*768*192, (long)EDIM*DIM, 1);
    // weight converts (fp32 -> bf16), already (N,K) layout
    k_cvt<<<4096, T256, 0, stream>>>(inw,  inw_bf,  3*QKVC*DIM);
    k_cvt<<<2048, T256, 0, stream>>>(outw, outw_bf, 3*DIM*DIM);
    k_cvt<<<2048, T256, 0, stream>>>(pw,   pw_bf,   3*DIM*DIM);
    k_cvt<<<256,  T256, 0, stream>>>(mem0, mem_bf,              64*DIM);
    k_cvt<<<256,  T256, 0, stream>>>(mem1, mem_bf + 64*DIM,    128*DIM);
    k_cvt<<<512,  T256, 0, stream>>>(mem2, mem_bf + 192*DIM,   256*DIM);

    // ---- quantum attention ----
    k_mgemm<2,2><<<dim3(16,18), T256, 0, stream>>>(lnx_bf, DIM, NTOK, Wqkv_bf, DIM, QKVC, DIM,
                                                   qkvb, nullptr, 0, nullptr, qkv_bf, QKVC, 1.f, 0);
    k_transv<<<dim3(8,12,NBATCH), T256, 0, stream>>>(qkv_bf, Vt_bf);
    k_mgemm_qk<2,2><<<dim3(4,4,48), T256, 0, stream>>>(qkv_bf, attnb);
    k_supsoft<<<dim3(NTOK), T256, 0, stream>>>(attnb, P_bf, wsup, went);
    k_cvt<<<4096, T256, 0, stream>>>(ndw, ndw_bf, NEXP*DIM*EDIM);   // attnb tail reusable now
    k_mgemm_pv<1,1><<<dim3(8,1,48), T64, 0, stream>>>(P_bf, Vt_bf, o_bf);
    k_mgemm<1,2><<<dim3(32,6), T128, 0, stream>>>(o_bf, DIM, NTOK, Wproj_bf, DIM, DIM, DIM,
                                                  projb, x, DIM, attnd, nullptr, DIM, 1.f, 0);
    // ---- MoE ----
    k_ln<<<NTOK, T256, 0, stream>>>(attnd, ln2g, ln2b, lnbuf, lnx_bf);
    k_route<<<NTOK, T256, 0, stream>>>(lnbuf, Wrout, rb, dr, did, topi, topw, cnt);
    k_prefix<<<1, 1, 0, stream>>>(cnt, prefix);
    k_assign<<<8, T256, 0, stream>>>(topi, prefix, cnt2, rowof, tokof);
    k_gather<<<dim3((4096*DIM)/256), T256, 0, stream>>>(lnx_bf, tokof, Xg_bf);
    k_mgemm_expert<2,2><<<dim3(16,24,NEXP), T256, 0, stream>>>(Xg_bf, DIM, Wexp_bf, DIM, (long)EDIM*DIM,
                                                               eb, EDIM, prefix, cnt,
                                                               nullptr, hidden_bf, EDIM, EDIM, DIM, 1);
    k_mgemm_expert<1,2><<<dim3(32,6,NEXP), T128, 0, stream>>>(hidden_bf, EDIM, ndw_bf, EDIM, (long)DIM*EDIM,
                                                              ndb, DIM, prefix, cnt,
                                                              outg, nullptr, DIM, DIM, EDIM, 0);
    k_combine<<<dim3(6144), T256, 0, stream>>>(attnd, outg, rowof, topw, eo, inx_bf);
    // ---- fractal memory (3 levels, MFMA mem-MHA) ----
    int Ms[3] = {64, 128, 256};
    long moff[3] = {0, 64L*DIM, 192L*DIM};
    for (int l=0; l<3; ++l){
        const u16* iwl = inw_bf + (size_t)l*QKVC*DIM;
        int M = Ms[l];
        int mt64 = (M+63)/64;
        k_mgemm<1,2><<<dim3(32,6), T128, 0, stream>>>(inx_bf, DIM, NTOK, iwl, DIM, DIM, DIM,
                                                      inb + (size_t)l*QKVC, nullptr, 0, nullptr, qm_bf, DIM, 1.f, 0);
        // fused K|V projection: N=1536 (k rows 768..1535, v rows 1536..2303 of inw are contiguous)
        k_mgemm<1,2><<<dim3(mt64,12), T128, 0, stream>>>(mem_bf + moff[l], DIM, M, iwl + (size_t)DIM*DIM, DIM, 2*DIM, DIM,
                                                         inb + (size_t)l*QKVC + DIM, nullptr, 0, nullptr, kv_bf, 2*DIM, 1.f, 0);
        k_mgemm_memqk<1,1><<<dim3(32,mt64,MHEADS), T64, 0, stream>>>(qm_bf, kv_bf, 2*DIM, Smem, M, 0.10206207261596577f);
        k_softmax_mem<<<dim3(MHEADS*NTOK), T64, 0, stream>>>(Smem, Pm_bf, M);
        k_transvm<<<dim3((DIM*M+255)/256), T256, 0, stream>>>(kv_bf + DIM, 2*DIM, Vtm_bf, M);
        k_mgemm_mempv<1,1><<<dim3(32,2,MHEADS), T64, 0, stream>>>(Pm_bf, Vtm_bf, mhao_bf, M);
        k_mgemm<1,2><<<dim3(32,6), T128, 0, stream>>>(mhao_bf, DIM, NTOK, outw_bf + (size_t)l*DIM*DIM, DIM, DIM, DIM,
                                                      outb + (size_t)l*DIM, nullptr, 0, nullptr, qbuf_bf, DIM, 1.f, 0);
        k_mgemm<1,2><<<dim3(32,6), T128, 0, stream>>>(qbuf_bf, DIM, NTOK, pw_bf + (size_t)l*DIM*DIM, DIM, DIM, DIM,
                                                      pb + (size_t)l*DIM, (l==0 ? eo : accum), DIM,
                                                      accum, inx_bf, DIM, 1.f, 0);
    }
    k_ln<<<NTOK, T256, 0, stream>>>(accum, ln3g, ln3b, outf, nullptr);
}

// Round 5
// 766.575 us; speedup vs baseline: 5.9445x; 1.3069x over previous
//
#include <hip/hip_runtime.h>
#include <math.h>

#define DIM    768
#define NTOK   2048
#define NSEQ   512
#define NBATCH 4
#define NHEADS 12
#define HD     64
#define QKVC   2304
#define MHEADS 8
#define MHD    96
#define NEXP   8
#define EDIM   3072
#define DD     (DIM*DIM)

typedef unsigned short u16;
typedef __attribute__((ext_vector_type(8))) short short8;
typedef __attribute__((ext_vector_type(4))) float f32x4;

__device__ __forceinline__ float gelu_exact(float v){
    return 0.5f * v * (1.f + erff(v * 0.70710678118654752f));
}
__device__ __forceinline__ u16 f2bf(float f){
    unsigned int u = __builtin_bit_cast(unsigned int, f);
    unsigned int r = (u + 0x7FFFu + ((u >> 16) & 1u)) >> 16;
    return (u16)r;
}
// async global->LDS, 16B per lane; LDS dest linear (wave-uniform base + lane*16)
__device__ __forceinline__ void gll16(const u16* g, u16* l){
    __builtin_amdgcn_global_load_lds((const __attribute__((address_space(1))) void*)g,
                                     (__attribute__((address_space(3))) void*)l, 16, 0, 0);
}

// ================= MFMA bf16 GEMM core =================
// Per-wave tile (16*FR)x(16*FR); block tile (WM*16*FR)x(WN*16*FR); BK=64; WM*WN waves.
// XOR-swizzled LDS; fast path = linear-dest global_load_lds + pre-swizzled SOURCE (m201 rule).
template<int WM,int WN,int FR>
__device__ __forceinline__ void mgemm_core(
    const u16* __restrict__ Xb, int ldx, int rowBase, int rowLim,
    const u16* __restrict__ Wb, int ldw, int colBase, int colLim, int K,
    const float* __restrict__ bias,
    const float* __restrict__ res, int ldres,
    float* __restrict__ Cf, u16* __restrict__ Cb, int ldc,
    float scale, int act)
{
    constexpr int TM = 16*FR;
    constexpr int RM = WM*TM, RN = WN*TM, NT = WM*WN*64;
    constexpr int IA = (RM*8)/NT, IB = (RN*8)/NT;
    __shared__ u16 As[RM*64];
    __shared__ u16 Bs[RN*64];
    int tid = threadIdx.x;
    int lane = tid & 63, w = tid >> 6;
    int wm = (w / WN) * TM, wn = (w % WN) * TM;
    const f32x4 zf = {0.f, 0.f, 0.f, 0.f};
    f32x4 acc[FR][FR];
    #pragma unroll
    for (int i=0;i<FR;i++)
        #pragma unroll
        for (int j=0;j<FR;j++) acc[i][j] = zf;

    const bool fullA = (rowBase + RM <= rowLim);
    const bool fullB = (colBase + RN <= colLim);

    for (int k0 = 0; k0 < K; k0 += 64) {
        const bool kfull = (k0 + 64 <= K);
        if (fullA && kfull) {
            #pragma unroll
            for (int it = 0; it < IA; ++it) {
                int idx = it*NT + tid;
                int r = idx >> 3, c = idx & 7;
                gll16(&Xb[(size_t)(rowBase + r)*ldx + k0 + ((c ^ (r & 7)) << 3)], &As[(size_t)idx*8]);
            }
        } else {
            #pragma unroll
            for (int it = 0; it < IA; ++it) {
                int idx = it*NT + tid;
                int r = idx >> 3, c = idx & 7;
                int gr = rowBase + r;
                uint4 v = {0u,0u,0u,0u};
                if (gr < rowLim && (k0 + c*8) < K) v = *(const uint4*)&Xb[(size_t)gr*ldx + k0 + c*8];
                *(uint4*)&As[r*64 + ((c ^ (r & 7)) * 8)] = v;
            }
        }
        if (fullB && kfull) {
            #pragma unroll
            for (int it = 0; it < IB; ++it) {
                int idx = it*NT + tid;
                int r = idx >> 3, c = idx & 7;
                gll16(&Wb[(size_t)(colBase + r)*ldw + k0 + ((c ^ (r & 7)) << 3)], &Bs[(size_t)idx*8]);
            }
        } else {
            #pragma unroll
            for (int it = 0; it < IB; ++it) {
                int idx = it*NT + tid;
                int r = idx >> 3, c = idx & 7;
                int gc = colBase + r;
                uint4 v = {0u,0u,0u,0u};
                if (gc < colLim && (k0 + c*8) < K) v = *(const uint4*)&Wb[(size_t)gc*ldw + k0 + c*8];
                *(uint4*)&Bs[r*64 + ((c ^ (r & 7)) * 8)] = v;
            }
        }
        __syncthreads();
        int lr = lane & 15, lk = lane >> 4;
        #pragma unroll
        for (int ks = 0; ks < 2; ++ks) {
            short8 af[FR], bfr[FR];
            #pragma unroll
            for (int mi=0; mi<FR; mi++){
                int row = wm + mi*16 + lr;
                int cidx = (ks*4 + lk) ^ (row & 7);
                af[mi] = *(const short8*)&As[row*64 + cidx*8];
            }
            #pragma unroll
            for (int ni=0; ni<FR; ni++){
                int col = wn + ni*16 + lr;
                int cidx = (ks*4 + lk) ^ (col & 7);
                bfr[ni] = *(const short8*)&Bs[col*64 + cidx*8];
            }
            #pragma unroll
            for (int mi=0; mi<FR; mi++)
                #pragma unroll
                for (int ni=0; ni<FR; ni++)
                    acc[mi][ni] = __builtin_amdgcn_mfma_f32_16x16x32_bf16(af[mi], bfr[ni], acc[mi][ni], 0, 0, 0);
        }
        __syncthreads();
    }
    // epilogue: D row = (lane>>4)*4 + reg, col = lane&15  [m89-verified]
    int lr = lane & 15, lg = lane >> 4;
    #pragma unroll
    for (int mi=0; mi<FR; mi++){
        #pragma unroll
        for (int r=0; r<4; r++){
            int row = rowBase + wm + mi*16 + lg*4 + r;
            if (row >= rowLim) continue;
            #pragma unroll
            for (int ni=0; ni<FR; ni++){
                int col = colBase + wn + ni*16 + lr;
                if (col >= colLim) continue;
                float v = acc[mi][ni][r] * scale;
                if (bias) v += bias[col];
                if (act == 1) v = gelu_exact(v);
                if (Cb) Cb[(size_t)row*ldc + col] = f2bf(v);
                if (res) v += res[(size_t)row*ldres + col];
                if (Cf) Cf[(size_t)row*ldc + col] = v;
            }
        }
    }
}

template<int WM,int WN,int FR>
__global__ __launch_bounds__(WM*WN*64) void k_mgemm(
    const u16* __restrict__ X, int ldx, int M,
    const u16* __restrict__ W, int ldw, int N, int K,
    const float* __restrict__ bias, const float* __restrict__ res, int ldres,
    float* __restrict__ Cf, u16* __restrict__ Cb, int ldc, float scale, int act)
{
    constexpr int RM = WM*16*FR, RN = WN*16*FR;
    mgemm_core<WM,WN,FR>(X, ldx, blockIdx.x*RM, M, W, ldw, blockIdx.y*RN, N, K,
                         bias, res, ldres, Cf, Cb, ldc, scale, act);
}

template<int WM,int WN,int FR>
__global__ __launch_bounds__(WM*WN*64) void k_mgemm_expert(
    const u16* __restrict__ X, int ldx,
    const u16* __restrict__ Wb, int ldw, long wStride,
    const float* __restrict__ biasB, int biasStride,
    const int* __restrict__ prefix, const int* __restrict__ cnt,
    float* __restrict__ Cf, u16* __restrict__ Cb, int ldc, int N, int K, int act)
{
    constexpr int RM = WM*16*FR, RN = WN*16*FR;
    int e = blockIdx.z;
    int n = cnt[e];
    if ((int)blockIdx.x * RM >= n) return;
    mgemm_core<WM,WN,FR>(X, ldx, prefix[e] + blockIdx.x*RM, prefix[e] + n,
                         Wb + (size_t)e*wStride, ldw, blockIdx.y*RN, N, K,
                         biasB + (size_t)e*biasStride, nullptr, 0, Cf, Cb, ldc, 1.f, act);
}

// scores[b,h,n,m] = 0.125 * q_n . k_m
template<int WM,int WN,int FR>
__global__ __launch_bounds__(WM*WN*64) void k_mgemm_qk(const u16* __restrict__ qkv, float* __restrict__ attn)
{
    constexpr int RM = WM*16*FR, RN = WN*16*FR;
    int z = blockIdx.z, b = z / NHEADS, h = z % NHEADS;
    const u16* X = qkv + (size_t)b*NSEQ*QKVC + h*HD;          // q
    const u16* W = qkv + (size_t)b*NSEQ*QKVC + DIM + h*HD;    // k
    float* C = attn + (size_t)z*NSEQ*NSEQ;
    mgemm_core<WM,WN,FR>(X, QKVC, blockIdx.x*RM, NSEQ, W, QKVC, blockIdx.y*RN, NSEQ, HD,
                         nullptr, nullptr, 0, C, nullptr, NSEQ, 0.125f, 0);
}

// o[b,n,h*64+d] = sum_m P[b,h,n,m] * V[b,m,h*64+d]; Vt[b][d][m] supplies W
template<int WM,int WN,int FR>
__global__ __launch_bounds__(WM*WN*64) void k_mgemm_pv(const u16* __restrict__ P, const u16* __restrict__ Vt, u16* __restrict__ o)
{
    constexpr int RM = WM*16*FR, RN = WN*16*FR;
    int z = blockIdx.z, b = z / NHEADS, h = z % NHEADS;
    const u16* X = P + (size_t)z*NSEQ*NSEQ;
    const u16* W = Vt + ((size_t)b*DIM + h*HD)*NSEQ;
    u16* C = o + (size_t)b*NSEQ*DIM + h*HD;
    mgemm_core<WM,WN,FR>(X, NSEQ, blockIdx.x*RM, NSEQ, W, NSEQ, blockIdx.y*RN, HD, NSEQ,
                         nullptr, nullptr, 0, nullptr, C, DIM, 1.f, 0);
}

// mem-MHA scores: S[h][n][m] = scale * q[n, h*96:..] . k[m, h*96:..]   (K=96)
template<int WM,int WN,int FR>
__global__ __launch_bounds__(WM*WN*64) void k_mgemm_memqk(const u16* __restrict__ q, const u16* __restrict__ k, int ldk,
                                                          float* __restrict__ S, int M, float scale)
{
    constexpr int RM = WM*16*FR, RN = WN*16*FR;
    int h = blockIdx.z;
    mgemm_core<WM,WN,FR>(q + h*MHD, DIM, blockIdx.x*RM, NTOK, k + h*MHD, ldk, blockIdx.y*RN, M, MHD,
                         nullptr, nullptr, 0, S + (size_t)h*NTOK*M, nullptr, M, scale, 0);
}

// mem-MHA PV: O[n, h*96+d] = sum_m P[h][n][m] * Vt[h*96+d][m]
template<int WM,int WN,int FR>
__global__ __launch_bounds__(WM*WN*64) void k_mgemm_mempv(const u16* __restrict__ P, const u16* __restrict__ Vt,
                                                          u16* __restrict__ O, int M)
{
    constexpr int RM = WM*16*FR, RN = WN*16*FR;
    int h = blockIdx.z;
    mgemm_core<WM,WN,FR>(P + (size_t)h*NTOK*M, M, blockIdx.x*RM, NTOK, Vt + (size_t)h*MHD*M, M,
                         blockIdx.y*RN, MHD, M,
                         nullptr, nullptr, 0, nullptr, O + h*MHD, DIM, 1.f, 0);
}

// Vt[d][m] = v[m*ldv + d]   (d < DIM)
__global__ __launch_bounds__(256) void k_transvm(const u16* __restrict__ v, int ldv, u16* __restrict__ Vt, int M)
{
    int idx = blockIdx.x*256 + threadIdx.x;
    if (idx >= DIM*M) return;
    int m = idx / DIM, d = idx % DIM;
    Vt[(size_t)d*M + m] = v[(size_t)m*ldv + d];
}

// softmax over row of length M (<=256), fp32 in -> bf16 out
__global__ __launch_bounds__(64) void k_softmax_mem(const float* __restrict__ S, u16* __restrict__ P, int M)
{
    size_t base = (size_t)blockIdx.x * M;
    int lane = threadIdx.x;
    float mx = -1e30f;
    for (int i = lane; i < M; i += 64) mx = fmaxf(mx, S[base+i]);
    for (int off=32; off; off>>=1) mx = fmaxf(mx, __shfl_xor(mx, off));
    float sum = 0.f;
    for (int i = lane; i < M; i += 64) sum += expf(S[base+i]-mx);
    for (int off=32; off; off>>=1) sum += __shfl_xor(sum, off);
    float inv = 1.f/sum;
    for (int i = lane; i < M; i += 64) P[base+i] = f2bf(expf(S[base+i]-mx)*inv);
}

// ================= PHM weight materialization =================
__global__ __launch_bounds__(256) void k_phm(
    const float* __restrict__ A, const float* __restrict__ S, void* __restrict__ W,
    int So, int Si, int inF, long Astride, long Sstride, long Wstride, int obf)
{
    int e = blockIdx.y;
    const float* Ae = A + (size_t)e*Astride;
    const float* Se = S + (size_t)e*Sstride;
    size_t idx = (size_t)blockIdx.x*256 + threadIdx.x;
    size_t total = (size_t)(So*4) * inF;
    if (idx >= total) return;
    int in = (int)(idx % inF);
    int o  = (int)(idx / inF);
    int a = o / So, c = o % So, b = in / Si, d = in % Si;
    float w = 0.f;
    #pragma unroll
    for (int i=0;i<4;i++) w = fmaf(Ae[i*16 + a*4 + b], Se[((size_t)i*So + c)*Si + d], w);
    if (obf) ((u16*)W)[(size_t)e*Wstride + idx] = f2bf(w);
    else     ((float*)W)[(size_t)e*Wstride + idx] = w;
}

// ================= fp32 -> bf16 convert, 4-wide =================
__global__ __launch_bounds__(256) void k_cvt4(const float4* __restrict__ s, ushort4* __restrict__ d, int n4)
{
    for (int i = blockIdx.x*256 + threadIdx.x; i < n4; i += gridDim.x*256){
        float4 v = s[i];
        ushort4 o; o.x = f2bf(v.x); o.y = f2bf(v.y); o.z = f2bf(v.z); o.w = f2bf(v.w);
        d[i] = o;
    }
}

// bc[l][i] = dot(pw[l][i][:], outb[l][:]) + pb[l][i]
__global__ __launch_bounds__(256) void k_bc(const float* __restrict__ pw, const float* __restrict__ outb,
                                            const float* __restrict__ pb, float* __restrict__ bc)
{
    int l = blockIdx.y;
    int i = blockIdx.x*4 + (threadIdx.x >> 6);
    int lane = threadIdx.x & 63;
    const float* pr = pw + ((size_t)l*DIM + i)*DIM;
    const float* ob = outb + (size_t)l*DIM;
    float s = 0.f;
    for (int j = lane; j < DIM; j += 64) s = fmaf(pr[j], ob[j], s);
    for (int off=32; off; off>>=1) s += __shfl_xor(s, off);
    if (lane == 0) bc[(size_t)l*DIM + i] = s + pb[(size_t)l*DIM + i];
}

// ================= LayerNorm (row=768), dual output =================
__global__ __launch_bounds__(256) void k_ln(const float* __restrict__ x, const float* __restrict__ g,
                                            const float* __restrict__ b,
                                            float* __restrict__ yf, u16* __restrict__ yb)
{
    int row = blockIdx.x, tid = threadIdx.x;
    const float* xr = x + (size_t)row * DIM;
    float v0 = xr[tid], v1 = xr[tid+256], v2 = xr[tid+512];
    float s = v0+v1+v2;
    float ss = v0*v0 + v1*v1 + v2*v2;
    for (int off=32; off; off>>=1){ s += __shfl_xor(s,off); ss += __shfl_xor(ss,off); }
    __shared__ float sa[4], sb[4];
    int wid = tid >> 6;
    if ((tid & 63) == 0){ sa[wid]=s; sb[wid]=ss; }
    __syncthreads();
    s  = sa[0]+sa[1]+sa[2]+sa[3];
    ss = sb[0]+sb[1]+sb[2]+sb[3];
    float mean = s * (1.f/DIM);
    float var  = ss * (1.f/DIM) - mean*mean;
    float rstd = rsqrtf(var + 1e-5f);
    float o0 = (v0-mean)*rstd*g[tid]     + b[tid];
    float o1 = (v1-mean)*rstd*g[tid+256] + b[tid+256];
    float o2 = (v2-mean)*rstd*g[tid+512] + b[tid+512];
    if (yf){ float* yr = yf + (size_t)row*DIM; yr[tid]=o0; yr[tid+256]=o1; yr[tid+512]=o2; }
    if (yb){ u16* yr = yb + (size_t)row*DIM; yr[tid]=f2bf(o0); yr[tid+256]=f2bf(o1); yr[tid+512]=f2bf(o2); }
}

// ================= fused sup/ent mix + tanh + softmax: block per (b,n) =================
__global__ __launch_bounds__(256) void k_supsoft(
    const float* __restrict__ attn, u16* __restrict__ P,
    const float* __restrict__ wsup, const float* __restrict__ went)
{
    __shared__ float S[NHEADS][NSEQ];
    __shared__ float ws[144], we[144];
    int bn = blockIdx.x;
    int b = bn >> 9, n = bn & 511;
    int tid = threadIdx.x;
    if (tid < 144){ ws[tid] = wsup[tid]; we[tid] = went[tid]; }
    size_t base = ((size_t)b*NHEADS*NSEQ + n)*NSEQ;
    #pragma unroll
    for (int it=0; it<24; ++it){
        int idx = it*256 + tid;
        int j = idx >> 9, m = idx & 511;
        S[j][m] = attn[base + (size_t)j*NSEQ*NSEQ + m];
    }
    __syncthreads();
    #pragma unroll
    for (int half=0; half<2; ++half){
        int m = tid + half*256;
        float av[12], sup[12];
        #pragma unroll
        for (int j=0;j<12;j++) av[j] = S[j][m];
        #pragma unroll
        for (int i=0;i<12;i++){
            float s = 0.f;
            #pragma unroll
            for (int j=0;j<12;j++) s = fmaf(ws[i*12+j], av[j], s);
            sup[i] = s;
        }
        #pragma unroll
        for (int i=0;i<12;i++){
            float s = sup[i];
            #pragma unroll
            for (int j=0;j<12;j++) s = fmaf(we[i*12+j], sup[j], s);
            av[i] = tanhf(s);
        }
        #pragma unroll
        for (int i=0;i<12;i++) S[i][m] = av[i];
    }
    __syncthreads();
    int lane = tid & 63, wv = tid >> 6;
    #pragma unroll
    for (int jj=0; jj<3; ++jj){
        int j = wv*3 + jj;
        float v[8], mx = -1e30f;
        #pragma unroll
        for (int k=0;k<8;k++){ v[k] = S[j][lane + 64*k]; mx = fmaxf(mx, v[k]); }
        for (int off=32; off; off>>=1) mx = fmaxf(mx, __shfl_xor(mx, off));
        float sum = 0.f;
        #pragma unroll
        for (int k=0;k<8;k++){ v[k] = expf(v[k]-mx); sum += v[k]; }
        for (int off=32; off; off>>=1) sum += __shfl_xor(sum, off);
        float inv = 1.f/sum;
        #pragma unroll
        for (int k=0;k<8;k++) P[base + (size_t)j*NSEQ*NSEQ + lane + 64*k] = f2bf(v[k]*inv);
    }
}

// ================= V transpose (main attn): Vt[b][d][m] = qkv_bf[b][m][1536+d] =================
__global__ __launch_bounds__(256) void k_transv(const u16* __restrict__ qkv, u16* __restrict__ Vt)
{
    __shared__ u16 L[64][65];
    int mt = blockIdx.x*64, dt = blockIdx.y*64, b = blockIdx.z;
    int tid = threadIdx.x;
    #pragma unroll
    for (int it=0; it<16; ++it){
        int idx = it*256 + tid;
        int mm = idx >> 6, dd = idx & 63;
        L[mm][dd] = qkv[((size_t)b*NSEQ + mt + mm)*QKVC + 1536 + dt + dd];
    }
    __syncthreads();
    #pragma unroll
    for (int it=0; it<16; ++it){
        int idx = it*256 + tid;
        int dd = idx >> 6, mm = idx & 63;
        Vt[((size_t)b*DIM + dt + dd)*NSEQ + mt + mm] = L[mm][dd];
    }
}

// ================= MoE routing =================
__global__ __launch_bounds__(256) void k_route(
    const float* __restrict__ ln2, const float* __restrict__ Wr,
    const float* __restrict__ rb, const float* __restrict__ dr,
    const int* __restrict__ did, int* __restrict__ topi, float* __restrict__ topw, int* __restrict__ cnt)
{
    int t = blockIdx.x, tid = threadIdx.x;
    const float* xr = ln2 + (size_t)t*DIM;
    float a[8] = {};
    #pragma unroll
    for (int ii=0; ii<3; ii++){
        int i = tid + ii*256;
        float xv = xr[i];
        #pragma unroll
        for (int e=0;e<8;e++) a[e] = fmaf(xv, Wr[e*DIM + i], a[e]);
    }
    #pragma unroll
    for (int e=0;e<8;e++)
        for (int off=32; off; off>>=1) a[e] += __shfl_xor(a[e], off);
    __shared__ float sred[4][8];
    int wid = tid >> 6;
    if ((tid & 63) == 0){
        #pragma unroll
        for (int e=0;e<8;e++) sred[wid][e] = a[e];
    }
    __syncthreads();
    if (tid == 0){
        int d = did[0];
        float lg[8];
        #pragma unroll
        for (int e=0;e<8;e++) lg[e] = sred[0][e]+sred[1][e]+sred[2][e]+sred[3][e] + rb[e] + dr[d*8+e];
        int i1 = 0; float v1 = lg[0];
        #pragma unroll
        for (int e=1;e<8;e++) if (lg[e] > v1){ v1 = lg[e]; i1 = e; }
        int i2 = -1; float v2 = -1e30f;
        #pragma unroll
        for (int e=0;e<8;e++) if (e != i1 && lg[e] > v2){ v2 = lg[e]; i2 = e; }
        float e2 = expf(v2 - v1);
        float inv = 1.f / (1.f + e2);
        topi[2*t] = i1; topi[2*t+1] = i2;
        topw[2*t] = inv; topw[2*t+1] = e2 * inv;
        atomicAdd(&cnt[i1], 1); atomicAdd(&cnt[i2], 1);
    }
}

__global__ void k_zero(int* p, int n){ int i = threadIdx.x; if (i < n) p[i] = 0; }

__global__ void k_prefix(const int* __restrict__ cnt, int* __restrict__ prefix){
    if (threadIdx.x == 0){ int s=0; for (int e=0;e<8;e++){ prefix[e]=s; s+=cnt[e]; } }
}

__global__ __launch_bounds__(256) void k_assign(
    const int* __restrict__ topi, const int* __restrict__ prefix,
    int* __restrict__ cnt2, int* __restrict__ rowof, int* __restrict__ tokof)
{
    int t = blockIdx.x*256 + threadIdx.x;
    if (t >= NTOK) return;
    #pragma unroll
    for (int k=0;k<2;k++){
        int e = topi[2*t+k];
        int slot = atomicAdd(&cnt2[e], 1);
        int row = prefix[e] + slot;
        rowof[2*t+k] = row;
        tokof[row] = t;
    }
}

// 16B-vectorized gather: i over 4096 * (768/8)
__global__ __launch_bounds__(256) void k_gather(const u16* __restrict__ src, const int* __restrict__ tokof, u16* __restrict__ dst)
{
    int i = blockIdx.x*256 + threadIdx.x;
    int row = i / 96, c = (i % 96) * 8;
    *(uint4*)&dst[(size_t)row*DIM + c] = *(const uint4*)&src[(size_t)tokof[row]*DIM + c];
}

__global__ __launch_bounds__(256) void k_combine(
    const float* __restrict__ att, const float* __restrict__ outg,
    const int* __restrict__ rowof, const float* __restrict__ topw,
    float* __restrict__ eo, u16* __restrict__ eob)
{
    size_t i = (size_t)blockIdx.x*256 + threadIdx.x;
    int t = (int)(i / DIM), c = (int)(i % DIM);
    int r0 = rowof[2*t], r1 = rowof[2*t+1];
    float v = att[i] + topw[2*t]*outg[(size_t)r0*DIM+c] + topw[2*t+1]*outg[(size_t)r1*DIM+c];
    eo[i] = v;
    eob[i] = f2bf(v);
}

// ================= host =================
extern "C" void kernel_launch(void* const* d_in, const int* in_sizes, int n_in,
                              void* d_out, int out_size, void* d_ws, size_t ws_size,
                              hipStream_t stream)
{
    const float* x     = (const float*)d_in[0];
    const float* ln1g  = (const float*)d_in[1];
    const float* ln1b  = (const float*)d_in[2];
    const float* ln2g  = (const float*)d_in[3];
    const float* ln2b  = (const float*)d_in[4];
    const float* ln3g  = (const float*)d_in[5];
    const float* ln3b  = (const float*)d_in[6];
    const float* qkvA  = (const float*)d_in[7];
    const float* qkvS  = (const float*)d_in[8];
    const float* qkvb  = (const float*)d_in[9];
    const float* projA = (const float*)d_in[10];
    const float* projS = (const float*)d_in[11];
    const float* projb = (const float*)d_in[12];
    const float* wsup  = (const float*)d_in[13];
    const float* went  = (const float*)d_in[14];
    const float* rA    = (const float*)d_in[15];
    const float* rS    = (const float*)d_in[16];
    const float* rb    = (const float*)d_in[17];
    const float* dr    = (const float*)d_in[18];
    const float* eA    = (const float*)d_in[19];
    const float* eS    = (const float*)d_in[20];
    const float* eb    = (const float*)d_in[21];
    const float* ndw   = (const float*)d_in[22];
    const float* ndb   = (const float*)d_in[23];
    const float* mem0  = (const float*)d_in[24];
    const float* mem1  = (const float*)d_in[25];
    const float* mem2  = (const float*)d_in[26];
    const float* inw   = (const float*)d_in[27];
    const float* inb   = (const float*)d_in[28];
    const float* outw  = (const float*)d_in[29];
    const float* outb  = (const float*)d_in[30];
    const float* pw    = (const float*)d_in[31];
    const float* pb    = (const float*)d_in[32];
    const int*   did   = (const int*)d_in[33];

    float* f = (float*)d_ws;
    size_t off = 0;
    auto alloc = [&](size_t n){ float* p = f + off; off += (n + 3) & ~(size_t)3; return p; };
    auto allocb = [&](size_t n){ return (u16*)alloc((n + 1) / 2); };

    // fp32 buffers
    float* lnbuf  = alloc((size_t)NTOK*DIM);
    float* attnd  = alloc((size_t)NTOK*DIM);
    float* eo     = alloc((size_t)NTOK*DIM);
    float* accum  = alloc((size_t)NTOK*DIM);
    float* attnb  = alloc((size_t)48*NSEQ*NSEQ);   // scores; hosts outg + ndw_bf; later Smem
    float* Wrout  = alloc((size_t)NEXP*DIM);
    float* topw   = alloc((size_t)2*NTOK);
    float* bcb    = alloc((size_t)3*DIM);
    int* ip = (int*)alloc((size_t)6*NTOK + 64);
    int* topi   = ip;            ip += 2*NTOK;
    int* rowof  = ip;            ip += 2*NTOK;
    int* tokof  = ip;            ip += 2*NTOK;
    int* cnt    = ip;            ip += 8;
    int* cnt2   = ip;            ip += 8;
    int* prefix = ip;            ip += 8;

    // aliases inside attnb
    float* outg   = attnb;                               // 4096x768 fp32
    u16*   ndw_bf = (u16*)(attnb + (size_t)3146240);     // 18.87M u16
    float* Smem   = attnb;                               // fractal-phase scores

    // bf16 buffers
    u16* Wqkv_bf  = allocb((size_t)QKVC*DIM);
    u16* Wproj_bf = allocb((size_t)DD);
    u16* Wexp_bf  = allocb((size_t)NEXP*EDIM*DIM);
    u16* inw_bf   = allocb((size_t)3*QKVC*DIM);
    u16* outw_bf  = allocb((size_t)3*DD);
    u16* pw_bf    = allocb((size_t)3*DD);
    u16* Wc_bf    = allocb((size_t)3*DD);
    u16* wT_bf    = allocb((size_t)DD);
    u16* mem_bf   = allocb((size_t)448*DIM);
    u16* qkv_bf   = allocb((size_t)NTOK*QKVC);     // hosts Xg_bf later
    u16* Vt_bf    = allocb((size_t)NBATCH*DIM*NSEQ);
    u16* P_bf     = allocb((size_t)48*NSEQ*NSEQ);  // also hidden_bf, later Pm_bf
    u16* lnx_bf   = allocb((size_t)NTOK*DIM);
    u16* o_bf     = allocb((size_t)NTOK*DIM);      // attn out; later qm_bf
    u16* inx_bf   = allocb((size_t)NTOK*DIM);
    u16* mhao_bf  = allocb((size_t)NTOK*DIM);
    u16* kv_bf    = allocb((size_t)256*2*DIM);     // [M][1536] fused K|V
    u16* Vtm_bf   = allocb((size_t)MHEADS*MHD*256);
    u16* Xg_bf    = qkv_bf;
    u16* hidden_bf= P_bf;
    u16* Pm_bf    = P_bf;
    u16* qm_bf    = o_bf;

    float* outf = (float*)d_out;
    dim3 T256(256), T64(64);

    k_zero<<<1, 32, 0, stream>>>(cnt, 16);
    k_ln<<<NTOK, T256, 0, stream>>>(x, ln1g, ln1b, nullptr, lnx_bf);
    // PHM weight builds (bf16 except router)
    k_phm<<<dim3((QKVC*DIM+255)/256,1), T256, 0, stream>>>(qkvA, qkvS, Wqkv_bf, 576, 192, DIM, 0,0,0, 1);
    k_phm<<<dim3((DD+255)/256,1),  T256, 0, stream>>>(projA, projS, Wproj_bf, 192, 192, DIM, 0,0,0, 1);
    k_phm<<<dim3((NEXP*DIM+255)/256,1), T256, 0, stream>>>(rA, rS, Wrout, 2, 192, DIM, 0,0,0, 0);
    k_phm<<<dim3((EDIM*DIM+255)/256,NEXP), T256, 0, stream>>>(eA, eS, Wexp_bf, 768, 192, DIM,
                                                              64L, (long)4*768*192, (long)EDIM*DIM, 1);
    // weight converts (fp32 -> bf16)
    k_cvt4<<<2048, T256, 0, stream>>>((const float4*)inw,  (ushort4*)inw_bf,  3*QKVC*DIM/4);
    k_cvt4<<<1024, T256, 0, stream>>>((const float4*)outw, (ushort4*)outw_bf, 3*DD/4);
    k_cvt4<<<1024, T256, 0, stream>>>((const float4*)pw,   (ushort4*)pw_bf,   3*DD/4);
    k_cvt4<<<128,  T256, 0, stream>>>((const float4*)mem0, (ushort4*)mem_bf,               64*DIM/4);
    k_cvt4<<<128,  T256, 0, stream>>>((const float4*)mem1, (ushort4*)(mem_bf + 64*DIM),   128*DIM/4);
    k_cvt4<<<256,  T256, 0, stream>>>((const float4*)mem2, (ushort4*)(mem_bf + 192*DIM),  256*DIM/4);
    // fused fractal out-proj: Wc[l] = pw[l] @ outw[l]; bc[l] = pw[l]@outb[l] + pb[l]
    k_bc<<<dim3(DIM/4, 3), T256, 0, stream>>>(pw, outb, pb, bcb);
    for (int l=0; l<3; ++l){
        k_transvm<<<dim3((DD+255)/256), T256, 0, stream>>>(outw_bf + (size_t)l*DD, DIM, wT_bf, DIM);
        k_mgemm<2,2,2><<<dim3(12,12), T256, 0, stream>>>(pw_bf + (size_t)l*DD, DIM, DIM, wT_bf, DIM, DIM, DIM,
                                                         nullptr, nullptr, 0, nullptr, Wc_bf + (size_t)l*DD, DIM, 1.f, 0);
    }

    // ---- quantum attention ----
    k_mgemm<2,2,4><<<dim3(16,18), T256, 0, stream>>>(lnx_bf, DIM, NTOK, Wqkv_bf, DIM, QKVC, DIM,
                                                     qkvb, nullptr, 0, nullptr, qkv_bf, QKVC, 1.f, 0);
    k_transv<<<dim3(8,12,NBATCH), T256, 0, stream>>>(qkv_bf, Vt_bf);
    k_mgemm_qk<2,2,4><<<dim3(4,4,48), T256, 0, stream>>>(qkv_bf, attnb);
    k_supsoft<<<dim3(NTOK), T256, 0, stream>>>(attnb, P_bf, wsup, went);
    k_cvt4<<<4096, T256, 0, stream>>>((const float4*)ndw, (ushort4*)ndw_bf, NEXP*DIM*EDIM/4);
    k_mgemm_pv<1,1,2><<<dim3(16,2,48), T64, 0, stream>>>(P_bf, Vt_bf, o_bf);
    k_mgemm<2,2,2><<<dim3(32,12), T256, 0, stream>>>(o_bf, DIM, NTOK, Wproj_bf, DIM, DIM, DIM,
                                                     projb, x, DIM, attnd, nullptr, DIM, 1.f, 0);
    // ---- MoE ----
    k_ln<<<NTOK, T256, 0, stream>>>(attnd, ln2g, ln2b, lnbuf, lnx_bf);
    k_route<<<NTOK, T256, 0, stream>>>(lnbuf, Wrout, rb, dr, did, topi, topw, cnt);
    k_prefix<<<1, 1, 0, stream>>>(cnt, prefix);
    k_assign<<<8, T256, 0, stream>>>(topi, prefix, cnt2, rowof, tokof);
    k_gather<<<dim3(1536), T256, 0, stream>>>(lnx_bf, tokof, Xg_bf);
    k_mgemm_expert<2,2,4><<<dim3(16,24,NEXP), T256, 0, stream>>>(Xg_bf, DIM, Wexp_bf, DIM, (long)EDIM*DIM,
                                                                 eb, EDIM, prefix, cnt,
                                                                 nullptr, hidden_bf, EDIM, EDIM, DIM, 1);
    k_mgemm_expert<2,2,2><<<dim3(32,12,NEXP), T256, 0, stream>>>(hidden_bf, EDIM, ndw_bf, EDIM, (long)DIM*EDIM,
                                                                 ndb, DIM, prefix, cnt,
                                                                 outg, nullptr, DIM, DIM, EDIM, 0);
    k_combine<<<dim3(6144), T256, 0, stream>>>(attnd, outg, rowof, topw, eo, inx_bf);
    // ---- fractal memory (3 levels) ----
    int Ms[3] = {64, 128, 256};
    long moff[3] = {0, 64L*DIM, 192L*DIM};
    for (int l=0; l<3; ++l){
        const u16* iwl = inw_bf + (size_t)l*QKVC*DIM;
        int M = Ms[l];
        k_mgemm<2,2,2><<<dim3(32,12), T256, 0, stream>>>(inx_bf, DIM, NTOK, iwl, DIM, DIM, DIM,
                                                         inb + (size_t)l*QKVC, nullptr, 0, nullptr, qm_bf, DIM, 1.f, 0);
        // fused K|V projection: N=1536
        k_mgemm<1,1,2><<<dim3(M/32,48), T64, 0, stream>>>(mem_bf + moff[l], DIM, M, iwl + (size_t)DD, DIM, 2*DIM, DIM,
                                                          inb + (size_t)l*QKVC + DIM, nullptr, 0, nullptr, kv_bf, 2*DIM, 1.f, 0);
        k_mgemm_memqk<1,1,2><<<dim3(64, M/32, MHEADS), T64, 0, stream>>>(qm_bf, kv_bf, 2*DIM, Smem, M, 0.10206207261596577f);
        k_softmax_mem<<<dim3(MHEADS*NTOK), T64, 0, stream>>>(Smem, Pm_bf, M);
        k_transvm<<<dim3((DIM*M+255)/256), T256, 0, stream>>>(kv_bf + DIM, 2*DIM, Vtm_bf, M);
        k_mgemm_mempv<1,1,2><<<dim3(64,3,MHEADS), T64, 0, stream>>>(Pm_bf, Vtm_bf, mhao_bf, M);
        // fused (out-proj ∘ proc-proj): a_l = mhao @ Wc^T + bc ; accum += a_l ; inx_bf = bf16(a_l)
        k_mgemm<2,2,2><<<dim3(32,12), T256, 0, stream>>>(mhao_bf, DIM, NTOK, Wc_bf + (size_t)l*DD, DIM, DIM, DIM,
                                                         bcb + (size_t)l*DIM, (l==0 ? eo : accum), DIM,
                                                         accum, inx_bf, DIM, 1.f, 0);
    }
    k_ln<<<NTOK, T256, 0, stream>>>(accum, ln3g, ln3b, outf, nullptr);
}

// Round 6
// 716.782 us; speedup vs baseline: 6.3575x; 1.0695x over previous
//
#include <hip/hip_runtime.h>
#include <math.h>

#define DIM    768
#define NTOK   2048
#define NSEQ   512
#define NBATCH 4
#define NHEADS 12
#define HD     64
#define QKVC   2304
#define MHEADS 8
#define MHD    96
#define NEXP   8
#define EDIM   3072
#define DD     (DIM*DIM)

typedef unsigned short u16;
typedef __attribute__((ext_vector_type(8))) short short8;
typedef __attribute__((ext_vector_type(4))) float f32x4;

struct L3 { long a, b, c; };
struct I3 { int a, b, c; };
struct CJ { const float4* s[6]; ushort4* d[6]; int n4[6]; };

__device__ __forceinline__ float gelu_exact(float v){
    return 0.5f * v * (1.f + erff(v * 0.70710678118654752f));
}
__device__ __forceinline__ u16 f2bf(float f){
    unsigned int u = __builtin_bit_cast(unsigned int, f);
    unsigned int r = (u + 0x7FFFu + ((u >> 16) & 1u)) >> 16;
    return (u16)r;
}
__device__ __forceinline__ float fast_tanh(float s){
    return 1.f - 2.f/(__expf(2.f*s) + 1.f);
}
// async global->LDS, 16B per lane; LDS dest linear (wave-uniform base + lane*16)
__device__ __forceinline__ void gll16(const u16* g, u16* l){
    __builtin_amdgcn_global_load_lds((const __attribute__((address_space(1))) void*)g,
                                     (__attribute__((address_space(3))) void*)l, 16, 0, 0);
}

// ================= MFMA bf16 GEMM core, 2-stage pipelined =================
// Per-wave tile (16*FR)^2; block tile (WM*16*FR)x(WN*16*FR); BK=64; WM*WN waves.
// Double-buffered LDS: STAGE(t+1) issued BEFORE compute(t); ONE barrier per k-step
// (its implicit vmcnt/lgkmcnt drain covers both). XOR-swizzled LDS via pre-swizzled
// global SOURCE + linear global_load_lds dest (m201 both-sides rule).
template<int WM,int WN,int FR>
__device__ __forceinline__ void mgemm_core(
    const u16* __restrict__ Xb, int ldx, int rowBase, int rowLim,
    const u16* __restrict__ Wb, int ldw, int colBase, int colLim, int K,
    const float* __restrict__ bias,
    const float* __restrict__ res, int ldres,
    float* __restrict__ Cf, u16* __restrict__ Cb, int ldc,
    float scale, int act)
{
    constexpr int TM = 16*FR;
    constexpr int RM = WM*TM, RN = WN*TM, NT = WM*WN*64;
    constexpr int IA = (RM*8)/NT, IB = (RN*8)/NT;
    __shared__ u16 As[2][RM*64];
    __shared__ u16 Bs[2][RN*64];
    int tid = threadIdx.x;
    int lane = tid & 63, w = tid >> 6;
    int wm = (w / WN) * TM, wn = (w % WN) * TM;
    const f32x4 zf = {0.f, 0.f, 0.f, 0.f};
    f32x4 acc[FR][FR];
    #pragma unroll
    for (int i=0;i<FR;i++)
        #pragma unroll
        for (int j=0;j<FR;j++) acc[i][j] = zf;

    const bool fullA = (rowBase + RM <= rowLim);
    const bool fullB = (colBase + RN <= colLim);
    const int nt = (K + 63) >> 6;

    auto stage = [&](int buf, int k0){
        const bool kfull = (k0 + 64 <= K);
        if (fullA && kfull) {
            #pragma unroll
            for (int it = 0; it < IA; ++it) {
                int idx = it*NT + tid;
                int r = idx >> 3, c = idx & 7;
                gll16(&Xb[(size_t)(rowBase + r)*ldx + k0 + ((c ^ (r & 7)) << 3)], &As[buf][(size_t)idx*8]);
            }
        } else {
            #pragma unroll
            for (int it = 0; it < IA; ++it) {
                int idx = it*NT + tid;
                int r = idx >> 3, c = idx & 7;
                int gr = rowBase + r;
                uint4 v = {0u,0u,0u,0u};
                if (gr < rowLim && (k0 + c*8) < K) v = *(const uint4*)&Xb[(size_t)gr*ldx + k0 + c*8];
                *(uint4*)&As[buf][r*64 + ((c ^ (r & 7)) * 8)] = v;
            }
        }
        if (fullB && kfull) {
            #pragma unroll
            for (int it = 0; it < IB; ++it) {
                int idx = it*NT + tid;
                int r = idx >> 3, c = idx & 7;
                gll16(&Wb[(size_t)(colBase + r)*ldw + k0 + ((c ^ (r & 7)) << 3)], &Bs[buf][(size_t)idx*8]);
            }
        } else {
            #pragma unroll
            for (int it = 0; it < IB; ++it) {
                int idx = it*NT + tid;
                int r = idx >> 3, c = idx & 7;
                int gc = colBase + r;
                uint4 v = {0u,0u,0u,0u};
                if (gc < colLim && (k0 + c*8) < K) v = *(const uint4*)&Wb[(size_t)gc*ldw + k0 + c*8];
                *(uint4*)&Bs[buf][r*64 + ((c ^ (r & 7)) * 8)] = v;
            }
        }
    };

    stage(0, 0);
    __syncthreads();
    for (int t = 0; t < nt; ++t) {
        if (t + 1 < nt) stage((t+1)&1, (t+1)*64);     // prefetch overlaps compute below
        const u16* Ac = As[t&1];
        const u16* Bc = Bs[t&1];
        int lr = lane & 15, lk = lane >> 4;
        #pragma unroll
        for (int ks = 0; ks < 2; ++ks) {
            short8 af[FR], bfr[FR];
            #pragma unroll
            for (int mi=0; mi<FR; mi++){
                int row = wm + mi*16 + lr;
                int cidx = (ks*4 + lk) ^ (row & 7);
                af[mi] = *(const short8*)&Ac[row*64 + cidx*8];
            }
            #pragma unroll
            for (int ni=0; ni<FR; ni++){
                int col = wn + ni*16 + lr;
                int cidx = (ks*4 + lk) ^ (col & 7);
                bfr[ni] = *(const short8*)&Bc[col*64 + cidx*8];
            }
            #pragma unroll
            for (int mi=0; mi<FR; mi++)
                #pragma unroll
                for (int ni=0; ni<FR; ni++)
                    acc[mi][ni] = __builtin_amdgcn_mfma_f32_16x16x32_bf16(af[mi], bfr[ni], acc[mi][ni], 0, 0, 0);
        }
        __syncthreads();   // drains this iteration's prefetch (vmcnt) + LDS reads
    }
    // epilogue: D row = (lane>>4)*4 + reg, col = lane&15  [m89-verified]
    int lr = lane & 15, lg = lane >> 4;
    #pragma unroll
    for (int mi=0; mi<FR; mi++){
        #pragma unroll
        for (int r=0; r<4; r++){
            int row = rowBase + wm + mi*16 + lg*4 + r;
            if (row >= rowLim) continue;
            #pragma unroll
            for (int ni=0; ni<FR; ni++){
                int col = colBase + wn + ni*16 + lr;
                if (col >= colLim) continue;
                float v = acc[mi][ni][r] * scale;
                if (bias) v += bias[col];
                if (act == 1) v = gelu_exact(v);
                if (Cb) Cb[(size_t)row*ldc + col] = f2bf(v);
                if (res) v += res[(size_t)row*ldres + col];
                if (Cf) Cf[(size_t)row*ldc + col] = v;
            }
        }
    }
}

template<int WM,int WN,int FR>
__global__ __launch_bounds__(WM*WN*64) void k_mgemm(
    const u16* __restrict__ X, int ldx, int M,
    const u16* __restrict__ W, int ldw, int N, int K,
    const float* __restrict__ bias, const float* __restrict__ res, int ldres,
    float* __restrict__ Cf, u16* __restrict__ Cb, int ldc, float scale, int act)
{
    constexpr int RM = WM*16*FR, RN = WN*16*FR;
    mgemm_core<WM,WN,FR>(X, ldx, blockIdx.x*RM, M, W, ldw, blockIdx.y*RN, N, K,
                         bias, res, ldres, Cf, Cb, ldc, scale, act);
}

// batched-by-3 variant: z selects offsets into X/W/bias/C and M
template<int WM,int WN,int FR>
__global__ __launch_bounds__(WM*WN*64) void k_mgemm_b3(
    const u16* __restrict__ X, L3 xo, int ldx, I3 Mv,
    const u16* __restrict__ W, L3 wo, int ldw, int N, int K,
    const float* __restrict__ bias, L3 bo,
    u16* __restrict__ Cb, L3 co, int ldc, float scale, int act)
{
    constexpr int RM = WM*16*FR, RN = WN*16*FR;
    int z = blockIdx.z;
    int M    = (z==0) ? Mv.a : (z==1) ? Mv.b : Mv.c;
    long xof = (z==0) ? xo.a : (z==1) ? xo.b : xo.c;
    long wof = (z==0) ? wo.a : (z==1) ? wo.b : wo.c;
    long bof = (z==0) ? bo.a : (z==1) ? bo.b : bo.c;
    long cof = (z==0) ? co.a : (z==1) ? co.b : co.c;
    if ((int)blockIdx.x * RM >= M) return;
    mgemm_core<WM,WN,FR>(X + xof, ldx, blockIdx.x*RM, M, W + wof, ldw, blockIdx.y*RN, N, K,
                         bias ? bias + bof : nullptr, nullptr, 0, nullptr, Cb + cof, ldc, scale, act);
}

template<int WM,int WN,int FR>
__global__ __launch_bounds__(WM*WN*64) void k_mgemm_expert(
    const u16* __restrict__ X, int ldx,
    const u16* __restrict__ Wb, int ldw, long wStride,
    const float* __restrict__ biasB, int biasStride,
    const int* __restrict__ prefix, const int* __restrict__ cnt,
    float* __restrict__ Cf, u16* __restrict__ Cb, int ldc, int N, int K, int act)
{
    constexpr int RM = WM*16*FR, RN = WN*16*FR;
    int e = blockIdx.z;
    int n = cnt[e];
    if ((int)blockIdx.x * RM >= n) return;
    mgemm_core<WM,WN,FR>(X, ldx, prefix[e] + blockIdx.x*RM, prefix[e] + n,
                         Wb + (size_t)e*wStride, ldw, blockIdx.y*RN, N, K,
                         biasB + (size_t)e*biasStride, nullptr, 0, Cf, Cb, ldc, 1.f, act);
}

// scores[b,h,n,m] = 0.125 * q_n . k_m
template<int WM,int WN,int FR>
__global__ __launch_bounds__(WM*WN*64) void k_mgemm_qk(const u16* __restrict__ qkv, float* __restrict__ attn)
{
    constexpr int RM = WM*16*FR, RN = WN*16*FR;
    int z = blockIdx.z, b = z / NHEADS, h = z % NHEADS;
    const u16* X = qkv + (size_t)b*NSEQ*QKVC + h*HD;          // q
    const u16* W = qkv + (size_t)b*NSEQ*QKVC + DIM + h*HD;    // k
    float* C = attn + (size_t)z*NSEQ*NSEQ;
    mgemm_core<WM,WN,FR>(X, QKVC, blockIdx.x*RM, NSEQ, W, QKVC, blockIdx.y*RN, NSEQ, HD,
                         nullptr, nullptr, 0, C, nullptr, NSEQ, 0.125f, 0);
}

// o[b,n,h*64+d] = sum_m P[b,h,n,m] * V[b,m,h*64+d]; Vt[b][d][m] supplies W
template<int WM,int WN,int FR>
__global__ __launch_bounds__(WM*WN*64) void k_mgemm_pv(const u16* __restrict__ P, const u16* __restrict__ Vt, u16* __restrict__ o)
{
    constexpr int RM = WM*16*FR, RN = WN*16*FR;
    int z = blockIdx.z, b = z / NHEADS, h = z % NHEADS;
    const u16* X = P + (size_t)z*NSEQ*NSEQ;
    const u16* W = Vt + ((size_t)b*DIM + h*HD)*NSEQ;
    u16* C = o + (size_t)b*NSEQ*DIM + h*HD;
    mgemm_core<WM,WN,FR>(X, NSEQ, blockIdx.x*RM, NSEQ, W, NSEQ, blockIdx.y*RN, HD, NSEQ,
                         nullptr, nullptr, 0, nullptr, C, DIM, 1.f, 0);
}

// mem-MHA scores: S[h][n][m] = scale * q[n, h*96:..] . k[m, h*96:..]   (K=96)
template<int WM,int WN,int FR>
__global__ __launch_bounds__(WM*WN*64) void k_mgemm_memqk(const u16* __restrict__ q, const u16* __restrict__ k, int ldk,
                                                          float* __restrict__ S, int M, float scale)
{
    constexpr int RM = WM*16*FR, RN = WN*16*FR;
    int h = blockIdx.z;
    mgemm_core<WM,WN,FR>(q + h*MHD, DIM, blockIdx.x*RM, NTOK, k + h*MHD, ldk, blockIdx.y*RN, M, MHD,
                         nullptr, nullptr, 0, S + (size_t)h*NTOK*M, nullptr, M, scale, 0);
}

// mem-MHA PV: O[n, h*96+d] = sum_m P[h][n][m] * Vt[h*96+d][m]
template<int WM,int WN,int FR>
__global__ __launch_bounds__(WM*WN*64) void k_mgemm_mempv(const u16* __restrict__ P, const u16* __restrict__ Vt,
                                                          u16* __restrict__ O, int M)
{
    constexpr int RM = WM*16*FR, RN = WN*16*FR;
    int h = blockIdx.z;
    mgemm_core<WM,WN,FR>(P + (size_t)h*NTOK*M, M, blockIdx.x*RM, NTOK, Vt + (size_t)h*MHD*M, M,
                         blockIdx.y*RN, MHD, M,
                         nullptr, nullptr, 0, nullptr, O + h*MHD, DIM, 1.f, 0);
}

// batched outw transpose: wT3[z][c][r] = outw[z][r][c], 768x768 each
__global__ __launch_bounds__(256) void k_transw_b(const u16* __restrict__ src, u16* __restrict__ dst)
{
    int z = blockIdx.y;
    int idx = blockIdx.x*256 + threadIdx.x;
    int r = idx / DIM, c = idx % DIM;
    dst[(size_t)z*DD + (size_t)c*DIM + r] = src[(size_t)z*DD + (size_t)r*DIM + c];
}

// batched V transpose from fused KV: Vtm3[z][d][m] = kvL[z][m][768+d], m<M_z
__global__ __launch_bounds__(256) void k_transvm_b(const u16* __restrict__ kvL, u16* __restrict__ Vtm3, I3 Mv)
{
    int z = blockIdx.y;
    int M = (z==0) ? Mv.a : (z==1) ? Mv.b : Mv.c;
    int idx = blockIdx.x*256 + threadIdx.x;
    if (idx >= DIM*M) return;
    int m = idx / DIM, d = idx % DIM;
    Vtm3[(size_t)z*DIM*256 + (size_t)d*M + m] = kvL[(size_t)z*256*2*DIM + (size_t)m*2*DIM + DIM + d];
}

// softmax over row of length M (<=256), fp32 in -> bf16 out
__global__ __launch_bounds__(64) void k_softmax_mem(const float* __restrict__ S, u16* __restrict__ P, int M)
{
    size_t base = (size_t)blockIdx.x * M;
    int lane = threadIdx.x;
    float mx = -1e30f;
    for (int i = lane; i < M; i += 64) mx = fmaxf(mx, S[base+i]);
    for (int off=32; off; off>>=1) mx = fmaxf(mx, __shfl_xor(mx, off));
    float sum = 0.f;
    for (int i = lane; i < M; i += 64) sum += __expf(S[base+i]-mx);
    for (int off=32; off; off>>=1) sum += __shfl_xor(sum, off);
    float inv = 1.f/sum;
    for (int i = lane; i < M; i += 64) P[base+i] = f2bf(__expf(S[base+i]-mx)*inv);
}

// ================= PHM weight materialization =================
__global__ __launch_bounds__(256) void k_phm(
    const float* __restrict__ A, const float* __restrict__ S, void* __restrict__ W,
    int So, int Si, int inF, long Astride, long Sstride, long Wstride, int obf)
{
    int e = blockIdx.y;
    const float* Ae = A + (size_t)e*Astride;
    const float* Se = S + (size_t)e*Sstride;
    size_t idx = (size_t)blockIdx.x*256 + threadIdx.x;
    size_t total = (size_t)(So*4) * inF;
    if (idx >= total) return;
    int in = (int)(idx % inF);
    int o  = (int)(idx / inF);
    int a = o / So, c = o % So, b = in / Si, d = in % Si;
    float w = 0.f;
    #pragma unroll
    for (int i=0;i<4;i++) w = fmaf(Ae[i*16 + a*4 + b], Se[((size_t)i*So + c)*Si + d], w);
    if (obf) ((u16*)W)[(size_t)e*Wstride + idx] = f2bf(w);
    else     ((float*)W)[(size_t)e*Wstride + idx] = w;
}

// ================= fp32 -> bf16 converts =================
__global__ __launch_bounds__(256) void k_cvt4(const float4* __restrict__ s, ushort4* __restrict__ d, int n4)
{
    for (int i = blockIdx.x*256 + threadIdx.x; i < n4; i += gridDim.x*256){
        float4 v = s[i];
        ushort4 o; o.x = f2bf(v.x); o.y = f2bf(v.y); o.z = f2bf(v.z); o.w = f2bf(v.w);
        d[i] = o;
    }
}
__global__ __launch_bounds__(256) void k_cvt_multi(CJ J)
{
    int z = blockIdx.y;
    const float4* s = J.s[z]; ushort4* d = J.d[z]; int n4 = J.n4[z];
    for (int i = blockIdx.x*256 + threadIdx.x; i < n4; i += gridDim.x*256){
        float4 v = s[i];
        ushort4 o; o.x = f2bf(v.x); o.y = f2bf(v.y); o.z = f2bf(v.z); o.w = f2bf(v.w);
        d[i] = o;
    }
}

// bc[l][i] = dot(pw[l][i][:], outb[l][:]) + pb[l][i]
__global__ __launch_bounds__(256) void k_bc(const float* __restrict__ pw, const float* __restrict__ outb,
                                            const float* __restrict__ pb, float* __restrict__ bc)
{
    int l = blockIdx.y;
    int i = blockIdx.x*4 + (threadIdx.x >> 6);
    int lane = threadIdx.x & 63;
    const float* pr = pw + ((size_t)l*DIM + i)*DIM;
    const float* ob = outb + (size_t)l*DIM;
    float s = 0.f;
    for (int j = lane; j < DIM; j += 64) s = fmaf(pr[j], ob[j], s);
    for (int off=32; off; off>>=1) s += __shfl_xor(s, off);
    if (lane == 0) bc[(size_t)l*DIM + i] = s + pb[(size_t)l*DIM + i];
}

// ================= LayerNorm (row=768), dual output =================
__global__ __launch_bounds__(256) void k_ln(const float* __restrict__ x, const float* __restrict__ g,
                                            const float* __restrict__ b,
                                            float* __restrict__ yf, u16* __restrict__ yb)
{
    int row = blockIdx.x, tid = threadIdx.x;
    const float* xr = x + (size_t)row * DIM;
    float v0 = xr[tid], v1 = xr[tid+256], v2 = xr[tid+512];
    float s = v0+v1+v2;
    float ss = v0*v0 + v1*v1 + v2*v2;
    for (int off=32; off; off>>=1){ s += __shfl_xor(s,off); ss += __shfl_xor(ss,off); }
    __shared__ float sa[4], sb[4];
    int wid = tid >> 6;
    if ((tid & 63) == 0){ sa[wid]=s; sb[wid]=ss; }
    __syncthreads();
    s  = sa[0]+sa[1]+sa[2]+sa[3];
    ss = sb[0]+sb[1]+sb[2]+sb[3];
    float mean = s * (1.f/DIM);
    float var  = ss * (1.f/DIM) - mean*mean;
    float rstd = rsqrtf(var + 1e-5f);
    float o0 = (v0-mean)*rstd*g[tid]     + b[tid];
    float o1 = (v1-mean)*rstd*g[tid+256] + b[tid+256];
    float o2 = (v2-mean)*rstd*g[tid+512] + b[tid+512];
    if (yf){ float* yr = yf + (size_t)row*DIM; yr[tid]=o0; yr[tid+256]=o1; yr[tid+512]=o2; }
    if (yb){ u16* yr = yb + (size_t)row*DIM; yr[tid]=f2bf(o0); yr[tid+256]=f2bf(o1); yr[tid+512]=f2bf(o2); }
}

// ================= fused sup/ent mix + tanh + softmax: block per (b,n) =================
__global__ __launch_bounds__(256) void k_supsoft(
    const float* __restrict__ attn, u16* __restrict__ P,
    const float* __restrict__ wsup, const float* __restrict__ went)
{
    __shared__ float S[NHEADS][NSEQ];
    __shared__ float ws[144], we[144];
    int bn = blockIdx.x;
    int b = bn >> 9, n = bn & 511;
    int tid = threadIdx.x;
    if (tid < 144){ ws[tid] = wsup[tid]; we[tid] = went[tid]; }
    size_t base = ((size_t)b*NHEADS*NSEQ + n)*NSEQ;
    #pragma unroll
    for (int it=0; it<24; ++it){
        int idx = it*256 + tid;
        int j = idx >> 9, m = idx & 511;
        S[j][m] = attn[base + (size_t)j*NSEQ*NSEQ + m];
    }
    __syncthreads();
    #pragma unroll
    for (int half=0; half<2; ++half){
        int m = tid + half*256;
        float av[12], sup[12];
        #pragma unroll
        for (int j=0;j<12;j++) av[j] = S[j][m];
        #pragma unroll
        for (int i=0;i<12;i++){
            float s = 0.f;
            #pragma unroll
            for (int j=0;j<12;j++) s = fmaf(ws[i*12+j], av[j], s);
            sup[i] = s;
        }
        #pragma unroll
        for (int i=0;i<12;i++){
            float s = sup[i];
            #pragma unroll
            for (int j=0;j<12;j++) s = fmaf(we[i*12+j], sup[j], s);
            av[i] = fast_tanh(s);
        }
        #pragma unroll
        for (int i=0;i<12;i++) S[i][m] = av[i];
    }
    __syncthreads();
    int lane = tid & 63, wv = tid >> 6;
    #pragma unroll
    for (int jj=0; jj<3; ++jj){
        int j = wv*3 + jj;
        float v[8], mx = -1e30f;
        #pragma unroll
        for (int k=0;k<8;k++){ v[k] = S[j][lane + 64*k]; mx = fmaxf(mx, v[k]); }
        for (int off=32; off; off>>=1) mx = fmaxf(mx, __shfl_xor(mx, off));
        float sum = 0.f;
        #pragma unroll
        for (int k=0;k<8;k++){ v[k] = __expf(v[k]-mx); sum += v[k]; }
        for (int off=32; off; off>>=1) sum += __shfl_xor(sum, off);
        float inv = 1.f/sum;
        #pragma unroll
        for (int k=0;k<8;k++) P[base + (size_t)j*NSEQ*NSEQ + lane + 64*k] = f2bf(v[k]*inv);
    }
}

// ================= V transpose (main attn): Vt[b][d][m] = qkv_bf[b][m][1536+d] =================
__global__ __launch_bounds__(256) void k_transv(const u16* __restrict__ qkv, u16* __restrict__ Vt)
{
    __shared__ u16 L[64][65];
    int mt = blockIdx.x*64, dt = blockIdx.y*64, b = blockIdx.z;
    int tid = threadIdx.x;
    #pragma unroll
    for (int it=0; it<16; ++it){
        int idx = it*256 + tid;
        int mm = idx >> 6, dd = idx & 63;
        L[mm][dd] = qkv[((size_t)b*NSEQ + mt + mm)*QKVC + 1536 + dt + dd];
    }
    __syncthreads();
    #pragma unroll
    for (int it=0; it<16; ++it){
        int idx = it*256 + tid;
        int dd = idx >> 6, mm = idx & 63;
        Vt[((size_t)b*DIM + dt + dd)*NSEQ + mt + mm] = L[mm][dd];
    }
}

// ================= MoE routing =================
__global__ __launch_bounds__(256) void k_route(
    const float* __restrict__ ln2, const float* __restrict__ Wr,
    const float* __restrict__ rb, const float* __restrict__ dr,
    const int* __restrict__ did, int* __restrict__ topi, float* __restrict__ topw, int* __restrict__ cnt)
{
    int t = blockIdx.x, tid = threadIdx.x;
    const float* xr = ln2 + (size_t)t*DIM;
    float a[8] = {};
    #pragma unroll
    for (int ii=0; ii<3; ii++){
        int i = tid + ii*256;
        float xv = xr[i];
        #pragma unroll
        for (int e=0;e<8;e++) a[e] = fmaf(xv, Wr[e*DIM + i], a[e]);
    }
    #pragma unroll
    for (int e=0;e<8;e++)
        for (int off=32; off; off>>=1) a[e] += __shfl_xor(a[e], off);
    __shared__ float sred[4][8];
    int wid = tid >> 6;
    if ((tid & 63) == 0){
        #pragma unroll
        for (int e=0;e<8;e++) sred[wid][e] = a[e];
    }
    __syncthreads();
    if (tid == 0){
        int d = did[0];
        float lg[8];
        #pragma unroll
        for (int e=0;e<8;e++) lg[e] = sred[0][e]+sred[1][e]+sred[2][e]+sred[3][e] + rb[e] + dr[d*8+e];
        int i1 = 0; float v1 = lg[0];
        #pragma unroll
        for (int e=1;e<8;e++) if (lg[e] > v1){ v1 = lg[e]; i1 = e; }
        int i2 = -1; float v2 = -1e30f;
        #pragma unroll
        for (int e=0;e<8;e++) if (e != i1 && lg[e] > v2){ v2 = lg[e]; i2 = e; }
        float e2 = __expf(v2 - v1);
        float inv = 1.f / (1.f + e2);
        topi[2*t] = i1; topi[2*t+1] = i2;
        topw[2*t] = inv; topw[2*t+1] = e2 * inv;
        atomicAdd(&cnt[i1], 1); atomicAdd(&cnt[i2], 1);
    }
}

__global__ void k_zero(int* p, int n){ int i = threadIdx.x; if (i < n) p[i] = 0; }

__global__ void k_prefix(const int* __restrict__ cnt, int* __restrict__ prefix){
    if (threadIdx.x == 0){ int s=0; for (int e=0;e<8;e++){ prefix[e]=s; s+=cnt[e]; } }
}

__global__ __launch_bounds__(256) void k_assign(
    const int* __restrict__ topi, const int* __restrict__ prefix,
    int* __restrict__ cnt2, int* __restrict__ rowof, int* __restrict__ tokof)
{
    int t = blockIdx.x*256 + threadIdx.x;
    if (t >= NTOK) return;
    #pragma unroll
    for (int k=0;k<2;k++){
        int e = topi[2*t+k];
        int slot = atomicAdd(&cnt2[e], 1);
        int row = prefix[e] + slot;
        rowof[2*t+k] = row;
        tokof[row] = t;
    }
}

// 16B-vectorized gather: i over 4096 * (768/8)
__global__ __launch_bounds__(256) void k_gather(const u16* __restrict__ src, const int* __restrict__ tokof, u16* __restrict__ dst)
{
    int i = blockIdx.x*256 + threadIdx.x;
    int row = i / 96, c = (i % 96) * 8;
    *(uint4*)&dst[(size_t)row*DIM + c] = *(const uint4*)&src[(size_t)tokof[row]*DIM + c];
}

__global__ __launch_bounds__(256) void k_combine(
    const float* __restrict__ att, const float* __restrict__ outg,
    const int* __restrict__ rowof, const float* __restrict__ topw,
    float* __restrict__ eo, u16* __restrict__ eob)
{
    size_t i = (size_t)blockIdx.x*256 + threadIdx.x;
    int t = (int)(i / DIM), c = (int)(i % DIM);
    int r0 = rowof[2*t], r1 = rowof[2*t+1];
    float v = att[i] + topw[2*t]*outg[(size_t)r0*DIM+c] + topw[2*t+1]*outg[(size_t)r1*DIM+c];
    eo[i] = v;
    eob[i] = f2bf(v);
}

// ================= host =================
extern "C" void kernel_launch(void* const* d_in, const int* in_sizes, int n_in,
                              void* d_out, int out_size, void* d_ws, size_t ws_size,
                              hipStream_t stream)
{
    const float* x     = (const float*)d_in[0];
    const float* ln1g  = (const float*)d_in[1];
    const float* ln1b  = (const float*)d_in[2];
    const float* ln2g  = (const float*)d_in[3];
    const float* ln2b  = (const float*)d_in[4];
    const float* ln3g  = (const float*)d_in[5];
    const float* ln3b  = (const float*)d_in[6];
    const float* qkvA  = (const float*)d_in[7];
    const float* qkvS  = (const float*)d_in[8];
    const float* qkvb  = (const float*)d_in[9];
    const float* projA = (const float*)d_in[10];
    const float* projS = (const float*)d_in[11];
    const float* projb = (const float*)d_in[12];
    const float* wsup  = (const float*)d_in[13];
    const float* went  = (const float*)d_in[14];
    const float* rA    = (const float*)d_in[15];
    const float* rS    = (const float*)d_in[16];
    const float* rb    = (const float*)d_in[17];
    const float* dr    = (const float*)d_in[18];
    const float* eA    = (const float*)d_in[19];
    const float* eS    = (const float*)d_in[20];
    const float* eb    = (const float*)d_in[21];
    const float* ndw   = (const float*)d_in[22];
    const float* ndb   = (const float*)d_in[23];
    const float* mem0  = (const float*)d_in[24];
    const float* mem1  = (const float*)d_in[25];
    const float* mem2  = (const float*)d_in[26];
    const float* inw   = (const float*)d_in[27];
    const float* inb   = (const float*)d_in[28];
    const float* outw  = (const float*)d_in[29];
    const float* outb  = (const float*)d_in[30];
    const float* pw    = (const float*)d_in[31];
    const float* pb    = (const float*)d_in[32];
    const int*   did   = (const int*)d_in[33];

    float* f = (float*)d_ws;
    size_t off = 0;
    auto alloc = [&](size_t n){ float* p = f + off; off += (n + 3) & ~(size_t)3; return p; };
    auto allocb = [&](size_t n){ return (u16*)alloc((n + 1) / 2); };

    // fp32 buffers
    float* lnbuf  = alloc((size_t)NTOK*DIM);
    float* attnd  = alloc((size_t)NTOK*DIM);
    float* eo     = alloc((size_t)NTOK*DIM);
    float* accum  = alloc((size_t)NTOK*DIM);
    float* attnb  = alloc((size_t)48*NSEQ*NSEQ);   // scores; hosts outg + ndw_bf; later Smem
    float* Wrout  = alloc((size_t)NEXP*DIM);
    float* topw   = alloc((size_t)2*NTOK);
    float* bcb    = alloc((size_t)3*DIM);
    int* ip = (int*)alloc((size_t)6*NTOK + 64);
    int* topi   = ip;            ip += 2*NTOK;
    int* rowof  = ip;            ip += 2*NTOK;
    int* tokof  = ip;            ip += 2*NTOK;
    int* cnt    = ip;            ip += 8;
    int* cnt2   = ip;            ip += 8;
    int* prefix = ip;            ip += 8;

    // aliases inside attnb
    float* outg   = attnb;                               // 4096x768 fp32 (MoE)
    u16*   ndw_bf = (u16*)(attnb + (size_t)3146240);     // 18.87M u16 (MoE)
    float* Smem   = attnb;                               // fractal-phase scores

    // bf16 buffers
    u16* Wqkv_bf  = allocb((size_t)QKVC*DIM);
    u16* Wproj_bf = allocb((size_t)DD);
    u16* Wexp_bf  = allocb((size_t)NEXP*EDIM*DIM);
    u16* inw_bf   = allocb((size_t)3*QKVC*DIM);
    u16* outw_bf  = allocb((size_t)3*DD);
    u16* pw_bf    = allocb((size_t)3*DD);
    u16* Wc_bf    = allocb((size_t)3*DD);
    u16* wT3_bf   = allocb((size_t)3*DD);
    u16* mem_bf   = allocb((size_t)448*DIM);
    u16* qkv_bf   = allocb((size_t)NTOK*QKVC);     // hosts Xg_bf later
    u16* Vt_bf    = allocb((size_t)NBATCH*DIM*NSEQ);
    u16* P_bf     = allocb((size_t)48*NSEQ*NSEQ);  // also hidden_bf, later Pm_bf
    u16* lnx_bf   = allocb((size_t)NTOK*DIM);
    u16* o_bf     = allocb((size_t)NTOK*DIM);      // attn out; later qm_bf
    u16* inx_bf   = allocb((size_t)NTOK*DIM);
    u16* mhao_bf  = allocb((size_t)NTOK*DIM);
    u16* kvL_bf   = allocb((size_t)3*256*2*DIM);   // [3][256][1536] fused K|V per level
    u16* Vtm3_bf  = allocb((size_t)3*DIM*256);     // [3][768][M_l]
    u16* Xg_bf    = qkv_bf;
    u16* hidden_bf= P_bf;
    u16* Pm_bf    = P_bf;
    u16* qm_bf    = o_bf;

    float* outf = (float*)d_out;
    dim3 T256(256), T64(64);
    I3 Ms3 = {64, 128, 256};

    k_zero<<<1, 32, 0, stream>>>(cnt, 16);
    k_ln<<<NTOK, T256, 0, stream>>>(x, ln1g, ln1b, nullptr, lnx_bf);
    // PHM weight builds (bf16 except router)
    k_phm<<<dim3((QKVC*DIM+255)/256,1), T256, 0, stream>>>(qkvA, qkvS, Wqkv_bf, 576, 192, DIM, 0,0,0, 1);
    k_phm<<<dim3((DD+255)/256,1),  T256, 0, stream>>>(projA, projS, Wproj_bf, 192, 192, DIM, 0,0,0, 1);
    k_phm<<<dim3((NEXP*DIM+255)/256,1), T256, 0, stream>>>(rA, rS, Wrout, 2, 192, DIM, 0,0,0, 0);
    k_phm<<<dim3((EDIM*DIM+255)/256,NEXP), T256, 0, stream>>>(eA, eS, Wexp_bf, 768, 192, DIM,
                                                              64L, (long)4*768*192, (long)EDIM*DIM, 1);
    // all small weight converts in ONE dispatch
    {
        CJ J;
        J.s[0]=(const float4*)inw;  J.d[0]=(ushort4*)inw_bf;  J.n4[0]=3*QKVC*DIM/4;
        J.s[1]=(const float4*)outw; J.d[1]=(ushort4*)outw_bf; J.n4[1]=3*DD/4;
        J.s[2]=(const float4*)pw;   J.d[2]=(ushort4*)pw_bf;   J.n4[2]=3*DD/4;
        J.s[3]=(const float4*)mem0; J.d[3]=(ushort4*)mem_bf;              J.n4[3]=64*DIM/4;
        J.s[4]=(const float4*)mem1; J.d[4]=(ushort4*)(mem_bf + 64*DIM);   J.n4[4]=128*DIM/4;
        J.s[5]=(const float4*)mem2; J.d[5]=(ushort4*)(mem_bf + 192*DIM);  J.n4[5]=256*DIM/4;
        k_cvt_multi<<<dim3(1024, 6), T256, 0, stream>>>(J);
    }
    // fused fractal out-proj weights: Wc[l] = pw[l] @ outw[l]; bc[l] = pw[l]@outb[l] + pb[l]
    k_bc<<<dim3(DIM/4, 3), T256, 0, stream>>>(pw, outb, pb, bcb);
    k_transw_b<<<dim3(DD/256, 3), T256, 0, stream>>>(outw_bf, wT3_bf);
    {
        L3 dd3 = {0, DD, 2*DD}, z3 = {0,0,0};
        I3 m768 = {DIM, DIM, DIM};
        k_mgemm_b3<2,2,2><<<dim3(12,12,3), T256, 0, stream>>>(pw_bf, dd3, DIM, m768,
                                                              wT3_bf, dd3, DIM, DIM, DIM,
                                                              nullptr, z3, Wc_bf, dd3, DIM, 1.f, 0);
    }
    // all 3 fractal K|V projections (mem-side, chain-independent) in ONE dispatch
    {
        L3 xo = {0, 64L*DIM, 192L*DIM};
        L3 wo = {(long)DD, (long)QKVC*DIM + DD, 2L*QKVC*DIM + DD};
        L3 bo = {(long)DIM, (long)QKVC + DIM, 2L*QKVC + DIM};
        L3 co = {0, 256L*2*DIM, 2*256L*2*DIM};
        k_mgemm_b3<1,1,2><<<dim3(8,48,3), T64, 0, stream>>>(mem_bf, xo, DIM, Ms3,
                                                            inw_bf, wo, DIM, 2*DIM, DIM,
                                                            inb, bo, kvL_bf, co, 2*DIM, 1.f, 0);
    }
    k_transvm_b<<<dim3((DIM*256)/256, 3), T256, 0, stream>>>(kvL_bf, Vtm3_bf, Ms3);

    // ---- quantum attention ----
    k_mgemm<2,2,4><<<dim3(16,18), T256, 0, stream>>>(lnx_bf, DIM, NTOK, Wqkv_bf, DIM, QKVC, DIM,
                                                     qkvb, nullptr, 0, nullptr, qkv_bf, QKVC, 1.f, 0);
    k_transv<<<dim3(8,12,NBATCH), T256, 0, stream>>>(qkv_bf, Vt_bf);
    k_mgemm_qk<2,2,4><<<dim3(4,4,48), T256, 0, stream>>>(qkv_bf, attnb);
    k_supsoft<<<dim3(NTOK), T256, 0, stream>>>(attnb, P_bf, wsup, went);
    k_cvt4<<<4096, T256, 0, stream>>>((const float4*)ndw, (ushort4*)ndw_bf, NEXP*DIM*EDIM/4);
    k_mgemm_pv<1,1,2><<<dim3(16,2,48), T64, 0, stream>>>(P_bf, Vt_bf, o_bf);
    k_mgemm<2,2,2><<<dim3(32,12), T256, 0, stream>>>(o_bf, DIM, NTOK, Wproj_bf, DIM, DIM, DIM,
                                                     projb, x, DIM, attnd, nullptr, DIM, 1.f, 0);
    // ---- MoE ----
    k_ln<<<NTOK, T256, 0, stream>>>(attnd, ln2g, ln2b, lnbuf, lnx_bf);
    k_route<<<NTOK, T256, 0, stream>>>(lnbuf, Wrout, rb, dr, did, topi, topw, cnt);
    k_prefix<<<1, 1, 0, stream>>>(cnt, prefix);
    k_assign<<<8, T256, 0, stream>>>(topi, prefix, cnt2, rowof, tokof);
    k_gather<<<dim3(1536), T256, 0, stream>>>(lnx_bf, tokof, Xg_bf);
    k_mgemm_expert<2,2,4><<<dim3(16,24,NEXP), T256, 0, stream>>>(Xg_bf, DIM, Wexp_bf, DIM, (long)EDIM*DIM,
                                                                 eb, EDIM, prefix, cnt,
                                                                 nullptr, hidden_bf, EDIM, EDIM, DIM, 1);
    k_mgemm_expert<2,2,2><<<dim3(32,12,NEXP), T256, 0, stream>>>(hidden_bf, EDIM, ndw_bf, EDIM, (long)DIM*EDIM,
                                                                 ndb, DIM, prefix, cnt,
                                                                 outg, nullptr, DIM, DIM, EDIM, 0);
    k_combine<<<dim3(6144), T256, 0, stream>>>(attnd, outg, rowof, topw, eo, inx_bf);
    // ---- fractal memory (3 levels; K/V + Vt precomputed above) ----
    int Ms[3] = {64, 128, 256};
    for (int l=0; l<3; ++l){
        const u16* iwl = inw_bf + (size_t)l*QKVC*DIM;
        int M = Ms[l];
        k_mgemm<2,2,2><<<dim3(32,12), T256, 0, stream>>>(inx_bf, DIM, NTOK, iwl, DIM, DIM, DIM,
                                                         inb + (size_t)l*QKVC, nullptr, 0, nullptr, qm_bf, DIM, 1.f, 0);
        k_mgemm_memqk<1,1,2><<<dim3(64, M/32, MHEADS), T64, 0, stream>>>(qm_bf, kvL_bf + (size_t)l*256*2*DIM, 2*DIM,
                                                                         Smem, M, 0.10206207261596577f);
        k_softmax_mem<<<dim3(MHEADS*NTOK), T64, 0, stream>>>(Smem, Pm_bf, M);
        k_mgemm_mempv<1,1,2><<<dim3(64,3,MHEADS), T64, 0, stream>>>(Pm_bf, Vtm3_bf + (size_t)l*DIM*256, mhao_bf, M);
        // fused (out-proj ∘ proc-proj): a_l = mhao @ Wc^T + bc ; accum += a_l ; inx_bf = bf16(a_l)
        k_mgemm<2,2,2><<<dim3(32,12), T256, 0, stream>>>(mhao_bf, DIM, NTOK, Wc_bf + (size_t)l*DD, DIM, DIM, DIM,
                                                         bcb + (size_t)l*DIM, (l==0 ? eo : accum), DIM,
                                                         accum, inx_bf, DIM, 1.f, 0);
    }
    k_ln<<<NTOK, T256, 0, stream>>>(accum, ln3g, ln3b, outf, nullptr);
}

// Round 7
// 686.001 us; speedup vs baseline: 6.6428x; 1.0449x over previous
//
#include <hip/hip_runtime.h>
#include <math.h>

#define DIM    768
#define NTOK   2048
#define NSEQ   512
#define NBATCH 4
#define NHEADS 12
#define HD     64
#define QKVC   2304
#define MHEADS 8
#define MHD    96
#define NEXP   8
#define EDIM   3072
#define DD     (DIM*DIM)

typedef unsigned short u16;
typedef __attribute__((ext_vector_type(8))) short short8;
typedef __attribute__((ext_vector_type(4))) float f32x4;

struct L3 { long a, b, c; };
struct I3 { int a, b, c; };
struct CJ { const float4* s[6]; ushort4* d[6]; int n4[6]; };

__device__ __forceinline__ float gelu_exact(float v){
    return 0.5f * v * (1.f + erff(v * 0.70710678118654752f));
}
__device__ __forceinline__ u16 f2bf(float f){
    unsigned int u = __builtin_bit_cast(unsigned int, f);
    unsigned int r = (u + 0x7FFFu + ((u >> 16) & 1u)) >> 16;
    return (u16)r;
}
__device__ __forceinline__ float bf2f(u16 b){
    unsigned int u = ((unsigned int)b) << 16;
    return __builtin_bit_cast(float, u);
}
__device__ __forceinline__ float fast_tanh(float s){
    return 1.f - 2.f/(__expf(2.f*s) + 1.f);
}
// async global->LDS, 16B per lane; LDS dest linear (wave-uniform base + lane*16)
__device__ __forceinline__ void gll16(const u16* g, u16* l){
    __builtin_amdgcn_global_load_lds((const __attribute__((address_space(1))) void*)g,
                                     (__attribute__((address_space(3))) void*)l, 16, 0, 0);
}

// ================= MFMA bf16 GEMM core =================
// Per-wave tile (16*FR)^2; block tile (WM*16*FR)x(WN*16*FR); BK=64; WM*WN waves.
// DB=1: double-buffered LDS (2-stage pipeline, one barrier/k-step) — use when LDS<=32KB.
// DB=0: single buffer, 2 barriers/k-step — use for 128x128 tiles (keeps 32KB LDS, occupancy).
// XOR-swizzled LDS via pre-swizzled global SOURCE + linear global_load_lds dest (m201 rule).
template<int WM,int WN,int FR,int DB>
__device__ __forceinline__ void mgemm_core(
    const u16* __restrict__ Xb, int ldx, int rowBase, int rowLim,
    const u16* __restrict__ Wb, int ldw, int colBase, int colLim, int K,
    const float* __restrict__ bias,
    const float* __restrict__ res, int ldres,
    float* __restrict__ Cf, u16* __restrict__ Cb, int ldc,
    float scale, int act)
{
    constexpr int TM = 16*FR;
    constexpr int RM = WM*TM, RN = WN*TM, NT = WM*WN*64;
    constexpr int IA = (RM*8)/NT, IB = (RN*8)/NT;
    constexpr int NB = DB ? 2 : 1;
    __shared__ u16 As[NB][RM*64];
    __shared__ u16 Bs[NB][RN*64];
    int tid = threadIdx.x;
    int lane = tid & 63, w = tid >> 6;
    int wm = (w / WN) * TM, wn = (w % WN) * TM;
    const f32x4 zf = {0.f, 0.f, 0.f, 0.f};
    f32x4 acc[FR][FR];
    #pragma unroll
    for (int i=0;i<FR;i++)
        #pragma unroll
        for (int j=0;j<FR;j++) acc[i][j] = zf;

    const bool fullA = (rowBase + RM <= rowLim);
    const bool fullB = (colBase + RN <= colLim);
    const int nt = (K + 63) >> 6;
    int lr = lane & 15, lk = lane >> 4;

    auto stage = [&](int buf, int k0){
        const bool kfull = (k0 + 64 <= K);
        if (fullA && kfull) {
            #pragma unroll
            for (int it = 0; it < IA; ++it) {
                int idx = it*NT + tid;
                int r = idx >> 3, c = idx & 7;
                gll16(&Xb[(size_t)(rowBase + r)*ldx + k0 + ((c ^ (r & 7)) << 3)], &As[buf][(size_t)idx*8]);
            }
        } else {
            #pragma unroll
            for (int it = 0; it < IA; ++it) {
                int idx = it*NT + tid;
                int r = idx >> 3, c = idx & 7;
                int gr = rowBase + r;
                uint4 v = {0u,0u,0u,0u};
                if (gr < rowLim && (k0 + c*8) < K) v = *(const uint4*)&Xb[(size_t)gr*ldx + k0 + c*8];
                *(uint4*)&As[buf][r*64 + ((c ^ (r & 7)) * 8)] = v;
            }
        }
        if (fullB && kfull) {
            #pragma unroll
            for (int it = 0; it < IB; ++it) {
                int idx = it*NT + tid;
                int r = idx >> 3, c = idx & 7;
                gll16(&Wb[(size_t)(colBase + r)*ldw + k0 + ((c ^ (r & 7)) << 3)], &Bs[buf][(size_t)idx*8]);
            }
        } else {
            #pragma unroll
            for (int it = 0; it < IB; ++it) {
                int idx = it*NT + tid;
                int r = idx >> 3, c = idx & 7;
                int gc = colBase + r;
                uint4 v = {0u,0u,0u,0u};
                if (gc < colLim && (k0 + c*8) < K) v = *(const uint4*)&Wb[(size_t)gc*ldw + k0 + c*8];
                *(uint4*)&Bs[buf][r*64 + ((c ^ (r & 7)) * 8)] = v;
            }
        }
    };
    auto compute = [&](const u16* Ac, const u16* Bc){
        #pragma unroll
        for (int ks = 0; ks < 2; ++ks) {
            short8 af[FR], bfr[FR];
            #pragma unroll
            for (int mi=0; mi<FR; mi++){
                int row = wm + mi*16 + lr;
                int cidx = (ks*4 + lk) ^ (row & 7);
                af[mi] = *(const short8*)&Ac[row*64 + cidx*8];
            }
            #pragma unroll
            for (int ni=0; ni<FR; ni++){
                int col = wn + ni*16 + lr;
                int cidx = (ks*4 + lk) ^ (col & 7);
                bfr[ni] = *(const short8*)&Bc[col*64 + cidx*8];
            }
            #pragma unroll
            for (int mi=0; mi<FR; mi++)
                #pragma unroll
                for (int ni=0; ni<FR; ni++)
                    acc[mi][ni] = __builtin_amdgcn_mfma_f32_16x16x32_bf16(af[mi], bfr[ni], acc[mi][ni], 0, 0, 0);
        }
    };

    if (DB) {
        stage(0, 0);
        __syncthreads();
        for (int t = 0; t < nt; ++t) {
            if (t + 1 < nt) stage((t+1)&1, (t+1)*64);
            compute(As[t&1], Bs[t&1]);
            __syncthreads();
        }
    } else {
        for (int t = 0; t < nt; ++t) {
            stage(0, t*64);
            __syncthreads();
            compute(As[0], Bs[0]);
            __syncthreads();
        }
    }
    // epilogue: D row = (lane>>4)*4 + reg, col = lane&15  [m89-verified]
    int lg = lane >> 4;
    #pragma unroll
    for (int mi=0; mi<FR; mi++){
        #pragma unroll
        for (int r=0; r<4; r++){
            int row = rowBase + wm + mi*16 + lg*4 + r;
            if (row >= rowLim) continue;
            #pragma unroll
            for (int ni=0; ni<FR; ni++){
                int col = colBase + wn + ni*16 + lr;
                if (col >= colLim) continue;
                float v = acc[mi][ni][r] * scale;
                if (bias) v += bias[col];
                if (act == 1) v = gelu_exact(v);
                if (Cb) Cb[(size_t)row*ldc + col] = f2bf(v);
                if (res) v += res[(size_t)row*ldres + col];
                if (Cf) Cf[(size_t)row*ldc + col] = v;
            }
        }
    }
}

template<int WM,int WN,int FR,int DB>
__global__ __launch_bounds__(WM*WN*64) void k_mgemm(
    const u16* __restrict__ X, int ldx, int M,
    const u16* __restrict__ W, int ldw, int N, int K,
    const float* __restrict__ bias, const float* __restrict__ res, int ldres,
    float* __restrict__ Cf, u16* __restrict__ Cb, int ldc, float scale, int act)
{
    constexpr int RM = WM*16*FR, RN = WN*16*FR;
    mgemm_core<WM,WN,FR,DB>(X, ldx, blockIdx.x*RM, M, W, ldw, blockIdx.y*RN, N, K,
                            bias, res, ldres, Cf, Cb, ldc, scale, act);
}

// batched-by-3 variant: z selects offsets into X/W/bias/C and M
template<int WM,int WN,int FR,int DB>
__global__ __launch_bounds__(WM*WN*64) void k_mgemm_b3(
    const u16* __restrict__ X, L3 xo, int ldx, I3 Mv,
    const u16* __restrict__ W, L3 wo, int ldw, int N, int K,
    const float* __restrict__ bias, L3 bo,
    u16* __restrict__ Cb, L3 co, int ldc, float scale, int act)
{
    constexpr int RM = WM*16*FR, RN = WN*16*FR;
    int z = blockIdx.z;
    int M    = (z==0) ? Mv.a : (z==1) ? Mv.b : Mv.c;
    long xof = (z==0) ? xo.a : (z==1) ? xo.b : xo.c;
    long wof = (z==0) ? wo.a : (z==1) ? wo.b : wo.c;
    long bof = (z==0) ? bo.a : (z==1) ? bo.b : bo.c;
    long cof = (z==0) ? co.a : (z==1) ? co.b : co.c;
    if ((int)blockIdx.x * RM >= M) return;
    mgemm_core<WM,WN,FR,DB>(X + xof, ldx, blockIdx.x*RM, M, W + wof, ldw, blockIdx.y*RN, N, K,
                            bias ? bias + bof : nullptr, nullptr, 0, nullptr, Cb + cof, ldc, scale, act);
}

template<int WM,int WN,int FR,int DB>
__global__ __launch_bounds__(WM*WN*64) void k_mgemm_expert(
    const u16* __restrict__ X, int ldx,
    const u16* __restrict__ Wb, int ldw, long wStride,
    const float* __restrict__ biasB, int biasStride,
    const int* __restrict__ prefix, const int* __restrict__ cnt,
    float* __restrict__ Cf, u16* __restrict__ Cb, int ldc, int N, int K, int act)
{
    constexpr int RM = WM*16*FR, RN = WN*16*FR;
    int e = blockIdx.z;
    int n = cnt[e];
    if ((int)blockIdx.x * RM >= n) return;
    mgemm_core<WM,WN,FR,DB>(X, ldx, prefix[e] + blockIdx.x*RM, prefix[e] + n,
                            Wb + (size_t)e*wStride, ldw, blockIdx.y*RN, N, K,
                            biasB + (size_t)e*biasStride, nullptr, 0, Cf, Cb, ldc, 1.f, act);
}

// scores[b,h,n,m] = 0.125 * q_n . k_m  (bf16 out)
template<int WM,int WN,int FR,int DB>
__global__ __launch_bounds__(WM*WN*64) void k_mgemm_qk(const u16* __restrict__ qkv, u16* __restrict__ attn)
{
    constexpr int RM = WM*16*FR, RN = WN*16*FR;
    int z = blockIdx.z, b = z / NHEADS, h = z % NHEADS;
    const u16* X = qkv + (size_t)b*NSEQ*QKVC + h*HD;          // q
    const u16* W = qkv + (size_t)b*NSEQ*QKVC + DIM + h*HD;    // k
    u16* C = attn + (size_t)z*NSEQ*NSEQ;
    mgemm_core<WM,WN,FR,DB>(X, QKVC, blockIdx.x*RM, NSEQ, W, QKVC, blockIdx.y*RN, NSEQ, HD,
                            nullptr, nullptr, 0, nullptr, C, NSEQ, 0.125f, 0);
}

// o[b,n,h*64+d] = sum_m P[b,h,n,m] * V[b,m,h*64+d]; Vt[b][d][m] supplies W
template<int WM,int WN,int FR,int DB>
__global__ __launch_bounds__(WM*WN*64) void k_mgemm_pv(const u16* __restrict__ P, const u16* __restrict__ Vt, u16* __restrict__ o)
{
    constexpr int RM = WM*16*FR, RN = WN*16*FR;
    int z = blockIdx.z, b = z / NHEADS, h = z % NHEADS;
    const u16* X = P + (size_t)z*NSEQ*NSEQ;
    const u16* W = Vt + ((size_t)b*DIM + h*HD)*NSEQ;
    u16* C = o + (size_t)b*NSEQ*DIM + h*HD;
    mgemm_core<WM,WN,FR,DB>(X, NSEQ, blockIdx.x*RM, NSEQ, W, NSEQ, blockIdx.y*RN, HD, NSEQ,
                            nullptr, nullptr, 0, nullptr, C, DIM, 1.f, 0);
}

// mem-MHA PV: O[n, h*96+d] = sum_m P[h][n][m] * Vt[h*96+d][m]
template<int WM,int WN,int FR,int DB>
__global__ __launch_bounds__(WM*WN*64) void k_mgemm_mempv(const u16* __restrict__ P, const u16* __restrict__ Vt,
                                                          u16* __restrict__ O, int M)
{
    constexpr int RM = WM*16*FR, RN = WN*16*FR;
    int h = blockIdx.z;
    mgemm_core<WM,WN,FR,DB>(P + (size_t)h*NTOK*M, M, blockIdx.x*RM, NTOK, Vt + (size_t)h*MHD*M, M,
                            blockIdx.y*RN, MHD, M,
                            nullptr, nullptr, 0, nullptr, O + h*MHD, DIM, 1.f, 0);
}

// ===== fused mem-MHA scores + row softmax: block = 64 q-rows x full M (<=256), 4 waves =====
// P[h][n][m] = softmax_m(scale * q[n,h*96:].k[m,h*96:]) as bf16
__global__ __launch_bounds__(256) void k_memqk_soft(
    const u16* __restrict__ q, const u16* __restrict__ kv, int ldk,
    u16* __restrict__ P, int M, float scale)
{
    constexpr int RM = 64, RN = 256, NT = 256, K = MHD;
    __shared__ u16 As[RM*64];
    __shared__ u16 Bs[RN*64];
    __shared__ float red0[RM][4];
    __shared__ float red1[RM][4];
    int h = blockIdx.y;
    int rowBase = blockIdx.x * RM;
    const u16* Xb = q + h*MHD;     // ldx = DIM
    const u16* Wb = kv + h*MHD;    // ldw = ldk
    int tid = threadIdx.x, lane = tid & 63, w = tid >> 6;
    int wn = w * 64;
    int lr = lane & 15, lk = lane >> 4;
    const f32x4 zf = {0.f,0.f,0.f,0.f};
    f32x4 acc[4][4];
    #pragma unroll
    for (int i=0;i<4;i++)
        #pragma unroll
        for (int j=0;j<4;j++) acc[i][j] = zf;

    for (int k0 = 0; k0 < K; k0 += 64) {
        const bool kfull = (k0 + 64 <= K);
        if (kfull) {   // rows always full (NTOK multiple of 64)
            #pragma unroll
            for (int it = 0; it < 2; ++it) {
                int idx = it*NT + tid;
                int r = idx >> 3, c = idx & 7;
                gll16(&Xb[(size_t)(rowBase + r)*DIM + k0 + ((c ^ (r & 7)) << 3)], &As[(size_t)idx*8]);
            }
        } else {
            #pragma unroll
            for (int it = 0; it < 2; ++it) {
                int idx = it*NT + tid;
                int r = idx >> 3, c = idx & 7;
                uint4 v = {0u,0u,0u,0u};
                if ((k0 + c*8) < K) v = *(const uint4*)&Xb[(size_t)(rowBase + r)*DIM + k0 + c*8];
                *(uint4*)&As[r*64 + ((c ^ (r & 7)) * 8)] = v;
            }
        }
        #pragma unroll
        for (int it = 0; it < 8; ++it) {
            int idx = it*NT + tid;
            int r = idx >> 3, c = idx & 7;
            uint4 v = {0u,0u,0u,0u};
            if (r < M && (k0 + c*8) < K) v = *(const uint4*)&Wb[(size_t)r*ldk + k0 + c*8];
            *(uint4*)&Bs[r*64 + ((c ^ (r & 7)) * 8)] = v;
        }
        __syncthreads();
        #pragma unroll
        for (int ks = 0; ks < 2; ++ks) {
            short8 af[4], bfr[4];
            #pragma unroll
            for (int mi=0; mi<4; mi++){
                int row = mi*16 + lr;
                int cidx = (ks*4 + lk) ^ (row & 7);
                af[mi] = *(const short8*)&As[row*64 + cidx*8];
            }
            #pragma unroll
            for (int ni=0; ni<4; ni++){
                int col = wn + ni*16 + lr;
                int cidx = (ks*4 + lk) ^ (col & 7);
                bfr[ni] = *(const short8*)&Bs[col*64 + cidx*8];
            }
            #pragma unroll
            for (int mi=0; mi<4; mi++)
                #pragma unroll
                for (int ni=0; ni<4; ni++)
                    acc[mi][ni] = __builtin_amdgcn_mfma_f32_16x16x32_bf16(af[mi], bfr[ni], acc[mi][ni], 0, 0, 0);
        }
        __syncthreads();
    }
    // ---- fused row softmax over M cols ----
    int lg = lane >> 4;
    float sc[4][4][4];   // [mi][r][ni]
    float rmax[4][4];
    #pragma unroll
    for (int mi=0; mi<4; mi++){
        #pragma unroll
        for (int r=0; r<4; r++){
            float m = -1e30f;
            #pragma unroll
            for (int ni=0; ni<4; ni++){
                int col = wn + ni*16 + lr;
                float v = (col < M) ? acc[mi][ni][r]*scale : -1e30f;
                sc[mi][r][ni] = v;
                m = fmaxf(m, v);
            }
            m = fmaxf(m, __shfl_xor(m, 1));
            m = fmaxf(m, __shfl_xor(m, 2));
            m = fmaxf(m, __shfl_xor(m, 4));
            m = fmaxf(m, __shfl_xor(m, 8));
            rmax[mi][r] = m;
        }
    }
    if (lr == 0){
        #pragma unroll
        for (int mi=0; mi<4; mi++)
            #pragma unroll
            for (int r=0; r<4; r++) red0[mi*16 + lg*4 + r][w] = rmax[mi][r];
    }
    __syncthreads();
    float gmax[4][4], rsum[4][4];
    #pragma unroll
    for (int mi=0; mi<4; mi++){
        #pragma unroll
        for (int r=0; r<4; r++){
            int row = mi*16 + lg*4 + r;
            float g = fmaxf(fmaxf(red0[row][0], red0[row][1]), fmaxf(red0[row][2], red0[row][3]));
            gmax[mi][r] = g;
            float s = 0.f;
            #pragma unroll
            for (int ni=0; ni<4; ni++){
                int col = wn + ni*16 + lr;
                if (col < M) s += __expf(sc[mi][r][ni] - g);
            }
            s += __shfl_xor(s, 1);
            s += __shfl_xor(s, 2);
            s += __shfl_xor(s, 4);
            s += __shfl_xor(s, 8);
            rsum[mi][r] = s;
        }
    }
    if (lr == 0){
        #pragma unroll
        for (int mi=0; mi<4; mi++)
            #pragma unroll
            for (int r=0; r<4; r++) red1[mi*16 + lg*4 + r][w] = rsum[mi][r];
    }
    __syncthreads();
    #pragma unroll
    for (int mi=0; mi<4; mi++){
        #pragma unroll
        for (int r=0; r<4; r++){
            int row = mi*16 + lg*4 + r;
            float tot = red1[row][0] + red1[row][1] + red1[row][2] + red1[row][3];
            float inv = 1.f / tot;
            #pragma unroll
            for (int ni=0; ni<4; ni++){
                int col = wn + ni*16 + lr;
                if (col < M)
                    P[((size_t)h*NTOK + rowBase + row)*M + col] = f2bf(__expf(sc[mi][r][ni] - gmax[mi][r]) * inv);
            }
        }
    }
}

// batched outw transpose: wT3[z][c][r] = outw[z][r][c]
__global__ __launch_bounds__(256) void k_transw_b(const u16* __restrict__ src, u16* __restrict__ dst)
{
    int z = blockIdx.y;
    int idx = blockIdx.x*256 + threadIdx.x;
    int r = idx / DIM, c = idx % DIM;
    dst[(size_t)z*DD + (size_t)c*DIM + r] = src[(size_t)z*DD + (size_t)r*DIM + c];
}

// batched V transpose from fused KV: Vtm3[z][d][m] = kvL[z][m][768+d], m<M_z
__global__ __launch_bounds__(256) void k_transvm_b(const u16* __restrict__ kvL, u16* __restrict__ Vtm3, I3 Mv)
{
    int z = blockIdx.y;
    int M = (z==0) ? Mv.a : (z==1) ? Mv.b : Mv.c;
    int idx = blockIdx.x*256 + threadIdx.x;
    if (idx >= DIM*M) return;
    int m = idx / DIM, d = idx % DIM;
    Vtm3[(size_t)z*DIM*256 + (size_t)d*M + m] = kvL[(size_t)z*256*2*DIM + (size_t)m*2*DIM + DIM + d];
}

// ================= PHM weight materialization =================
__global__ __launch_bounds__(256) void k_phm(
    const float* __restrict__ A, const float* __restrict__ S, void* __restrict__ W,
    int So, int Si, int inF, long Astride, long Sstride, long Wstride, int obf)
{
    int e = blockIdx.y;
    const float* Ae = A + (size_t)e*Astride;
    const float* Se = S + (size_t)e*Sstride;
    size_t idx = (size_t)blockIdx.x*256 + threadIdx.x;
    size_t total = (size_t)(So*4) * inF;
    if (idx >= total) return;
    int in = (int)(idx % inF);
    int o  = (int)(idx / inF);
    int a = o / So, c = o % So, b = in / Si, d = in % Si;
    float w = 0.f;
    #pragma unroll
    for (int i=0;i<4;i++) w = fmaf(Ae[i*16 + a*4 + b], Se[((size_t)i*So + c)*Si + d], w);
    if (obf) ((u16*)W)[(size_t)e*Wstride + idx] = f2bf(w);
    else     ((float*)W)[(size_t)e*Wstride + idx] = w;
}

// ================= fp32 -> bf16 converts =================
__global__ __launch_bounds__(256) void k_cvt4(const float4* __restrict__ s, ushort4* __restrict__ d, int n4)
{
    for (int i = blockIdx.x*256 + threadIdx.x; i < n4; i += gridDim.x*256){
        float4 v = s[i];
        ushort4 o; o.x = f2bf(v.x); o.y = f2bf(v.y); o.z = f2bf(v.z); o.w = f2bf(v.w);
        d[i] = o;
    }
}
__global__ __launch_bounds__(256) void k_cvt_multi(CJ J)
{
    int z = blockIdx.y;
    const float4* s = J.s[z]; ushort4* d = J.d[z]; int n4 = J.n4[z];
    for (int i = blockIdx.x*256 + threadIdx.x; i < n4; i += gridDim.x*256){
        float4 v = s[i];
        ushort4 o; o.x = f2bf(v.x); o.y = f2bf(v.y); o.z = f2bf(v.z); o.w = f2bf(v.w);
        d[i] = o;
    }
}

// bc[l][i] = dot(pw[l][i][:], outb[l][:]) + pb[l][i]
__global__ __launch_bounds__(256) void k_bc(const float* __restrict__ pw, const float* __restrict__ outb,
                                            const float* __restrict__ pb, float* __restrict__ bc)
{
    int l = blockIdx.y;
    int i = blockIdx.x*4 + (threadIdx.x >> 6);
    int lane = threadIdx.x & 63;
    const float* pr = pw + ((size_t)l*DIM + i)*DIM;
    const float* ob = outb + (size_t)l*DIM;
    float s = 0.f;
    for (int j = lane; j < DIM; j += 64) s = fmaf(pr[j], ob[j], s);
    for (int off=32; off; off>>=1) s += __shfl_xor(s, off);
    if (lane == 0) bc[(size_t)l*DIM + i] = s + pb[(size_t)l*DIM + i];
}

// ================= LayerNorm (row=768), dual output =================
__global__ __launch_bounds__(256) void k_ln(const float* __restrict__ x, const float* __restrict__ g,
                                            const float* __restrict__ b,
                                            float* __restrict__ yf, u16* __restrict__ yb)
{
    int row = blockIdx.x, tid = threadIdx.x;
    const float* xr = x + (size_t)row * DIM;
    float v0 = xr[tid], v1 = xr[tid+256], v2 = xr[tid+512];
    float s = v0+v1+v2;
    float ss = v0*v0 + v1*v1 + v2*v2;
    for (int off=32; off; off>>=1){ s += __shfl_xor(s,off); ss += __shfl_xor(ss,off); }
    __shared__ float sa[4], sb[4];
    int wid = tid >> 6;
    if ((tid & 63) == 0){ sa[wid]=s; sb[wid]=ss; }
    __syncthreads();
    s  = sa[0]+sa[1]+sa[2]+sa[3];
    ss = sb[0]+sb[1]+sb[2]+sb[3];
    float mean = s * (1.f/DIM);
    float var  = ss * (1.f/DIM) - mean*mean;
    float rstd = rsqrtf(var + 1e-5f);
    float o0 = (v0-mean)*rstd*g[tid]     + b[tid];
    float o1 = (v1-mean)*rstd*g[tid+256] + b[tid+256];
    float o2 = (v2-mean)*rstd*g[tid+512] + b[tid+512];
    if (yf){ float* yr = yf + (size_t)row*DIM; yr[tid]=o0; yr[tid+256]=o1; yr[tid+512]=o2; }
    if (yb){ u16* yr = yb + (size_t)row*DIM; yr[tid]=f2bf(o0); yr[tid+256]=f2bf(o1); yr[tid+512]=f2bf(o2); }
}

// ===== fused sup/ent mix + tanh + softmax (bf16 scores in): block per (b,n) =====
__global__ __launch_bounds__(256) void k_supsoft(
    const u16* __restrict__ attn, u16* __restrict__ P,
    const float* __restrict__ wsup, const float* __restrict__ went)
{
    __shared__ float S[NHEADS][NSEQ];
    __shared__ float ws[144], we[144];
    int bn = blockIdx.x;
    int b = bn >> 9, n = bn & 511;
    int tid = threadIdx.x;
    if (tid < 144){ ws[tid] = wsup[tid]; we[tid] = went[tid]; }
    size_t base = ((size_t)b*NHEADS*NSEQ + n)*NSEQ;
    #pragma unroll
    for (int it=0; it<12; ++it){
        int idx = it*256 + tid;
        int j = idx >> 8, m2 = (idx & 255) * 2;
        unsigned int v = *(const unsigned int*)&attn[base + (size_t)j*NSEQ*NSEQ + m2];
        S[j][m2]   = bf2f((u16)(v & 0xFFFFu));
        S[j][m2+1] = bf2f((u16)(v >> 16));
    }
    __syncthreads();
    #pragma unroll
    for (int half=0; half<2; ++half){
        int m = tid + half*256;
        float av[12], sup[12];
        #pragma unroll
        for (int j=0;j<12;j++) av[j] = S[j][m];
        #pragma unroll
        for (int i=0;i<12;i++){
            float s = 0.f;
            #pragma unroll
            for (int j=0;j<12;j++) s = fmaf(ws[i*12+j], av[j], s);
            sup[i] = s;
        }
        #pragma unroll
        for (int i=0;i<12;i++){
            float s = sup[i];
            #pragma unroll
            for (int j=0;j<12;j++) s = fmaf(we[i*12+j], sup[j], s);
            av[i] = fast_tanh(s);
        }
        #pragma unroll
        for (int i=0;i<12;i++) S[i][m] = av[i];
    }
    __syncthreads();
    int lane = tid & 63, wv = tid >> 6;
    #pragma unroll
    for (int jj=0; jj<3; ++jj){
        int j = wv*3 + jj;
        float v[8], mx = -1e30f;
        #pragma unroll
        for (int k=0;k<8;k++){ v[k] = S[j][lane + 64*k]; mx = fmaxf(mx, v[k]); }
        for (int off=32; off; off>>=1) mx = fmaxf(mx, __shfl_xor(mx, off));
        float sum = 0.f;
        #pragma unroll
        for (int k=0;k<8;k++){ v[k] = __expf(v[k]-mx); sum += v[k]; }
        for (int off=32; off; off>>=1) sum += __shfl_xor(sum, off);
        float inv = 1.f/sum;
        #pragma unroll
        for (int k=0;k<8;k++) P[base + (size_t)j*NSEQ*NSEQ + lane + 64*k] = f2bf(v[k]*inv);
    }
}

// ================= V transpose (main attn): Vt[b][d][m] = qkv_bf[b][m][1536+d] =================
__global__ __launch_bounds__(256) void k_transv(const u16* __restrict__ qkv, u16* __restrict__ Vt)
{
    __shared__ u16 L[64][65];
    int mt = blockIdx.x*64, dt = blockIdx.y*64, b = blockIdx.z;
    int tid = threadIdx.x;
    #pragma unroll
    for (int it=0; it<16; ++it){
        int idx = it*256 + tid;
        int mm = idx >> 6, dd = idx & 63;
        L[mm][dd] = qkv[((size_t)b*NSEQ + mt + mm)*QKVC + 1536 + dt + dd];
    }
    __syncthreads();
    #pragma unroll
    for (int it=0; it<16; ++it){
        int idx = it*256 + tid;
        int dd = idx >> 6, mm = idx & 63;
        Vt[((size_t)b*DIM + dt + dd)*NSEQ + mt + mm] = L[mm][dd];
    }
}

// ================= MoE routing =================
__global__ __launch_bounds__(256) void k_route(
    const float* __restrict__ ln2, const float* __restrict__ Wr,
    const float* __restrict__ rb, const float* __restrict__ dr,
    const int* __restrict__ did, int* __restrict__ topi, float* __restrict__ topw, int* __restrict__ cnt)
{
    int t = blockIdx.x, tid = threadIdx.x;
    const float* xr = ln2 + (size_t)t*DIM;
    float a[8] = {};
    #pragma unroll
    for (int ii=0; ii<3; ii++){
        int i = tid + ii*256;
        float xv = xr[i];
        #pragma unroll
        for (int e=0;e<8;e++) a[e] = fmaf(xv, Wr[e*DIM + i], a[e]);
    }
    #pragma unroll
    for (int e=0;e<8;e++)
        for (int off=32; off; off>>=1) a[e] += __shfl_xor(a[e], off);
    __shared__ float sred[4][8];
    int wid = tid >> 6;
    if ((tid & 63) == 0){
        #pragma unroll
        for (int e=0;e<8;e++) sred[wid][e] = a[e];
    }
    __syncthreads();
    if (tid == 0){
        int d = did[0];
        float lg[8];
        #pragma unroll
        for (int e=0;e<8;e++) lg[e] = sred[0][e]+sred[1][e]+sred[2][e]+sred[3][e] + rb[e] + dr[d*8+e];
        int i1 = 0; float v1 = lg[0];
        #pragma unroll
        for (int e=1;e<8;e++) if (lg[e] > v1){ v1 = lg[e]; i1 = e; }
        int i2 = -1; float v2 = -1e30f;
        #pragma unroll
        for (int e=0;e<8;e++) if (e != i1 && lg[e] > v2){ v2 = lg[e]; i2 = e; }
        float e2 = __expf(v2 - v1);
        float inv = 1.f / (1.f + e2);
        topi[2*t] = i1; topi[2*t+1] = i2;
        topw[2*t] = inv; topw[2*t+1] = e2 * inv;
        atomicAdd(&cnt[i1], 1); atomicAdd(&cnt[i2], 1);
    }
}

__global__ void k_zero(int* p, int n){ int i = threadIdx.x; if (i < n) p[i] = 0; }

__global__ void k_prefix(const int* __restrict__ cnt, int* __restrict__ prefix){
    if (threadIdx.x == 0){ int s=0; for (int e=0;e<8;e++){ prefix[e]=s; s+=cnt[e]; } }
}

__global__ __launch_bounds__(256) void k_assign(
    const int* __restrict__ topi, const int* __restrict__ prefix,
    int* __restrict__ cnt2, int* __restrict__ rowof, int* __restrict__ tokof)
{
    int t = blockIdx.x*256 + threadIdx.x;
    if (t >= NTOK) return;
    #pragma unroll
    for (int k=0;k<2;k++){
        int e = topi[2*t+k];
        int slot = atomicAdd(&cnt2[e], 1);
        int row = prefix[e] + slot;
        rowof[2*t+k] = row;
        tokof[row] = t;
    }
}

// 16B-vectorized gather
__global__ __launch_bounds__(256) void k_gather(const u16* __restrict__ src, const int* __restrict__ tokof, u16* __restrict__ dst)
{
    int i = blockIdx.x*256 + threadIdx.x;
    int row = i / 96, c = (i % 96) * 8;
    *(uint4*)&dst[(size_t)row*DIM + c] = *(const uint4*)&src[(size_t)tokof[row]*DIM + c];
}

__global__ __launch_bounds__(256) void k_combine(
    const float* __restrict__ att, const float* __restrict__ outg,
    const int* __restrict__ rowof, const float* __restrict__ topw,
    float* __restrict__ eo, u16* __restrict__ eob)
{
    size_t i = (size_t)blockIdx.x*256 + threadIdx.x;
    int t = (int)(i / DIM), c = (int)(i % DIM);
    int r0 = rowof[2*t], r1 = rowof[2*t+1];
    float v = att[i] + topw[2*t]*outg[(size_t)r0*DIM+c] + topw[2*t+1]*outg[(size_t)r1*DIM+c];
    eo[i] = v;
    eob[i] = f2bf(v);
}

// ================= host =================
extern "C" void kernel_launch(void* const* d_in, const int* in_sizes, int n_in,
                              void* d_out, int out_size, void* d_ws, size_t ws_size,
                              hipStream_t stream)
{
    const float* x     = (const float*)d_in[0];
    const float* ln1g  = (const float*)d_in[1];
    const float* ln1b  = (const float*)d_in[2];
    const float* ln2g  = (const float*)d_in[3];
    const float* ln2b  = (const float*)d_in[4];
    const float* ln3g  = (const float*)d_in[5];
    const float* ln3b  = (const float*)d_in[6];
    const float* qkvA  = (const float*)d_in[7];
    const float* qkvS  = (const float*)d_in[8];
    const float* qkvb  = (const float*)d_in[9];
    const float* projA = (const float*)d_in[10];
    const float* projS = (const float*)d_in[11];
    const float* projb = (const float*)d_in[12];
    const float* wsup  = (const float*)d_in[13];
    const float* went  = (const float*)d_in[14];
    const float* rA    = (const float*)d_in[15];
    const float* rS    = (const float*)d_in[16];
    const float* rb    = (const float*)d_in[17];
    const float* dr    = (const float*)d_in[18];
    const float* eA    = (const float*)d_in[19];
    const float* eS    = (const float*)d_in[20];
    const float* eb    = (const float*)d_in[21];
    const float* ndw   = (const float*)d_in[22];
    const float* ndb   = (const float*)d_in[23];
    const float* mem0  = (const float*)d_in[24];
    const float* mem1  = (const float*)d_in[25];
    const float* mem2  = (const float*)d_in[26];
    const float* inw   = (const float*)d_in[27];
    const float* inb   = (const float*)d_in[28];
    const float* outw  = (const float*)d_in[29];
    const float* outb  = (const float*)d_in[30];
    const float* pw    = (const float*)d_in[31];
    const float* pb    = (const float*)d_in[32];
    const int*   did   = (const int*)d_in[33];

    float* f = (float*)d_ws;
    size_t off = 0;
    auto alloc = [&](size_t n){ float* p = f + off; off += (n + 3) & ~(size_t)3; return p; };
    auto allocb = [&](size_t n){ return (u16*)alloc((n + 1) / 2); };

    // fp32 buffers
    float* lnbuf  = alloc((size_t)NTOK*DIM);
    float* attnd  = alloc((size_t)NTOK*DIM);
    float* eo     = alloc((size_t)NTOK*DIM);
    float* accum  = alloc((size_t)NTOK*DIM);
    float* attnb  = alloc((size_t)48*NSEQ*NSEQ);   // u16 scores; hosts outg + ndw_bf
    float* Wrout  = alloc((size_t)NEXP*DIM);
    float* topw   = alloc((size_t)2*NTOK);
    float* bcb    = alloc((size_t)3*DIM);
    int* ip = (int*)alloc((size_t)6*NTOK + 64);
    int* topi   = ip;            ip += 2*NTOK;
    int* rowof  = ip;            ip += 2*NTOK;
    int* tokof  = ip;            ip += 2*NTOK;
    int* cnt    = ip;            ip += 8;
    int* cnt2   = ip;            ip += 8;
    int* prefix = ip;            ip += 8;

    // aliases inside attnb (scores dead after supsoft)
    u16*   scores = (u16*)attnb;                         // 48*512*512 u16
    float* outg   = attnb;                               // 4096x768 fp32 (MoE)
    u16*   ndw_bf = (u16*)(attnb + (size_t)3146240);     // 18.87M u16 (MoE)

    // bf16 buffers
    u16* Wqkv_bf  = allocb((size_t)QKVC*DIM);
    u16* Wproj_bf = allocb((size_t)DD);
    u16* Wexp_bf  = allocb((size_t)NEXP*EDIM*DIM);
    u16* inw_bf   = allocb((size_t)3*QKVC*DIM);
    u16* outw_bf  = allocb((size_t)3*DD);
    u16* pw_bf    = allocb((size_t)3*DD);
    u16* Wc_bf    = allocb((size_t)3*DD);
    u16* wT3_bf   = allocb((size_t)3*DD);
    u16* mem_bf   = allocb((size_t)448*DIM);
    u16* qkv_bf   = allocb((size_t)NTOK*QKVC);     // hosts Xg_bf later
    u16* Vt_bf    = allocb((size_t)NBATCH*DIM*NSEQ);
    u16* P_bf     = allocb((size_t)48*NSEQ*NSEQ);  // also hidden_bf, later Pm_bf
    u16* lnx_bf   = allocb((size_t)NTOK*DIM);
    u16* o_bf     = allocb((size_t)NTOK*DIM);      // attn out; later qm_bf
    u16* inx_bf   = allocb((size_t)NTOK*DIM);
    u16* mhao_bf  = allocb((size_t)NTOK*DIM);
    u16* kvL_bf   = allocb((size_t)3*256*2*DIM);   // [3][256][1536] fused K|V per level
    u16* Vtm3_bf  = allocb((size_t)3*DIM*256);     // [3][768][M_l]
    u16* Xg_bf    = qkv_bf;
    u16* hidden_bf= P_bf;
    u16* Pm_bf    = P_bf;
    u16* qm_bf    = o_bf;

    float* outf = (float*)d_out;
    dim3 T256(256), T64(64);
    I3 Ms3 = {64, 128, 256};

    k_zero<<<1, 32, 0, stream>>>(cnt, 16);
    k_ln<<<NTOK, T256, 0, stream>>>(x, ln1g, ln1b, nullptr, lnx_bf);
    // PHM weight builds (bf16 except router)
    k_phm<<<dim3((QKVC*DIM+255)/256,1), T256, 0, stream>>>(qkvA, qkvS, Wqkv_bf, 576, 192, DIM, 0,0,0, 1);
    k_phm<<<dim3((DD+255)/256,1),  T256, 0, stream>>>(projA, projS, Wproj_bf, 192, 192, DIM, 0,0,0, 1);
    k_phm<<<dim3((NEXP*DIM+255)/256,1), T256, 0, stream>>>(rA, rS, Wrout, 2, 192, DIM, 0,0,0, 0);
    k_phm<<<dim3((EDIM*DIM+255)/256,NEXP), T256, 0, stream>>>(eA, eS, Wexp_bf, 768, 192, DIM,
                                                              64L, (long)4*768*192, (long)EDIM*DIM, 1);
    // all small weight converts in ONE dispatch
    {
        CJ J;
        J.s[0]=(const float4*)inw;  J.d[0]=(ushort4*)inw_bf;  J.n4[0]=3*QKVC*DIM/4;
        J.s[1]=(const float4*)outw; J.d[1]=(ushort4*)outw_bf; J.n4[1]=3*DD/4;
        J.s[2]=(const float4*)pw;   J.d[2]=(ushort4*)pw_bf;   J.n4[2]=3*DD/4;
        J.s[3]=(const float4*)mem0; J.d[3]=(ushort4*)mem_bf;              J.n4[3]=64*DIM/4;
        J.s[4]=(const float4*)mem1; J.d[4]=(ushort4*)(mem_bf + 64*DIM);   J.n4[4]=128*DIM/4;
        J.s[5]=(const float4*)mem2; J.d[5]=(ushort4*)(mem_bf + 192*DIM);  J.n4[5]=256*DIM/4;
        k_cvt_multi<<<dim3(1024, 6), T256, 0, stream>>>(J);
    }
    // fused fractal out-proj weights: Wc[l] = pw[l] @ outw[l]; bc[l] = pw[l]@outb[l] + pb[l]
    k_bc<<<dim3(DIM/4, 3), T256, 0, stream>>>(pw, outb, pb, bcb);
    k_transw_b<<<dim3(DD/256, 3), T256, 0, stream>>>(outw_bf, wT3_bf);
    {
        L3 dd3 = {0, DD, 2*DD}, z3 = {0,0,0};
        I3 m768 = {DIM, DIM, DIM};
        k_mgemm_b3<2,2,2,1><<<dim3(12,12,3), T256, 0, stream>>>(pw_bf, dd3, DIM, m768,
                                                                wT3_bf, dd3, DIM, DIM, DIM,
                                                                nullptr, z3, Wc_bf, dd3, DIM, 1.f, 0);
    }
    // all 3 fractal K|V projections (mem-side, chain-independent) in ONE dispatch
    {
        L3 xo = {0, 64L*DIM, 192L*DIM};
        L3 wo = {(long)DD, (long)QKVC*DIM + DD, 2L*QKVC*DIM + DD};
        L3 bo = {(long)DIM, (long)QKVC + DIM, 2L*QKVC + DIM};
        L3 co = {0, 256L*2*DIM, 2*256L*2*DIM};
        k_mgemm_b3<1,1,2,1><<<dim3(8,48,3), T64, 0, stream>>>(mem_bf, xo, DIM, Ms3,
                                                              inw_bf, wo, DIM, 2*DIM, DIM,
                                                              inb, bo, kvL_bf, co, 2*DIM, 1.f, 0);
    }
    k_transvm_b<<<dim3((DIM*256)/256, 3), T256, 0, stream>>>(kvL_bf, Vtm3_bf, Ms3);

    // ---- quantum attention ----
    k_mgemm<2,2,4,0><<<dim3(16,18), T256, 0, stream>>>(lnx_bf, DIM, NTOK, Wqkv_bf, DIM, QKVC, DIM,
                                                       qkvb, nullptr, 0, nullptr, qkv_bf, QKVC, 1.f, 0);
    k_transv<<<dim3(8,12,NBATCH), T256, 0, stream>>>(qkv_bf, Vt_bf);
    k_mgemm_qk<2,2,4,0><<<dim3(4,4,48), T256, 0, stream>>>(qkv_bf, scores);
    k_supsoft<<<dim3(NTOK), T256, 0, stream>>>(scores, P_bf, wsup, went);
    k_cvt4<<<4096, T256, 0, stream>>>((const float4*)ndw, (ushort4*)ndw_bf, NEXP*DIM*EDIM/4);
    k_mgemm_pv<1,1,2,1><<<dim3(16,2,48), T64, 0, stream>>>(P_bf, Vt_bf, o_bf);
    k_mgemm<2,2,2,1><<<dim3(32,12), T256, 0, stream>>>(o_bf, DIM, NTOK, Wproj_bf, DIM, DIM, DIM,
                                                       projb, x, DIM, attnd, nullptr, DIM, 1.f, 0);
    // ---- MoE ----
    k_ln<<<NTOK, T256, 0, stream>>>(attnd, ln2g, ln2b, lnbuf, lnx_bf);
    k_route<<<NTOK, T256, 0, stream>>>(lnbuf, Wrout, rb, dr, did, topi, topw, cnt);
    k_prefix<<<1, 1, 0, stream>>>(cnt, prefix);
    k_assign<<<8, T256, 0, stream>>>(topi, prefix, cnt2, rowof, tokof);
    k_gather<<<dim3(1536), T256, 0, stream>>>(lnx_bf, tokof, Xg_bf);
    k_mgemm_expert<2,2,4,0><<<dim3(16,24,NEXP), T256, 0, stream>>>(Xg_bf, DIM, Wexp_bf, DIM, (long)EDIM*DIM,
                                                                   eb, EDIM, prefix, cnt,
                                                                   nullptr, hidden_bf, EDIM, EDIM, DIM, 1);
    k_mgemm_expert<2,2,2,1><<<dim3(32,12,NEXP), T256, 0, stream>>>(hidden_bf, EDIM, ndw_bf, EDIM, (long)DIM*EDIM,
                                                                   ndb, DIM, prefix, cnt,
                                                                   outg, nullptr, DIM, DIM, EDIM, 0);
    k_combine<<<dim3(6144), T256, 0, stream>>>(attnd, outg, rowof, topw, eo, inx_bf);
    // ---- fractal memory (3 levels; K/V + Vt precomputed above) ----
    int Ms[3] = {64, 128, 256};
    for (int l=0; l<3; ++l){
        const u16* iwl = inw_bf + (size_t)l*QKVC*DIM;
        int M = Ms[l];
        k_mgemm<2,2,2,1><<<dim3(32,12), T256, 0, stream>>>(inx_bf, DIM, NTOK, iwl, DIM, DIM, DIM,
                                                           inb + (size_t)l*QKVC, nullptr, 0, nullptr, qm_bf, DIM, 1.f, 0);
        k_memqk_soft<<<dim3(NTOK/64, MHEADS), T256, 0, stream>>>(qm_bf, kvL_bf + (size_t)l*256*2*DIM, 2*DIM,
                                                                 Pm_bf, M, 0.10206207261596577f);
        k_mgemm_mempv<1,1,2,1><<<dim3(64,3,MHEADS), T64, 0, stream>>>(Pm_bf, Vtm3_bf + (size_t)l*DIM*256, mhao_bf, M);
        // fused (out-proj ∘ proc-proj): a_l = mhao @ Wc^T + bc ; accum += a_l ; inx_bf = bf16(a_l)
        k_mgemm<2,2,2,1><<<dim3(32,12), T256, 0, stream>>>(mhao_bf, DIM, NTOK, Wc_bf + (size_t)l*DD, DIM, DIM, DIM,
                                                           bcb + (size_t)l*DIM, (l==0 ? eo : accum), DIM,
                                                           accum, inx_bf, DIM, 1.f, 0);
    }
    k_ln<<<NTOK, T256, 0, stream>>>(accum, ln3g, ln3b, outf, nullptr);
}